// Round 3
// baseline (845.910 us; speedup 1.0000x reference)
//
#include <hip/hip_runtime.h>
#include <cstdint>
#include <cstddef>

// ---------------- static problem config ----------------
#define B_   2
#define S_   2048
#define D_   1024
#define T_   4096          // B*S
#define H_   16
#define HD_  64
#define LQ_  512
#define LKV_ 256
#define FF_  1024
#define NR_  7
#define CAP_ 585

typedef unsigned int   u32;
typedef unsigned long long u64;
typedef __bf16 bf16_t;
typedef __bf16 bf16x8 __attribute__((ext_vector_type(8)));
typedef __bf16 bf16x4 __attribute__((ext_vector_type(4)));
typedef float  f32x4  __attribute__((ext_vector_type(4)));

// ---------------- workspace layout (bytes), regions phase-reused, ~111 MB ----------------
static constexpr size_t MB_ = 1024 * 1024;
static constexpr size_t KB_ = 1024;
// R0 0-16M: xn hi(8M)+lo(8M) -> att hi+lo -> xn2 f32 -> Wr2T bf16 (14.7M)
static constexpr size_t OFF_R0   = 0;
// R1 16-28M: zlat hi(6M)+lo(6M) -> Vthi bf16 8M (attn) -> xnb bf16 8M + Ws1T 4M
static constexpr size_t OFF_R1   = 16 * MB_;
// R2 28-44M: PLAT/PQC/PKV f32 temps (7M) -> q f32 16M -> hbuf bf16 16M
static constexpr size_t OFF_R2   = 28 * MB_;
// R3 44-76M: kv f32 32M -> actb bf16 8M + eout f32 16.8M
static constexpr size_t OFF_R3   = 44 * MB_;
// R4 76-92M: WoutT splits (4M) + packT temps -> Vtlo (8M @ 80M) -> Wr1H bf16 14.7M -> shout f32 16M
static constexpr size_t OFF_R4   = 76 * MB_;
static constexpr size_t OFF_X1   = 92 * MB_;             // Khi/Klo (attn) -> [T][D] f32 x1
static constexpr size_t OFF_PRI  = 108 * MB_;            // [NR][T] f32 (128K)
static constexpr size_t OFF_SELI = OFF_PRI + 128 * KB_;  // [NR][CAP] int
static constexpr size_t OFF_SELW = OFF_SELI + 32 * KB_;  // [NR][CAP] f32
static constexpr size_t OFF_ICNT = OFF_SELW + 32 * KB_;  // [T] int
static constexpr size_t OFF_IPR  = OFF_ICNT + 32 * KB_;  // [T][2] int
static constexpr size_t OFF_COS  = OFF_IPR + 64 * KB_;   // [S][16] f32
static constexpr size_t OFF_SIN  = OFF_COS + 128 * KB_;  // [S][16] f32
static constexpr size_t OFF_WS2T = 109 * MB_;            // Ws2T bf16 2M -> ends 111M
// sub-offsets
static constexpr size_t OFF_PLAT = OFF_R2;               // [1024][768] f32 (3M)
static constexpr size_t OFF_PQC  = OFF_R2 + 3 * MB_;     // [512][1024] f32 (2M)
static constexpr size_t OFF_PKV  = OFF_R2 + 5 * MB_;     // [256][2048] f32 (2M)
// R4 internals: WoutT survives through attn; PLT/PQT/PKT dead after q/kv GEMMs
static constexpr size_t OFF_WOTH = OFF_R4;                    // 76M, 2M (needed after attn)
static constexpr size_t OFF_WOTL = OFF_R4 + 2 * MB_;          // 78M, 2M
static constexpr size_t OFF_PLTH = OFF_R4 + 4 * MB_;          // 80M, 1.5M (dead after zlat GEMM)
static constexpr size_t OFF_PLTL = OFF_R4 + 5632 * KB_;       // 81.5M
static constexpr size_t OFF_PQTH = OFF_R4 + 7 * MB_;          // 83M, 1M (dead after q GEMM)
static constexpr size_t OFF_PQTL = OFF_R4 + 8 * MB_;          // 84M
static constexpr size_t OFF_PKTH = OFF_R4 + 9 * MB_;          // 85M, 1M (dead after kv GEMM)
static constexpr size_t OFF_PKTL = OFF_R4 + 10 * MB_;         // 86M -> ends 87M
// attention bf16 planes (alive only during attn)
static constexpr size_t OFF_VTHI = OFF_R1;                    // 16M, 8M (over dead zlat)
static constexpr size_t OFF_VTLO = OFF_R4 + 4 * MB_;          // 80M, 8M (over dead PLT/PQT/PKT + free)
static constexpr size_t OFF_KHI  = OFF_X1;                    // 92M, 8M (x1 written after attn)
static constexpr size_t OFF_KLO  = OFF_X1 + 8 * MB_;          // 100M, 8M

__device__ __forceinline__ void split2(float v, bf16_t& h, bf16_t& l) {
    h = (bf16_t)v;
    l = (bf16_t)(v - (float)h);
}

// ---------------- RMSNorm: MODE 0 -> emit hi/lo bf16 planes; MODE 1 -> emit f32 + single bf16 ----------------
template <int MODE>
__global__ __launch_bounds__(256) void rmsnorm_kernel(const float* __restrict__ x,
                                                      const float* __restrict__ w,
                                                      float* __restrict__ outf,
                                                      bf16_t* __restrict__ o1,
                                                      bf16_t* __restrict__ o2) {
    int t = blockIdx.x;
    int c = threadIdx.x * 4;
    float4 f = *(const float4*)(x + (size_t)t * D_ + c);
    float ss = f.x * f.x + f.y * f.y + f.z * f.z + f.w * f.w;
#pragma unroll
    for (int off = 32; off > 0; off >>= 1) ss += __shfl_down(ss, off);
    __shared__ float red[4];
    int lane = threadIdx.x & 63, wid = threadIdx.x >> 6;
    if (lane == 0) red[wid] = ss;
    __syncthreads();
    float tot = red[0] + red[1] + red[2] + red[3];
    float inv = 1.f / sqrtf(tot * (1.f / D_) + 1e-6f);
    float4 wv = *(const float4*)(w + c);
    float v[4];
    v[0] = f.x * inv * wv.x; v[1] = f.y * inv * wv.y;
    v[2] = f.z * inv * wv.z; v[3] = f.w * inv * wv.w;
    if (MODE == 0) {
        bf16x4 hv, lv;
#pragma unroll
        for (int j = 0; j < 4; j++) { bf16_t h, l; split2(v[j], h, l); hv[j] = h; lv[j] = l; }
        *(bf16x4*)(o1 + (size_t)t * D_ + c) = hv;
        *(bf16x4*)(o2 + (size_t)t * D_ + c) = lv;
    } else {
        float4 o; o.x = v[0]; o.y = v[1]; o.z = v[2]; o.w = v[3];
        *(float4*)(outf + (size_t)t * D_ + c) = o;
        bf16x4 bv;
#pragma unroll
        for (int j = 0; j < 4; j++) bv[j] = (bf16_t)v[j];
        *(bf16x4*)(o1 + (size_t)t * D_ + c) = bv;
    }
}

// ---------------- pack fp32 attention weights into [K][N] fused layouts ----------------
__global__ __launch_bounds__(256) void pack_w_kernel(const float* __restrict__ Wq_lat, const float* __restrict__ Wkv_lat,
                                                     const float* __restrict__ Wq_up, const float* __restrict__ Wrot_q,
                                                     const float* __restrict__ Wk_up, const float* __restrict__ Wrot_k,
                                                     const float* __restrict__ Wv_up,
                                                     float* __restrict__ PLAT, float* __restrict__ PQC,
                                                     float* __restrict__ PKV) {
    int i = blockIdx.x * 256 + threadIdx.x;
    const int NL = 1024 * 768;
    const int NQ = 512 * 1024;
    if (i < NL) {
        int k = i / 768, c = i - k * 768;
        PLAT[i] = (c < 512) ? Wq_lat[k * 512 + c] : Wkv_lat[k * 256 + (c - 512)];
    } else if (i < NL + NQ) {
        int i2 = i - NL;
        int k = i2 >> 10, c = i2 & 1023, h = c >> 6, j = c & 63;
        PQC[i2] = (j < 32) ? Wq_up[k * 1024 + c] : Wrot_q[k * 1024 + h * 64 + (j - 32)];
    } else {
        int i3 = i - NL - NQ;
        int k = i3 >> 11, c = i3 & 2047;
        if (c < 1024) {
            int h = c >> 6, j = c & 63;
            PKV[i3] = (j < 32) ? Wk_up[k * 1024 + c] : Wrot_k[k * 1024 + h * 64 + (j - 32)];
        } else {
            PKV[i3] = Wv_up[k * 1024 + (c - 1024)];
        }
    }
}

// ---------------- transpose + split: in [K][N] f32 -> outhi/outlo [N][K] bf16 ----------------
__global__ __launch_bounds__(256) void packTsplit_kernel(const float* __restrict__ in,
                                                         bf16_t* __restrict__ outhi, bf16_t* __restrict__ outlo,
                                                         int K, int N) {
    __shared__ float tile[32][33];
    const int k0 = blockIdx.x * 32, n0 = blockIdx.y * 32;
    const int rr = threadIdx.x >> 5, cc = threadIdx.x & 31;
#pragma unroll
    for (int it = 0; it < 4; it++) {
        int k = k0 + rr + it * 8;
        tile[rr + it * 8][cc] = in[(size_t)k * N + n0 + cc];
    }
    __syncthreads();
#pragma unroll
    for (int it = 0; it < 4; it++) {
        int nl = n0 + rr + it * 8;
        float v = tile[cc][rr + it * 8];
        bf16_t h, l; split2(v, h, l);
        outhi[(size_t)nl * K + k0 + cc] = h;
        outlo[(size_t)nl * K + k0 + cc] = l;
    }
}

// ---------------- rope tables ----------------
__global__ __launch_bounds__(256) void rope_table_kernel(float* __restrict__ ct, float* __restrict__ st) {
    int i = blockIdx.x * 256 + threadIdx.x;   // S_*16
    if (i >= S_ * 16) return;
    int s = i >> 4, j = i & 15;
    float inv = 1.f / powf(10000.f, (float)j * (1.f / 16.f));
    float fr = (float)s * inv;
    ct[i] = cosf(fr);
    st[i] = sinf(fr);
}

// apply rope in place: q [T][1024], k = cols 0..1023 of kv [T][2048]; rot dims = h*64+32..63
__global__ __launch_bounds__(256) void rope_apply_kernel(float* __restrict__ q, float* __restrict__ kv,
                                                         const float* __restrict__ ct, const float* __restrict__ st) {
    int gid = blockIdx.x * 256 + threadIdx.x;
    if (gid >= T_ * H_) return;
    int t = gid >> 4, h = gid & 15;
    int s = t & (S_ - 1);
    float c[16], sn[16];
#pragma unroll
    for (int j = 0; j < 16; j += 4) {
        *(float4*)&c[j]  = *(const float4*)(ct + s * 16 + j);
        *(float4*)&sn[j] = *(const float4*)(st + s * 16 + j);
    }
#pragma unroll
    for (int a2 = 0; a2 < 2; a2++) {
        float* p = a2 ? (kv + (size_t)t * 2048 + h * 64 + 32)
                      : (q  + (size_t)t * 1024 + h * 64 + 32);
        float r[32], o2[32];
#pragma unroll
        for (int j2 = 0; j2 < 32; j2 += 4) *(float4*)&r[j2] = *(const float4*)(p + j2);
#pragma unroll
        for (int i = 0; i < 16; i++) {
            o2[i]      = r[i] * c[i] - r[i + 16] * sn[i];
            o2[i + 16] = r[i + 16] * c[i] + r[i] * sn[i];
        }
#pragma unroll
        for (int j2 = 0; j2 < 32; j2 += 4) *(float4*)(p + j2) = *(const float4*)&o2[j2];
    }
}

// ---------------- K planes: kv f32 [T][2048] cols h*64+d -> Khi/Klo [(b*16+h)][s][64] bf16 ----------------
__global__ __launch_bounds__(256) void kpack_kernel(const float* __restrict__ kv,
                                                    bf16_t* __restrict__ Khi, bf16_t* __restrict__ Klo) {
    int i = blockIdx.x * 256 + threadIdx.x;      // T_*1024/4 threads
    int idx = i * 4;                             // output element index
    int d = idx & 63;
    int s = (idx >> 6) & (S_ - 1);
    int bh = idx >> 17;                          // b*16+h  (2^17 = S_*64)
    int b = bh >> 4, h = bh & 15;
    size_t src = ((size_t)(b * S_ + s)) * 2048 + h * 64 + d;
    float4 v = *(const float4*)(kv + src);
    bf16x4 hv, lv; bf16_t hh, ll;
    split2(v.x, hh, ll); hv[0] = hh; lv[0] = ll;
    split2(v.y, hh, ll); hv[1] = hh; lv[1] = ll;
    split2(v.z, hh, ll); hv[2] = hh; lv[2] = ll;
    split2(v.w, hh, ll); hv[3] = hh; lv[3] = ll;
    *(bf16x4*)(Khi + idx) = hv;
    *(bf16x4*)(Klo + idx) = lv;
}

// ---------------- V planes: kv f32 [b][s][1024 + hd] -> Vthi/Vtlo [b*1024+hd][S] bf16 (transposed) ----------------
__global__ __launch_bounds__(256) void vtrans_kernel(const float* __restrict__ kv,
                                                     bf16_t* __restrict__ Vthi, bf16_t* __restrict__ Vtlo) {
    __shared__ float tile[32][33];
    const int bz = blockIdx.z;
    const int s0 = blockIdx.x * 32, hd0 = blockIdx.y * 32;
    const int rr = threadIdx.x >> 5, cc = threadIdx.x & 31;
    const float* inb = kv + (size_t)bz * S_ * 2048 + 1024;
#pragma unroll
    for (int it = 0; it < 4; it++) {
        int s = s0 + rr + it * 8;
        tile[rr + it * 8][cc] = inb[(size_t)s * 2048 + hd0 + cc];
    }
    __syncthreads();
    bf16_t* oh = Vthi + (size_t)bz * 1024 * S_;
    bf16_t* ol = Vtlo + (size_t)bz * 1024 * S_;
#pragma unroll
    for (int it = 0; it < 4; it++) {
        int hd = hd0 + rr + it * 8;
        float v = tile[cc][rr + it * 8];
        bf16_t hh, ll; split2(v, hh, ll);
        oh[(size_t)hd * S_ + s0 + cc] = hh;
        ol[(size_t)hd * S_ + s0 + cc] = ll;
    }
}

// ---------------- bf16x3 MFMA GEMM (near-fp32): C = (Ah+Al)@(Bh+Bl)^T (+resid) ----------------
// M fixed = 4096 (full rows). EMIT: 0 = f32 out, 1 = hi/lo split out.
template <bool RESID, int EMIT>
__global__ __launch_bounds__(256) void mfma3_gemm_kernel(const bf16_t* __restrict__ Ah, const bf16_t* __restrict__ Al,
                                                         const bf16_t* __restrict__ Bh, const bf16_t* __restrict__ Bl,
                                                         float* __restrict__ Cf,
                                                         bf16_t* __restrict__ Chi, bf16_t* __restrict__ Clo,
                                                         const float* __restrict__ resid,
                                                         int K, int lda, int ldc) {
    __shared__ __align__(16) bf16_t Ash[128 * 32];
    __shared__ __align__(16) bf16_t Asl[128 * 32];
    __shared__ __align__(16) bf16_t Bsh[128 * 32];
    __shared__ __align__(16) bf16_t Bsl[128 * 32];
    const int tid = threadIdx.x;
    const int lane = tid & 63, w = tid >> 6;
    const int wm = (w & 1) * 64, wn = (w >> 1) * 64;
    const int m0 = blockIdx.y * 128, n0 = blockIdx.x * 128;

    f32x4 acc[4][4];
#pragma unroll
    for (int mi = 0; mi < 4; mi++)
#pragma unroll
        for (int ni = 0; ni < 4; ni++) { f32x4 zz = {0.f, 0.f, 0.f, 0.f}; acc[mi][ni] = zz; }

    const int mrow = lane & 15, q = lane >> 4;
    for (int k0 = 0; k0 < K; k0 += 32) {
#pragma unroll
        for (int i = 0; i < 2; i++) {
            int chunk = tid + i * 256;
            int row = chunk >> 2, koff = (chunk & 3) * 8;
            size_t aoff = (size_t)(m0 + row) * lda + k0 + koff;
            size_t boff = (size_t)(n0 + row) * K + k0 + koff;
            *(uint4*)(Ash + row * 32 + koff) = *(const uint4*)(Ah + aoff);
            *(uint4*)(Asl + row * 32 + koff) = *(const uint4*)(Al + aoff);
            *(uint4*)(Bsh + row * 32 + koff) = *(const uint4*)(Bh + boff);
            *(uint4*)(Bsl + row * 32 + koff) = *(const uint4*)(Bl + boff);
        }
        __syncthreads();
        bf16x8 ah[4], al[4], bh[4], bl[4];
#pragma unroll
        for (int mi = 0; mi < 4; mi++) {
            ah[mi] = *(const bf16x8*)(Ash + (wm + mi * 16 + mrow) * 32 + q * 8);
            al[mi] = *(const bf16x8*)(Asl + (wm + mi * 16 + mrow) * 32 + q * 8);
        }
#pragma unroll
        for (int ni = 0; ni < 4; ni++) {
            bh[ni] = *(const bf16x8*)(Bsh + (wn + ni * 16 + mrow) * 32 + q * 8);
            bl[ni] = *(const bf16x8*)(Bsl + (wn + ni * 16 + mrow) * 32 + q * 8);
        }
#pragma unroll
        for (int mi = 0; mi < 4; mi++)
#pragma unroll
            for (int ni = 0; ni < 4; ni++) {
                acc[mi][ni] = __builtin_amdgcn_mfma_f32_16x16x32_bf16(al[mi], bh[ni], acc[mi][ni], 0, 0, 0);
                acc[mi][ni] = __builtin_amdgcn_mfma_f32_16x16x32_bf16(ah[mi], bl[ni], acc[mi][ni], 0, 0, 0);
                acc[mi][ni] = __builtin_amdgcn_mfma_f32_16x16x32_bf16(ah[mi], bh[ni], acc[mi][ni], 0, 0, 0);
            }
        __syncthreads();
    }
    // epilogue: C/D layout col = lane&15, row = (lane>>4)*4 + v
#pragma unroll
    for (int mi = 0; mi < 4; mi++) {
        int rbase = m0 + wm + mi * 16 + q * 4;
#pragma unroll
        for (int v = 0; v < 4; v++) {
            int r = rbase + v;
#pragma unroll
            for (int ni = 0; ni < 4; ni++) {
                int c = n0 + wn + ni * 16 + mrow;
                float val = acc[mi][ni][v];
                if (RESID) val += resid[(size_t)r * ldc + c];
                if (EMIT == 0) {
                    Cf[(size_t)r * ldc + c] = val;
                } else {
                    bf16_t h, l; split2(val, h, l);
                    Chi[(size_t)r * ldc + c] = h;
                    Clo[(size_t)r * ldc + c] = l;
                }
            }
        }
    }
}

// ---------------- MFMA flash attention (causal), bf16x3 QK / bf16x2 PV, K/V pre-split planes ----------------
// grid: 512 = 16 q-tiles (128 rows) x 32 bh, LPT heavy-first. 4 waves, wave w owns q rows [w*32, w*32+32).
// LDS: Kh/Kl [64][64] XOR-swizzled, Vth/Vtl [64][72] transposed+padded, Ph [128][64] XOR-swizzled. 50 KB.
__global__ __launch_bounds__(256) void attn_mfma_kernel(const float* __restrict__ Q,
                                                        const bf16_t* __restrict__ Khig, const bf16_t* __restrict__ Klog,
                                                        const bf16_t* __restrict__ Vthig, const bf16_t* __restrict__ Vtlog,
                                                        bf16_t* __restrict__ Ohi, bf16_t* __restrict__ Olo) {
    __shared__ __align__(16) bf16_t Kh[64][64];
    __shared__ __align__(16) bf16_t Kl[64][64];
    __shared__ __align__(16) bf16_t Vth[64][72];   // Vth[d][k] (transposed)
    __shared__ __align__(16) bf16_t Vtl[64][72];
    __shared__ __align__(16) bf16_t Ph[128][64];   // P rounded to bf16, XOR-swizzled cols

    const int tid = threadIdx.x;
    const int lane = tid & 63, w = tid >> 6;
    const int mrow = lane & 15, qq = lane >> 4;
    const int jb = blockIdx.x;
    const int qt = 15 - (jb >> 5);                 // LPT: heaviest q-tiles first
    const int bh = jb & 31, b = bh >> 4, h = bh & 15;
    const int q0 = qt * 128;
    const float*  Qb  = Q + (size_t)b * S_ * 1024 + h * 64;
    const bf16_t* Khb = Khig + (size_t)bh * S_ * 64;
    const bf16_t* Klb = Klog + (size_t)bh * S_ * 64;
    const bf16_t* Vhb = Vthig + (size_t)(b * 1024 + h * 64) * S_;
    const bf16_t* Vlb = Vtlog + (size_t)(b * 1024 + h * 64) * S_;

    // ---- Q fragments in registers, pre-scaled by 1/sqrt(HD)=0.125 (exact), hi/lo split ----
    bf16x8 qh[2][2], ql[2][2];                     // [mi][ks]
#pragma unroll
    for (int mi = 0; mi < 2; mi++) {
        int r = q0 + w * 32 + mi * 16 + mrow;
#pragma unroll
        for (int ks = 0; ks < 2; ks++) {
            const float* p = Qb + (size_t)r * 1024 + ks * 32 + qq * 8;
            float4 a = *(const float4*)p;
            float4 b2 = *(const float4*)(p + 4);
            float vals[8] = {a.x, a.y, a.z, a.w, b2.x, b2.y, b2.z, b2.w};
#pragma unroll
            for (int j = 0; j < 8; j++) {
                bf16_t hh, ll; split2(vals[j] * 0.125f, hh, ll);
                qh[mi][ks][j] = hh; ql[mi][ks][j] = ll;
            }
        }
    }

    f32x4 acc_o[2][4];
    float m_r[2][4], l_r[2][4];
#pragma unroll
    for (int mi = 0; mi < 2; mi++) {
#pragma unroll
        for (int ni = 0; ni < 4; ni++) { f32x4 zz = {0.f, 0.f, 0.f, 0.f}; acc_o[mi][ni] = zz; }
#pragma unroll
        for (int v = 0; v < 4; v++) { m_r[mi][v] = -1e30f; l_r[mi][v] = 0.f; }
    }

    const int ktmax = 2 * qt + 1;
    for (int kt = 0; kt <= ktmax; kt++) {
        const int k0 = kt * 64;
        // ---- stage K (row-major, XOR-swizzled) and V (transposed, padded) from bf16 planes ----
#pragma unroll
        for (int i = 0; i < 2; i++) {
            int c = tid + i * 256;                 // 512 chunks of 8 bf16 per plane
            int r = c >> 3, c8 = (c & 7) * 8;
            int csw = c8 ^ ((r & 7) << 3);
            *(uint4*)&Kh[r][csw] = *(const uint4*)(Khb + (size_t)(k0 + r) * 64 + c8);
            *(uint4*)&Kl[r][csw] = *(const uint4*)(Klb + (size_t)(k0 + r) * 64 + c8);
            *(uint4*)&Vth[r][c8] = *(const uint4*)(Vhb + (size_t)r * S_ + k0 + c8);
            *(uint4*)&Vtl[r][c8] = *(const uint4*)(Vlb + (size_t)r * S_ + k0 + c8);
        }
        __syncthreads();

        if (k0 <= q0 + w * 32 + 31) {   // wave-uniform: skip fully-masked half-tiles
            // ---- S = Q @ K^T (bf16x3) ----
            f32x4 acc_s[2][4];
#pragma unroll
            for (int mi = 0; mi < 2; mi++)
#pragma unroll
                for (int ni = 0; ni < 4; ni++) { f32x4 zz = {0.f, 0.f, 0.f, 0.f}; acc_s[mi][ni] = zz; }
#pragma unroll
            for (int ks = 0; ks < 2; ks++) {
                const int c0 = ks * 32 + qq * 8;
                bf16x8 bhf[4], blf[4];
#pragma unroll
                for (int ni = 0; ni < 4; ni++) {
                    int row = ni * 16 + mrow;
                    int cs = c0 ^ ((row & 7) << 3);
                    bhf[ni] = *(const bf16x8*)&Kh[row][cs];
                    blf[ni] = *(const bf16x8*)&Kl[row][cs];
                }
#pragma unroll
                for (int mi = 0; mi < 2; mi++)
#pragma unroll
                    for (int ni = 0; ni < 4; ni++) {
                        acc_s[mi][ni] = __builtin_amdgcn_mfma_f32_16x16x32_bf16(ql[mi][ks], bhf[ni], acc_s[mi][ni], 0, 0, 0);
                        acc_s[mi][ni] = __builtin_amdgcn_mfma_f32_16x16x32_bf16(qh[mi][ks], blf[ni], acc_s[mi][ni], 0, 0, 0);
                        acc_s[mi][ni] = __builtin_amdgcn_mfma_f32_16x16x32_bf16(qh[mi][ks], bhf[ni], acc_s[mi][ni], 0, 0, 0);
                    }
            }
            // ---- online softmax (rows: qq*4+v within 16-block; cols: ni*16+mrow) ----
            const bool diag = (kt >= 2 * qt);
#pragma unroll
            for (int mi = 0; mi < 2; mi++) {
#pragma unroll
                for (int v = 0; v < 4; v++) {
                    int rq = q0 + w * 32 + mi * 16 + qq * 4 + v;
                    float sv[4];
                    float rmax = -1e30f;
#pragma unroll
                    for (int ni = 0; ni < 4; ni++) {
                        float s = acc_s[mi][ni][v];
                        if (diag && (k0 + ni * 16 + mrow) > rq) s = -1e30f;
                        sv[ni] = s;
                        rmax = fmaxf(rmax, s);
                    }
#pragma unroll
                    for (int off = 1; off < 16; off <<= 1) rmax = fmaxf(rmax, __shfl_xor(rmax, off));
                    float mo = m_r[mi][v];
                    float mn = fmaxf(mo, rmax);
                    float al = __expf(mo - mn);
                    m_r[mi][v] = mn;
                    int rl = w * 32 + mi * 16 + qq * 4 + v;
                    int t7 = (rl & 7) << 3;
                    float rs = 0.f;
#pragma unroll
                    for (int ni = 0; ni < 4; ni++) {
                        float p = __expf(sv[ni] - mn);
                        bf16_t ph = (bf16_t)p;
                        Ph[rl][(ni * 16 + mrow) ^ t7] = ph;
                        rs += (float)ph;            // denominator from same rounded P -> consistent weights
                    }
#pragma unroll
                    for (int off = 1; off < 16; off <<= 1) rs += __shfl_xor(rs, off);
                    l_r[mi][v] = l_r[mi][v] * al + rs;
#pragma unroll
                    for (int ni = 0; ni < 4; ni++) acc_o[mi][ni][v] *= al;
                }
            }
            // ---- O += P @ V (bf16x2: P@Vl + P@Vh). P rows read by owning wave only. ----
#pragma unroll
            for (int ks = 0; ks < 2; ks++) {
                const int rc = ks * 32 + qq * 8;
                bf16x8 pah[2], vhf[4], vlf[4];
#pragma unroll
                for (int mi = 0; mi < 2; mi++) {
                    int rowp = w * 32 + mi * 16 + mrow;
                    int cp = rc ^ ((rowp & 7) << 3);
                    pah[mi] = *(const bf16x8*)&Ph[rowp][cp];
                }
#pragma unroll
                for (int ni = 0; ni < 4; ni++) {
                    int c = ni * 16 + mrow;
                    vhf[ni] = *(const bf16x8*)&Vth[c][rc];
                    vlf[ni] = *(const bf16x8*)&Vtl[c][rc];
                }
#pragma unroll
                for (int mi = 0; mi < 2; mi++)
#pragma unroll
                    for (int ni = 0; ni < 4; ni++) {
                        acc_o[mi][ni] = __builtin_amdgcn_mfma_f32_16x16x32_bf16(pah[mi], vlf[ni], acc_o[mi][ni], 0, 0, 0);
                        acc_o[mi][ni] = __builtin_amdgcn_mfma_f32_16x16x32_bf16(pah[mi], vhf[ni], acc_o[mi][ni], 0, 0, 0);
                    }
            }
        }
        __syncthreads();
    }
    // ---- epilogue: normalize, split hi/lo, store ----
#pragma unroll
    for (int mi = 0; mi < 2; mi++) {
#pragma unroll
        for (int v = 0; v < 4; v++) {
            int rq = q0 + w * 32 + mi * 16 + qq * 4 + v;
            float inv = 1.f / l_r[mi][v];
            size_t base = (size_t)(b * S_ + rq) * 1024 + h * 64;
#pragma unroll
            for (int ni = 0; ni < 4; ni++) {
                float val = acc_o[mi][ni][v] * inv;
                bf16_t hh, ll; split2(val, hh, ll);
                Ohi[base + ni * 16 + mrow] = hh;
                Olo[base + ni * 16 + mrow] = ll;
            }
        }
    }
}

// ---------------- gate: affinities + top-2 membership -> priority [NR][T] ----------------
__global__ __launch_bounds__(256) void gate_kernel(const float* __restrict__ xn2, const float* __restrict__ Wg,
                                                   const float* __restrict__ bias, float* __restrict__ pri) {
    __shared__ float red[256][8];
    int t = blockIdx.x, tid = threadIdx.x;
    float acc[7] = {0.f, 0.f, 0.f, 0.f, 0.f, 0.f, 0.f};
    for (int d = tid; d < D_; d += 256) {
        float xv = xn2[(size_t)t * D_ + d];
        const float* wr = Wg + d * 7;
#pragma unroll
        for (int e = 0; e < 7; e++) acc[e] = fmaf(xv, wr[e], acc[e]);
    }
#pragma unroll
    for (int e = 0; e < 7; e++) red[tid][e] = acc[e];
    __syncthreads();
    for (int s2 = 128; s2 > 0; s2 >>= 1) {
        if (tid < s2) {
#pragma unroll
            for (int e = 0; e < 7; e++) red[tid][e] += red[tid + s2][e];
        }
        __syncthreads();
    }
    if (tid == 0) {
        float a[7];
#pragma unroll
        for (int e = 0; e < 7; e++) a[e] = 1.f / (1.f + expf(-(red[0][e] + bias[e])));
        int e1 = 0;
#pragma unroll
        for (int e = 1; e < 7; e++) if (a[e] > a[e1]) e1 = e;     // strict > : lowest-index tiebreak
        int e2 = -1;
#pragma unroll
        for (int e = 0; e < 7; e++) if (e != e1 && (e2 < 0 || a[e] > a[e2])) e2 = e;
#pragma unroll
        for (int e = 0; e < 7; e++) pri[(size_t)e * T_ + t] = (e == e1 || e == e2) ? a[e] : -1.f;
    }
}

// ---------------- exact top-585 via 32-step binary threshold search (order-free slots) ----------------
__global__ __launch_bounds__(1024) void select_kernel(const float* __restrict__ pri, int* __restrict__ sel_idx,
                                                      float* __restrict__ sel_w, int* __restrict__ inv_cnt,
                                                      int* __restrict__ inv_pair) {
    __shared__ u32 keys[T_];        // 16 KB: float bits (monotone for positive floats); 0 = invalid
    __shared__ int redc[16];
    __shared__ int bcast;
    __shared__ int ctr;
    const int e = blockIdx.x, tid = threadIdx.x;
    const int lane = tid & 63, wid = tid >> 6;
#pragma unroll
    for (int i = 0; i < 4; i++) {
        int idx = tid + i * 1024;
        float p = pri[(size_t)e * T_ + idx];
        keys[idx] = (p > 0.f) ? __float_as_uint(p) : 0u;
    }
    if (tid == 0) ctr = 0;
    __syncthreads();

    u32 myk[4];
#pragma unroll
    for (int i = 0; i < 4; i++) myk[i] = keys[tid + i * 1024];

    // binary search: p = max t with count(keys >= t) >= CAP  (= CAP-th largest key, or 0 if < CAP valid)
    u32 p = 0;
    for (int b = 31; b >= 0; b--) {
        u32 t = p | (1u << b);
        int cnt = 0;
#pragma unroll
        for (int i = 0; i < 4; i++) cnt += (myk[i] >= t) ? 1 : 0;
#pragma unroll
        for (int off = 32; off > 0; off >>= 1) cnt += __shfl_down(cnt, off);
        if (lane == 0) redc[wid] = cnt;
        __syncthreads();
        if (tid == 0) {
            int tot = 0;
#pragma unroll
            for (int k2 = 0; k2 < 16; k2++) tot += redc[k2];
            bcast = tot;
        }
        __syncthreads();
        if (bcast >= CAP_) p = t;
        __syncthreads();
    }
    // count strictly greater
    {
        int cnt = 0;
#pragma unroll
        for (int i = 0; i < 4; i++) cnt += (myk[i] > p) ? 1 : 0;
#pragma unroll
        for (int off = 32; off > 0; off >>= 1) cnt += __shfl_down(cnt, off);
        if (lane == 0) redc[wid] = cnt;
        __syncthreads();
        if (tid == 0) {
            int tot = 0;
#pragma unroll
            for (int k2 = 0; k2 < 16; k2++) tot += redc[k2];
            bcast = tot;
        }
        __syncthreads();
    }
    int cntGT = bcast;
    int quota = CAP_ - cntGT;   // slots left for keys == p (>=1 when p>0)

    // assignment: kept = (k > p) or (k == p, p>0, index-rank < quota)
#pragma unroll
    for (int i = 0; i < 4; i++) {
        int idx = tid + i * 1024;
        u32 k = myk[i];
        bool kept = false;
        if (k > p) kept = true;
        else if (k == p && p != 0u) {
            int rank = 0;
            for (int j = 0; j < idx; j++) rank += (keys[j] == p) ? 1 : 0;
            kept = (rank < quota);
        }
        if (kept) {
            int s = atomicAdd(&ctr, 1);
            sel_idx[e * CAP_ + s] = idx;
            sel_w[e * CAP_ + s] = __uint_as_float(k);
            int pos = atomicAdd(&inv_cnt[idx], 1);
            inv_pair[idx * 2 + pos] = e * CAP_ + s;
        }
    }
    __syncthreads();
    for (int s = ctr + tid; s < CAP_; s += 1024) {  // unfilled slots -> token 0, weight 0
        sel_idx[e * CAP_ + s] = 0;
        sel_w[e * CAP_ + s] = 0.f;
    }
}

// ---------------- transpose + convert: out[z][n][k] = (bf16) in[z][k][nbase+n] ----------------
__global__ __launch_bounds__(256) void packT_kernel(const float* __restrict__ in, bf16_t* __restrict__ out,
                                                    int K, int N, int nbase,
                                                    long long inStride, long long outStride) {
    __shared__ float tile[32][33];
    const int z = blockIdx.z;
    const int k0 = blockIdx.x * 32, n0 = blockIdx.y * 32;
    const int rr = threadIdx.x >> 5, cc = threadIdx.x & 31;
    const float* inz = in + (size_t)z * inStride;
#pragma unroll
    for (int it = 0; it < 4; it++) {
        int k = k0 + rr + it * 8;
        tile[rr + it * 8][cc] = inz[(size_t)k * N + nbase + n0 + cc];
    }
    __syncthreads();
    bf16_t* outz = out + (size_t)z * outStride;
#pragma unroll
    for (int it = 0; it < 4; it++) {
        int nl = n0 + rr + it * 8;
        outz[(size_t)nl * K + k0 + cc] = (bf16_t)tile[cc][rr + it * 8];
    }
}

// ---------------- bf16 MFMA GEMM (single precision pass, experts): C = gather(A) @ Bt^T (*scale) ----------------
template <bool GATHER, bool SCALE, bool OUTBF16>
__global__ __launch_bounds__(256) void mfma_gemm_kernel(const bf16_t* __restrict__ A, const bf16_t* __restrict__ Bt,
                                                        void* __restrict__ Cv,
                                                        const int* __restrict__ gidx, const float* __restrict__ scale,
                                                        int M, int K, int lda, int ldc,
                                                        long long strideA, long long strideBt, long long strideC,
                                                        int gstride) {
    __shared__ __align__(16) bf16_t As[128 * 32];
    __shared__ __align__(16) bf16_t Bs[128 * 32];
    const int tid = threadIdx.x;
    const int lane = tid & 63, w = tid >> 6;
    const int wm = (w & 1) * 64, wn = (w >> 1) * 64;
    const int z = blockIdx.z;
    const int m0 = blockIdx.y * 128, n0 = blockIdx.x * 128;
    const bf16_t* Az = A + (GATHER ? 0 : (size_t)z * strideA);
    const bf16_t* Bz = Bt + (size_t)z * strideBt;

    int arow[2];
#pragma unroll
    for (int i = 0; i < 2; i++) {
        int chunk = tid + i * 256;
        int r = m0 + (chunk >> 2);
        if (r > M - 1) r = M - 1;
        arow[i] = GATHER ? gidx[z * gstride + r] : r;
    }

    f32x4 acc[4][4];
#pragma unroll
    for (int mi = 0; mi < 4; mi++)
#pragma unroll
        for (int ni = 0; ni < 4; ni++) { f32x4 zz = {0.f, 0.f, 0.f, 0.f}; acc[mi][ni] = zz; }

    const int mrow = lane & 15, q = lane >> 4;
    for (int k0 = 0; k0 < K; k0 += 32) {
#pragma unroll
        for (int i = 0; i < 2; i++) {
            int chunk = tid + i * 256;
            int row = chunk >> 2, koff = (chunk & 3) * 8;
            *(uint4*)(As + row * 32 + koff) = *(const uint4*)(Az + (size_t)arow[i] * lda + k0 + koff);
            *(uint4*)(Bs + row * 32 + koff) = *(const uint4*)(Bz + (size_t)(n0 + row) * K + k0 + koff);
        }
        __syncthreads();
        bf16x8 af[4], bfr[4];
#pragma unroll
        for (int mi = 0; mi < 4; mi++)
            af[mi] = *(const bf16x8*)(As + (wm + mi * 16 + mrow) * 32 + q * 8);
#pragma unroll
        for (int ni = 0; ni < 4; ni++)
            bfr[ni] = *(const bf16x8*)(Bs + (wn + ni * 16 + mrow) * 32 + q * 8);
#pragma unroll
        for (int mi = 0; mi < 4; mi++)
#pragma unroll
            for (int ni = 0; ni < 4; ni++)
                acc[mi][ni] = __builtin_amdgcn_mfma_f32_16x16x32_bf16(af[mi], bfr[ni], acc[mi][ni], 0, 0, 0);
        __syncthreads();
    }
#pragma unroll
    for (int mi = 0; mi < 4; mi++) {
        int rbase = m0 + wm + mi * 16 + q * 4;
#pragma unroll
        for (int v = 0; v < 4; v++) {
            int r = rbase + v;
            if (r < M) {
                float sc = SCALE ? scale[z * gstride + r] : 1.f;
#pragma unroll
                for (int ni = 0; ni < 4; ni++) {
                    int c = n0 + wn + ni * 16 + mrow;
                    float val = acc[mi][ni][v];
                    if (SCALE) val *= sc;
                    size_t off = (size_t)z * strideC + (size_t)r * ldc + c;
                    if (OUTBF16) ((bf16_t*)Cv)[off] = (bf16_t)val;
                    else         ((float*)Cv)[off] = val;
                }
            }
        }
    }
}

// ---------------- SwiGLU elementwise ----------------
__global__ __launch_bounds__(256) void swiglu_kernel(const bf16_t* __restrict__ h, bf16_t* __restrict__ act,
                                                     int rows) {
    int i8 = blockIdx.x * 256 + threadIdx.x;
    int total = rows * 128;
    if (i8 >= total) return;
    int r = i8 >> 7, f = (i8 & 127) * 8;
    bf16x8 h1 = *(const bf16x8*)(h + (size_t)r * 2048 + f);
    bf16x8 h2 = *(const bf16x8*)(h + (size_t)r * 2048 + 1024 + f);
    bf16x8 o;
#pragma unroll
    for (int j = 0; j < 8; j++) {
        float a = (float)h1[j], g = (float)h2[j];
        o[j] = (bf16_t)(a * g / (1.f + __expf(-g)));
    }
    *(bf16x8*)(act + (size_t)r * 1024 + f) = o;
}

// ---------------- final combine: out = x1 + shared + sum routed ----------------
__global__ __launch_bounds__(256) void final_kernel(const float* __restrict__ x1, const float* __restrict__ sh,
                                                    const float* __restrict__ eout, const int* __restrict__ icnt,
                                                    const int* __restrict__ ipair, float* __restrict__ out) {
    int t = blockIdx.x, c = threadIdx.x * 4;
    float4 v = *(const float4*)(x1 + (size_t)t * D_ + c);
    float4 s2 = *(const float4*)(sh + (size_t)t * D_ + c);
    v.x += s2.x; v.y += s2.y; v.z += s2.z; v.w += s2.w;
    int n = icnt[t];
    for (int p = 0; p < n; p++) {
        int row = ipair[t * 2 + p];
        float4 ev = *(const float4*)(eout + (size_t)row * D_ + c);
        v.x += ev.x; v.y += ev.y; v.z += ev.z; v.w += ev.w;
    }
    *(float4*)(out + (size_t)t * D_ + c) = v;
}

// ---------------- launch ----------------
extern "C" void kernel_launch(void* const* d_in, const int* in_sizes, int n_in,
                              void* d_out, int out_size, void* d_ws, size_t ws_size,
                              hipStream_t stream) {
    (void)in_sizes; (void)n_in; (void)out_size; (void)ws_size;
    const float* x       = (const float*)d_in[0];
    const float* Wq_lat  = (const float*)d_in[2];
    const float* Wkv_lat = (const float*)d_in[3];
    const float* Wrot_q  = (const float*)d_in[4];
    const float* Wrot_k  = (const float*)d_in[5];
    const float* Wq_up   = (const float*)d_in[6];
    const float* Wk_up   = (const float*)d_in[7];
    const float* Wv_up   = (const float*)d_in[8];
    const float* Wout    = (const float*)d_in[9];
    const float* n1w     = (const float*)d_in[10];
    const float* n2w     = (const float*)d_in[11];
    const float* Ws1     = (const float*)d_in[12];
    const float* Ws2     = (const float*)d_in[13];
    const float* Wr1     = (const float*)d_in[14];
    const float* Wr2     = (const float*)d_in[15];
    const float* Wgate   = (const float*)d_in[16];
    const float* ebias   = (const float*)d_in[17];
    float* out = (float*)d_out;

    char* wsb = (char*)d_ws;
    // phase-1 pointers
    bf16_t* xnhi = (bf16_t*)(wsb + OFF_R0);
    bf16_t* xnlo = (bf16_t*)(wsb + OFF_R0 + 8 * MB_);
    bf16_t* zlhi = (bf16_t*)(wsb + OFF_R1);
    bf16_t* zllo = (bf16_t*)(wsb + OFF_R1 + 6 * MB_);
    float*  plat = (float*)(wsb + OFF_PLAT);
    float*  pqc  = (float*)(wsb + OFF_PQC);
    float*  pkv  = (float*)(wsb + OFF_PKV);
    bf16_t* plth = (bf16_t*)(wsb + OFF_PLTH);
    bf16_t* pltl = (bf16_t*)(wsb + OFF_PLTL);
    bf16_t* pqth = (bf16_t*)(wsb + OFF_PQTH);
    bf16_t* pqtl = (bf16_t*)(wsb + OFF_PQTL);
    bf16_t* pkth = (bf16_t*)(wsb + OFF_PKTH);
    bf16_t* pktl = (bf16_t*)(wsb + OFF_PKTL);
    bf16_t* woth = (bf16_t*)(wsb + OFF_WOTH);
    bf16_t* wotl = (bf16_t*)(wsb + OFF_WOTL);
    float*  qb   = (float*)(wsb + OFF_R2);
    float*  kvb  = (float*)(wsb + OFF_R3);
    bf16_t* khig = (bf16_t*)(wsb + OFF_KHI);
    bf16_t* klog = (bf16_t*)(wsb + OFF_KLO);
    bf16_t* vthig = (bf16_t*)(wsb + OFF_VTHI);
    bf16_t* vtlog = (bf16_t*)(wsb + OFF_VTLO);
    bf16_t* atth = (bf16_t*)(wsb + OFF_R0);            // att splits reuse R0 (xn dead after zlat GEMM)
    bf16_t* attl = (bf16_t*)(wsb + OFF_R0 + 8 * MB_);
    float*  x1   = (float*)(wsb + OFF_X1);
    float*  cost = (float*)(wsb + OFF_COS);
    float*  sint = (float*)(wsb + OFF_SIN);
    // phase-2 pointers
    float*  xn2  = (float*)(wsb + OFF_R0);             // f32 for gate (att splits dead after Wout GEMM)
    bf16_t* Wr2T = (bf16_t*)(wsb + OFF_R0);            // after gate
    bf16_t* xnb  = (bf16_t*)(wsb + OFF_R1);
    bf16_t* Ws1T = (bf16_t*)(wsb + OFF_R1 + 8 * MB_);
    bf16_t* hbuf = (bf16_t*)(wsb + OFF_R2);
    bf16_t* actb = (bf16_t*)(wsb + OFF_R3);
    float*  eout = (float*)(wsb + OFF_R3 + 8 * MB_);
    bf16_t* Wr1H = (bf16_t*)(wsb + OFF_R4);
    float*  shout = (float*)(wsb + OFF_R4);
    bf16_t* Ws2T = (bf16_t*)(wsb + OFF_WS2T);
    float*  pri  = (float*)(wsb + OFF_PRI);
    int*    seli = (int*)(wsb + OFF_SELI);
    float*  selw = (float*)(wsb + OFF_SELW);
    int*    icnt = (int*)(wsb + OFF_ICNT);
    int*    ipr  = (int*)(wsb + OFF_IPR);

    // --- sublayer 1: attention path (bf16x3 MFMA GEMMs, MFMA flash attention) ---
    rmsnorm_kernel<0><<<T_, 256, 0, stream>>>(x, n1w, nullptr, xnhi, xnlo);
    pack_w_kernel<<<7168, 256, 0, stream>>>(Wq_lat, Wkv_lat, Wq_up, Wrot_q, Wk_up, Wrot_k, Wv_up,
                                            plat, pqc, pkv);
    rope_table_kernel<<<(S_ * 16) / 256, 256, 0, stream>>>(cost, sint);
    packTsplit_kernel<<<dim3(32, 24), 256, 0, stream>>>(plat, plth, pltl, 1024, 768);
    packTsplit_kernel<<<dim3(16, 32), 256, 0, stream>>>(pqc, pqth, pqtl, 512, 1024);
    packTsplit_kernel<<<dim3(8, 64), 256, 0, stream>>>(pkv, pkth, pktl, 256, 2048);
    packTsplit_kernel<<<dim3(32, 32), 256, 0, stream>>>(Wout, woth, wotl, 1024, 1024);
    // zlat = xn @ PLAT : 4096x768x1024, split output
    mfma3_gemm_kernel<false, 1><<<dim3(6, 32), 256, 0, stream>>>(
        xnhi, xnlo, plth, pltl, nullptr, zlhi, zllo, nullptr, 1024, 1024, 768);
    // q = zlat[:, :512] @ PQC : 4096x1024x512, f32 out
    mfma3_gemm_kernel<false, 0><<<dim3(8, 32), 256, 0, stream>>>(
        zlhi, zllo, pqth, pqtl, qb, nullptr, nullptr, nullptr, 512, 768, 1024);
    // k|v = zlat[:, 512:768] @ PKV : 4096x2048x256, f32 out
    mfma3_gemm_kernel<false, 0><<<dim3(16, 32), 256, 0, stream>>>(
        zlhi + 512, zllo + 512, pkth, pktl, kvb, nullptr, nullptr, nullptr, 256, 768, 2048);
    rope_apply_kernel<<<(T_ * H_) / 256, 256, 0, stream>>>(qb, kvb, cost, sint);
    // pre-split K/V to bf16 hi/lo planes (hoists conversion out of the flash loop)
    kpack_kernel<<<(T_ * 1024 / 4) / 256, 256, 0, stream>>>(kvb, khig, klog);
    vtrans_kernel<<<dim3(64, 32, 2), 256, 0, stream>>>(kvb, vthig, vtlog);
    attn_mfma_kernel<<<dim3(512), 256, 0, stream>>>(qb, khig, klog, vthig, vtlog, atth, attl);
    // x1 = att @ Wout + x : 4096x1024x1024
    mfma3_gemm_kernel<true, 0><<<dim3(8, 32), 256, 0, stream>>>(
        atth, attl, woth, wotl, x1, nullptr, nullptr, x, 1024, 1024, 1024);

    // --- sublayer 2: MoE ---
    rmsnorm_kernel<1><<<T_, 256, 0, stream>>>(x1, n2w, xn2, xnb, nullptr);
    hipMemsetAsync(icnt, 0, T_ * sizeof(int), stream);
    gate_kernel<<<T_, 256, 0, stream>>>(xn2, Wgate, ebias, pri);           // fp32 gate
    select_kernel<<<NR_, 1024, 0, stream>>>(pri, seli, selw, icnt, ipr);   // exact top-CAP

    // weight packs (R0 free after gate)
    packT_kernel<<<dim3(32, 32, 7), 256, 0, stream>>>(Wr2, Wr2T, 1024, 1024, 0,
                                                      (long long)1024 * 1024, (long long)1024 * 1024);
    packT_kernel<<<dim3(32, 64, 1), 256, 0, stream>>>(Ws1, Ws1T, 1024, 2048, 0, 0, 0);
    packT_kernel<<<dim3(32, 32, 1), 256, 0, stream>>>(Ws2, Ws2T, 1024, 1024, 0, 0, 0);

    // routed experts (Wr1 halves staged through R4)
    packT_kernel<<<dim3(32, 32, 7), 256, 0, stream>>>(Wr1, Wr1H, 1024, 2048, 0,
                                                      (long long)1024 * 2048, (long long)1024 * 1024);
    mfma_gemm_kernel<true, false, true><<<dim3(8, 5, 7), 256, 0, stream>>>(
        xnb, Wr1H, hbuf, seli, nullptr, CAP_, 1024, 1024, 2048,
        0, (long long)1024 * 1024, (long long)CAP_ * 2048, CAP_);
    packT_kernel<<<dim3(32, 32, 7), 256, 0, stream>>>(Wr1, Wr1H, 1024, 2048, 1024,
                                                      (long long)1024 * 2048, (long long)1024 * 1024);
    mfma_gemm_kernel<true, false, true><<<dim3(8, 5, 7), 256, 0, stream>>>(
        xnb, Wr1H, hbuf + 1024, seli, nullptr, CAP_, 1024, 1024, 2048,
        0, (long long)1024 * 1024, (long long)CAP_ * 2048, CAP_);
    swiglu_kernel<<<(NR_ * CAP_ * 128 + 255) / 256, 256, 0, stream>>>(hbuf, actb, NR_ * CAP_);
    mfma_gemm_kernel<false, true, false><<<dim3(8, 5, 7), 256, 0, stream>>>(
        actb, Wr2T, eout, nullptr, selw, CAP_, 1024, 1024, 1024,
        (long long)CAP_ * 1024, (long long)1024 * 1024, (long long)CAP_ * 1024, CAP_);

    // shared expert (R4 free -> shout)
    mfma_gemm_kernel<false, false, true><<<dim3(16, 32, 1), 256, 0, stream>>>(
        xnb, Ws1T, hbuf, nullptr, nullptr, T_, 1024, 1024, 2048, 0, 0, 0, 0);
    swiglu_kernel<<<(T_ * 128 + 255) / 256, 256, 0, stream>>>(hbuf, actb, T_);
    mfma_gemm_kernel<false, false, false><<<dim3(8, 32, 1), 256, 0, stream>>>(
        actb, Ws2T, shout, nullptr, nullptr, T_, 1024, 1024, 1024, 0, 0, 0, 0);

    // combine
    final_kernel<<<T_, 256, 0, stream>>>(x1, shout, eout, icnt, ipr, out);
}

// Round 4
// 841.814 us; speedup vs baseline: 1.0049x; 1.0049x over previous
//
#include <hip/hip_runtime.h>
#include <cstdint>
#include <cstddef>

// ---------------- static problem config ----------------
#define B_   2
#define S_   2048
#define D_   1024
#define T_   4096          // B*S
#define H_   16
#define HD_  64
#define LQ_  512
#define LKV_ 256
#define FF_  1024
#define NR_  7
#define CAP_ 585

typedef unsigned int   u32;
typedef unsigned long long u64;
typedef __bf16 bf16_t;
typedef __bf16 bf16x8 __attribute__((ext_vector_type(8)));
typedef __bf16 bf16x4 __attribute__((ext_vector_type(4)));
typedef float  f32x4  __attribute__((ext_vector_type(4)));

// ---------------- workspace layout (bytes), regions phase-reused, ~111 MB ----------------
static constexpr size_t MB_ = 1024 * 1024;
static constexpr size_t KB_ = 1024;
// R0 0-16M: xn hi(8M)+lo(8M) -> att hi+lo -> xn2 f32 -> Wr2T bf16 (14.7M)
static constexpr size_t OFF_R0   = 0;
// R1 16-28M: zlat hi(6M)+lo(6M) -> Vthi bf16 8M (attn) -> xnb bf16 8M + Ws1T 4M
static constexpr size_t OFF_R1   = 16 * MB_;
// R2 28-44M: PLAT/PQC/PKV f32 temps (7M) -> q f32 16M -> hbuf bf16 16M
static constexpr size_t OFF_R2   = 28 * MB_;
// R3 44-76M: kv f32 32M -> actb bf16 8M + eout f32 16.8M
static constexpr size_t OFF_R3   = 44 * MB_;
// R4 76-92M: WoutT splits (4M) + packT temps -> Vtlo (8M @ 80M) -> Wr1H bf16 14.7M -> shout f32 16M
static constexpr size_t OFF_R4   = 76 * MB_;
static constexpr size_t OFF_X1   = 92 * MB_;             // Khi/Klo (attn) -> [T][D] f32 x1
static constexpr size_t OFF_PRI  = 108 * MB_;            // [NR][T] f32 (128K)
static constexpr size_t OFF_SELI = OFF_PRI + 128 * KB_;  // [NR][CAP] int
static constexpr size_t OFF_SELW = OFF_SELI + 32 * KB_;  // [NR][CAP] f32
static constexpr size_t OFF_ICNT = OFF_SELW + 32 * KB_;  // [T] int
static constexpr size_t OFF_IPR  = OFF_ICNT + 32 * KB_;  // [T][2] int
static constexpr size_t OFF_COS  = OFF_IPR + 64 * KB_;   // [S][16] f32
static constexpr size_t OFF_SIN  = OFF_COS + 128 * KB_;  // [S][16] f32
static constexpr size_t OFF_WS2T = 109 * MB_;            // Ws2T bf16 2M -> ends 111M
// sub-offsets
static constexpr size_t OFF_PLAT = OFF_R2;               // [1024][768] f32 (3M)
static constexpr size_t OFF_PQC  = OFF_R2 + 3 * MB_;     // [512][1024] f32 (2M)
static constexpr size_t OFF_PKV  = OFF_R2 + 5 * MB_;     // [256][2048] f32 (2M)
// R4 internals: WoutT survives through attn; PLT/PQT/PKT dead after q/kv GEMMs
static constexpr size_t OFF_WOTH = OFF_R4;                    // 76M, 2M (needed after attn)
static constexpr size_t OFF_WOTL = OFF_R4 + 2 * MB_;          // 78M, 2M
static constexpr size_t OFF_PLTH = OFF_R4 + 4 * MB_;          // 80M, 1.5M (dead after zlat GEMM)
static constexpr size_t OFF_PLTL = OFF_R4 + 5632 * KB_;       // 81.5M
static constexpr size_t OFF_PQTH = OFF_R4 + 7 * MB_;          // 83M, 1M (dead after q GEMM)
static constexpr size_t OFF_PQTL = OFF_R4 + 8 * MB_;          // 84M
static constexpr size_t OFF_PKTH = OFF_R4 + 9 * MB_;          // 85M, 1M (dead after kv GEMM)
static constexpr size_t OFF_PKTL = OFF_R4 + 10 * MB_;         // 86M -> ends 87M
// attention bf16 planes (alive only during attn)
static constexpr size_t OFF_VTHI = OFF_R1;                    // 16M, 8M (over dead zlat)
static constexpr size_t OFF_VTLO = OFF_R4 + 4 * MB_;          // 80M, 8M (over dead PLT/PQT/PKT + free)
static constexpr size_t OFF_KHI  = OFF_X1;                    // 92M, 8M (x1 written after attn)
static constexpr size_t OFF_KLO  = OFF_X1 + 8 * MB_;          // 100M, 8M

__device__ __forceinline__ void split2(float v, bf16_t& h, bf16_t& l) {
    h = (bf16_t)v;
    l = (bf16_t)(v - (float)h);
}

// ---------------- RMSNorm: MODE 0 -> emit hi/lo bf16 planes; MODE 1 -> emit f32 + single bf16 ----------------
template <int MODE>
__global__ __launch_bounds__(256) void rmsnorm_kernel(const float* __restrict__ x,
                                                      const float* __restrict__ w,
                                                      float* __restrict__ outf,
                                                      bf16_t* __restrict__ o1,
                                                      bf16_t* __restrict__ o2) {
    int t = blockIdx.x;
    int c = threadIdx.x * 4;
    float4 f = *(const float4*)(x + (size_t)t * D_ + c);
    float ss = f.x * f.x + f.y * f.y + f.z * f.z + f.w * f.w;
#pragma unroll
    for (int off = 32; off > 0; off >>= 1) ss += __shfl_down(ss, off);
    __shared__ float red[4];
    int lane = threadIdx.x & 63, wid = threadIdx.x >> 6;
    if (lane == 0) red[wid] = ss;
    __syncthreads();
    float tot = red[0] + red[1] + red[2] + red[3];
    float inv = 1.f / sqrtf(tot * (1.f / D_) + 1e-6f);
    float4 wv = *(const float4*)(w + c);
    float v[4];
    v[0] = f.x * inv * wv.x; v[1] = f.y * inv * wv.y;
    v[2] = f.z * inv * wv.z; v[3] = f.w * inv * wv.w;
    if (MODE == 0) {
        bf16x4 hv, lv;
#pragma unroll
        for (int j = 0; j < 4; j++) { bf16_t h, l; split2(v[j], h, l); hv[j] = h; lv[j] = l; }
        *(bf16x4*)(o1 + (size_t)t * D_ + c) = hv;
        *(bf16x4*)(o2 + (size_t)t * D_ + c) = lv;
    } else {
        float4 o; o.x = v[0]; o.y = v[1]; o.z = v[2]; o.w = v[3];
        *(float4*)(outf + (size_t)t * D_ + c) = o;
        bf16x4 bv;
#pragma unroll
        for (int j = 0; j < 4; j++) bv[j] = (bf16_t)v[j];
        *(bf16x4*)(o1 + (size_t)t * D_ + c) = bv;
    }
}

// ---------------- pack fp32 attention weights into [K][N] fused layouts ----------------
__global__ __launch_bounds__(256) void pack_w_kernel(const float* __restrict__ Wq_lat, const float* __restrict__ Wkv_lat,
                                                     const float* __restrict__ Wq_up, const float* __restrict__ Wrot_q,
                                                     const float* __restrict__ Wk_up, const float* __restrict__ Wrot_k,
                                                     const float* __restrict__ Wv_up,
                                                     float* __restrict__ PLAT, float* __restrict__ PQC,
                                                     float* __restrict__ PKV) {
    int i = blockIdx.x * 256 + threadIdx.x;
    const int NL = 1024 * 768;
    const int NQ = 512 * 1024;
    if (i < NL) {
        int k = i / 768, c = i - k * 768;
        PLAT[i] = (c < 512) ? Wq_lat[k * 512 + c] : Wkv_lat[k * 256 + (c - 512)];
    } else if (i < NL + NQ) {
        int i2 = i - NL;
        int k = i2 >> 10, c = i2 & 1023, h = c >> 6, j = c & 63;
        PQC[i2] = (j < 32) ? Wq_up[k * 1024 + c] : Wrot_q[k * 1024 + h * 64 + (j - 32)];
    } else {
        int i3 = i - NL - NQ;
        int k = i3 >> 11, c = i3 & 2047;
        if (c < 1024) {
            int h = c >> 6, j = c & 63;
            PKV[i3] = (j < 32) ? Wk_up[k * 1024 + c] : Wrot_k[k * 1024 + h * 64 + (j - 32)];
        } else {
            PKV[i3] = Wv_up[k * 1024 + (c - 1024)];
        }
    }
}

// ---------------- transpose + split: in [K][N] f32 -> outhi/outlo [N][K] bf16 ----------------
__global__ __launch_bounds__(256) void packTsplit_kernel(const float* __restrict__ in,
                                                         bf16_t* __restrict__ outhi, bf16_t* __restrict__ outlo,
                                                         int K, int N) {
    __shared__ float tile[32][33];
    const int k0 = blockIdx.x * 32, n0 = blockIdx.y * 32;
    const int rr = threadIdx.x >> 5, cc = threadIdx.x & 31;
#pragma unroll
    for (int it = 0; it < 4; it++) {
        int k = k0 + rr + it * 8;
        tile[rr + it * 8][cc] = in[(size_t)k * N + n0 + cc];
    }
    __syncthreads();
#pragma unroll
    for (int it = 0; it < 4; it++) {
        int nl = n0 + rr + it * 8;
        float v = tile[cc][rr + it * 8];
        bf16_t h, l; split2(v, h, l);
        outhi[(size_t)nl * K + k0 + cc] = h;
        outlo[(size_t)nl * K + k0 + cc] = l;
    }
}

// ---------------- rope tables ----------------
__global__ __launch_bounds__(256) void rope_table_kernel(float* __restrict__ ct, float* __restrict__ st) {
    int i = blockIdx.x * 256 + threadIdx.x;   // S_*16
    if (i >= S_ * 16) return;
    int s = i >> 4, j = i & 15;
    float inv = 1.f / powf(10000.f, (float)j * (1.f / 16.f));
    float fr = (float)s * inv;
    ct[i] = cosf(fr);
    st[i] = sinf(fr);
}

// apply rope in place: q [T][1024], k = cols 0..1023 of kv [T][2048]; rot dims = h*64+32..63
__global__ __launch_bounds__(256) void rope_apply_kernel(float* __restrict__ q, float* __restrict__ kv,
                                                         const float* __restrict__ ct, const float* __restrict__ st) {
    int gid = blockIdx.x * 256 + threadIdx.x;
    if (gid >= T_ * H_) return;
    int t = gid >> 4, h = gid & 15;
    int s = t & (S_ - 1);
    float c[16], sn[16];
#pragma unroll
    for (int j = 0; j < 16; j += 4) {
        *(float4*)&c[j]  = *(const float4*)(ct + s * 16 + j);
        *(float4*)&sn[j] = *(const float4*)(st + s * 16 + j);
    }
#pragma unroll
    for (int a2 = 0; a2 < 2; a2++) {
        float* p = a2 ? (kv + (size_t)t * 2048 + h * 64 + 32)
                      : (q  + (size_t)t * 1024 + h * 64 + 32);
        float r[32], o2[32];
#pragma unroll
        for (int j2 = 0; j2 < 32; j2 += 4) *(float4*)&r[j2] = *(const float4*)(p + j2);
#pragma unroll
        for (int i = 0; i < 16; i++) {
            o2[i]      = r[i] * c[i] - r[i + 16] * sn[i];
            o2[i + 16] = r[i + 16] * c[i] + r[i] * sn[i];
        }
#pragma unroll
        for (int j2 = 0; j2 < 32; j2 += 4) *(float4*)(p + j2) = *(const float4*)&o2[j2];
    }
}

// ---------------- K planes: kv f32 [T][2048] cols h*64+d -> Khi/Klo [(b*16+h)][s][64] bf16 ----------------
__global__ __launch_bounds__(256) void kpack_kernel(const float* __restrict__ kv,
                                                    bf16_t* __restrict__ Khi, bf16_t* __restrict__ Klo) {
    int i = blockIdx.x * 256 + threadIdx.x;      // T_*1024/4 threads
    int idx = i * 4;                             // output element index
    int d = idx & 63;
    int s = (idx >> 6) & (S_ - 1);
    int bh = idx >> 17;                          // b*16+h  (2^17 = S_*64)
    int b = bh >> 4, h = bh & 15;
    size_t src = ((size_t)(b * S_ + s)) * 2048 + h * 64 + d;
    float4 v = *(const float4*)(kv + src);
    bf16x4 hv, lv; bf16_t hh, ll;
    split2(v.x, hh, ll); hv[0] = hh; lv[0] = ll;
    split2(v.y, hh, ll); hv[1] = hh; lv[1] = ll;
    split2(v.z, hh, ll); hv[2] = hh; lv[2] = ll;
    split2(v.w, hh, ll); hv[3] = hh; lv[3] = ll;
    *(bf16x4*)(Khi + idx) = hv;
    *(bf16x4*)(Klo + idx) = lv;
}

// ---------------- V planes: kv f32 [b][s][1024 + hd] -> Vthi/Vtlo [b*1024+hd][S] bf16 (transposed) ----------------
__global__ __launch_bounds__(256) void vtrans_kernel(const float* __restrict__ kv,
                                                     bf16_t* __restrict__ Vthi, bf16_t* __restrict__ Vtlo) {
    __shared__ float tile[32][33];
    const int bz = blockIdx.z;
    const int s0 = blockIdx.x * 32, hd0 = blockIdx.y * 32;
    const int rr = threadIdx.x >> 5, cc = threadIdx.x & 31;
    const float* inb = kv + (size_t)bz * S_ * 2048 + 1024;
#pragma unroll
    for (int it = 0; it < 4; it++) {
        int s = s0 + rr + it * 8;
        tile[rr + it * 8][cc] = inb[(size_t)s * 2048 + hd0 + cc];
    }
    __syncthreads();
    bf16_t* oh = Vthi + (size_t)bz * 1024 * S_;
    bf16_t* ol = Vtlo + (size_t)bz * 1024 * S_;
#pragma unroll
    for (int it = 0; it < 4; it++) {
        int hd = hd0 + rr + it * 8;
        float v = tile[cc][rr + it * 8];
        bf16_t hh, ll; split2(v, hh, ll);
        oh[(size_t)hd * S_ + s0 + cc] = hh;
        ol[(size_t)hd * S_ + s0 + cc] = ll;
    }
}

// ---------------- bf16x3 MFMA GEMM (near-fp32): C = (Ah+Al)@(Bh+Bl)^T (+resid) ----------------
// M fixed = 4096 (full rows). EMIT: 0 = f32 out, 1 = hi/lo split out.
template <bool RESID, int EMIT>
__global__ __launch_bounds__(256) void mfma3_gemm_kernel(const bf16_t* __restrict__ Ah, const bf16_t* __restrict__ Al,
                                                         const bf16_t* __restrict__ Bh, const bf16_t* __restrict__ Bl,
                                                         float* __restrict__ Cf,
                                                         bf16_t* __restrict__ Chi, bf16_t* __restrict__ Clo,
                                                         const float* __restrict__ resid,
                                                         int K, int lda, int ldc) {
    __shared__ __align__(16) bf16_t Ash[128 * 32];
    __shared__ __align__(16) bf16_t Asl[128 * 32];
    __shared__ __align__(16) bf16_t Bsh[128 * 32];
    __shared__ __align__(16) bf16_t Bsl[128 * 32];
    const int tid = threadIdx.x;
    const int lane = tid & 63, w = tid >> 6;
    const int wm = (w & 1) * 64, wn = (w >> 1) * 64;
    const int m0 = blockIdx.y * 128, n0 = blockIdx.x * 128;

    f32x4 acc[4][4];
#pragma unroll
    for (int mi = 0; mi < 4; mi++)
#pragma unroll
        for (int ni = 0; ni < 4; ni++) { f32x4 zz = {0.f, 0.f, 0.f, 0.f}; acc[mi][ni] = zz; }

    const int mrow = lane & 15, q = lane >> 4;
    for (int k0 = 0; k0 < K; k0 += 32) {
#pragma unroll
        for (int i = 0; i < 2; i++) {
            int chunk = tid + i * 256;
            int row = chunk >> 2, koff = (chunk & 3) * 8;
            size_t aoff = (size_t)(m0 + row) * lda + k0 + koff;
            size_t boff = (size_t)(n0 + row) * K + k0 + koff;
            *(uint4*)(Ash + row * 32 + koff) = *(const uint4*)(Ah + aoff);
            *(uint4*)(Asl + row * 32 + koff) = *(const uint4*)(Al + aoff);
            *(uint4*)(Bsh + row * 32 + koff) = *(const uint4*)(Bh + boff);
            *(uint4*)(Bsl + row * 32 + koff) = *(const uint4*)(Bl + boff);
        }
        __syncthreads();
        bf16x8 ah[4], al[4], bh[4], bl[4];
#pragma unroll
        for (int mi = 0; mi < 4; mi++) {
            ah[mi] = *(const bf16x8*)(Ash + (wm + mi * 16 + mrow) * 32 + q * 8);
            al[mi] = *(const bf16x8*)(Asl + (wm + mi * 16 + mrow) * 32 + q * 8);
        }
#pragma unroll
        for (int ni = 0; ni < 4; ni++) {
            bh[ni] = *(const bf16x8*)(Bsh + (wn + ni * 16 + mrow) * 32 + q * 8);
            bl[ni] = *(const bf16x8*)(Bsl + (wn + ni * 16 + mrow) * 32 + q * 8);
        }
#pragma unroll
        for (int mi = 0; mi < 4; mi++)
#pragma unroll
            for (int ni = 0; ni < 4; ni++) {
                acc[mi][ni] = __builtin_amdgcn_mfma_f32_16x16x32_bf16(al[mi], bh[ni], acc[mi][ni], 0, 0, 0);
                acc[mi][ni] = __builtin_amdgcn_mfma_f32_16x16x32_bf16(ah[mi], bl[ni], acc[mi][ni], 0, 0, 0);
                acc[mi][ni] = __builtin_amdgcn_mfma_f32_16x16x32_bf16(ah[mi], bh[ni], acc[mi][ni], 0, 0, 0);
            }
        __syncthreads();
    }
    // epilogue: C/D layout col = lane&15, row = (lane>>4)*4 + v
#pragma unroll
    for (int mi = 0; mi < 4; mi++) {
        int rbase = m0 + wm + mi * 16 + q * 4;
#pragma unroll
        for (int v = 0; v < 4; v++) {
            int r = rbase + v;
#pragma unroll
            for (int ni = 0; ni < 4; ni++) {
                int c = n0 + wn + ni * 16 + mrow;
                float val = acc[mi][ni][v];
                if (RESID) val += resid[(size_t)r * ldc + c];
                if (EMIT == 0) {
                    Cf[(size_t)r * ldc + c] = val;
                } else {
                    bf16_t h, l; split2(val, h, l);
                    Chi[(size_t)r * ldc + c] = h;
                    Clo[(size_t)r * ldc + c] = l;
                }
            }
        }
    }
}

// ---------------- MFMA flash attention (causal), bf16x3 QK / bf16x2 PV, K/V pre-split planes ----------------
// grid: 512 = 16 q-tiles (128 rows) x 32 bh, LPT heavy-first. 4 waves, wave w owns q rows [w*32, w*32+32).
// T14 async-STAGE: prefetch next tile's K/V planes to regs during compute; write LDS after barrier.
// LDS: Kh/Kl [64][64] XOR-swizzled, Vth/Vtl [64][72] transposed+padded, Ph [128][64] XOR-swizzled. 50 KB.
__global__ __launch_bounds__(256) void attn_mfma_kernel(const float* __restrict__ Q,
                                                        const bf16_t* __restrict__ Khig, const bf16_t* __restrict__ Klog,
                                                        const bf16_t* __restrict__ Vthig, const bf16_t* __restrict__ Vtlog,
                                                        bf16_t* __restrict__ Ohi, bf16_t* __restrict__ Olo) {
    __shared__ __align__(16) bf16_t Kh[64][64];
    __shared__ __align__(16) bf16_t Kl[64][64];
    __shared__ __align__(16) bf16_t Vth[64][72];   // Vth[d][k] (transposed)
    __shared__ __align__(16) bf16_t Vtl[64][72];
    __shared__ __align__(16) bf16_t Ph[128][64];   // P rounded to bf16, XOR-swizzled cols

    const int tid = threadIdx.x;
    const int lane = tid & 63, w = tid >> 6;
    const int mrow = lane & 15, qq = lane >> 4;
    const int jb = blockIdx.x;
    const int qt = 15 - (jb >> 5);                 // LPT: heaviest q-tiles first
    const int bh = jb & 31, b = bh >> 4, h = bh & 15;
    const int q0 = qt * 128;
    const float*  Qb  = Q + (size_t)b * S_ * 1024 + h * 64;
    const bf16_t* Khb = Khig + (size_t)bh * S_ * 64;
    const bf16_t* Klb = Klog + (size_t)bh * S_ * 64;
    const bf16_t* Vhb = Vthig + (size_t)(b * 1024 + h * 64) * S_;
    const bf16_t* Vlb = Vtlog + (size_t)(b * 1024 + h * 64) * S_;

    // per-thread staging geometry (2 chunks x 4 planes = 8 uint4)
    const int sc0 = tid, sc1 = tid + 256;
    const int sr0 = sc0 >> 3, sc80 = (sc0 & 7) * 8;
    const int sr1 = sc1 >> 3, sc81 = (sc1 & 7) * 8;
    const int ssw0 = sc80 ^ ((sr0 & 7) << 3);
    const int ssw1 = sc81 ^ ((sr1 & 7) << 3);

    uint4 rKh0, rKh1, rKl0, rKl1, rVh0, rVh1, rVl0, rVl1;

    // ---- Q fragments in registers, pre-scaled by 1/sqrt(HD)=0.125 (exact), hi/lo split ----
    bf16x8 qh[2][2], ql[2][2];                     // [mi][ks]
#pragma unroll
    for (int mi = 0; mi < 2; mi++) {
        int r = q0 + w * 32 + mi * 16 + mrow;
#pragma unroll
        for (int ks = 0; ks < 2; ks++) {
            const float* p = Qb + (size_t)r * 1024 + ks * 32 + qq * 8;
            float4 a = *(const float4*)p;
            float4 b2 = *(const float4*)(p + 4);
            float vals[8] = {a.x, a.y, a.z, a.w, b2.x, b2.y, b2.z, b2.w};
#pragma unroll
            for (int j = 0; j < 8; j++) {
                bf16_t hh, ll; split2(vals[j] * 0.125f, hh, ll);
                qh[mi][ks][j] = hh; ql[mi][ks][j] = ll;
            }
        }
    }

    f32x4 acc_o[2][4];
    float m_r[2][4], l_r[2][4];
#pragma unroll
    for (int mi = 0; mi < 2; mi++) {
#pragma unroll
        for (int ni = 0; ni < 4; ni++) { f32x4 zz = {0.f, 0.f, 0.f, 0.f}; acc_o[mi][ni] = zz; }
#pragma unroll
        for (int v = 0; v < 4; v++) { m_r[mi][v] = -1e30f; l_r[mi][v] = 0.f; }
    }

    const int ktmax = 2 * qt + 1;

    // prologue: load tile 0 to regs, write LDS
    {
        const int k0 = 0;
        rKh0 = *(const uint4*)(Khb + (size_t)(k0 + sr0) * 64 + sc80);
        rKl0 = *(const uint4*)(Klb + (size_t)(k0 + sr0) * 64 + sc80);
        rVh0 = *(const uint4*)(Vhb + (size_t)sr0 * S_ + k0 + sc80);
        rVl0 = *(const uint4*)(Vlb + (size_t)sr0 * S_ + k0 + sc80);
        rKh1 = *(const uint4*)(Khb + (size_t)(k0 + sr1) * 64 + sc81);
        rKl1 = *(const uint4*)(Klb + (size_t)(k0 + sr1) * 64 + sc81);
        rVh1 = *(const uint4*)(Vhb + (size_t)sr1 * S_ + k0 + sc81);
        rVl1 = *(const uint4*)(Vlb + (size_t)sr1 * S_ + k0 + sc81);
        *(uint4*)&Kh[sr0][ssw0] = rKh0;  *(uint4*)&Kl[sr0][ssw0] = rKl0;
        *(uint4*)&Vth[sr0][sc80] = rVh0; *(uint4*)&Vtl[sr0][sc80] = rVl0;
        *(uint4*)&Kh[sr1][ssw1] = rKh1;  *(uint4*)&Kl[sr1][ssw1] = rKl1;
        *(uint4*)&Vth[sr1][sc81] = rVh1; *(uint4*)&Vtl[sr1][sc81] = rVl1;
        __syncthreads();
    }

    for (int kt = 0; kt <= ktmax; kt++) {
        const int k0 = kt * 64;
        // ---- prefetch NEXT tile's K/V planes into registers (overlaps compute below) ----
        if (kt < ktmax) {
            const int kn = k0 + 64;
            rKh0 = *(const uint4*)(Khb + (size_t)(kn + sr0) * 64 + sc80);
            rKl0 = *(const uint4*)(Klb + (size_t)(kn + sr0) * 64 + sc80);
            rVh0 = *(const uint4*)(Vhb + (size_t)sr0 * S_ + kn + sc80);
            rVl0 = *(const uint4*)(Vlb + (size_t)sr0 * S_ + kn + sc80);
            rKh1 = *(const uint4*)(Khb + (size_t)(kn + sr1) * 64 + sc81);
            rKl1 = *(const uint4*)(Klb + (size_t)(kn + sr1) * 64 + sc81);
            rVh1 = *(const uint4*)(Vhb + (size_t)sr1 * S_ + kn + sc81);
            rVl1 = *(const uint4*)(Vlb + (size_t)sr1 * S_ + kn + sc81);
        }

        if (k0 <= q0 + w * 32 + 31) {   // wave-uniform: skip fully-masked half-tiles
            // ---- S = Q @ K^T (bf16x3) ----
            f32x4 acc_s[2][4];
#pragma unroll
            for (int mi = 0; mi < 2; mi++)
#pragma unroll
                for (int ni = 0; ni < 4; ni++) { f32x4 zz = {0.f, 0.f, 0.f, 0.f}; acc_s[mi][ni] = zz; }
#pragma unroll
            for (int ks = 0; ks < 2; ks++) {
                const int c0 = ks * 32 + qq * 8;
                bf16x8 bhf[4], blf[4];
#pragma unroll
                for (int ni = 0; ni < 4; ni++) {
                    int row = ni * 16 + mrow;
                    int cs = c0 ^ ((row & 7) << 3);
                    bhf[ni] = *(const bf16x8*)&Kh[row][cs];
                    blf[ni] = *(const bf16x8*)&Kl[row][cs];
                }
#pragma unroll
                for (int mi = 0; mi < 2; mi++)
#pragma unroll
                    for (int ni = 0; ni < 4; ni++) {
                        acc_s[mi][ni] = __builtin_amdgcn_mfma_f32_16x16x32_bf16(ql[mi][ks], bhf[ni], acc_s[mi][ni], 0, 0, 0);
                        acc_s[mi][ni] = __builtin_amdgcn_mfma_f32_16x16x32_bf16(qh[mi][ks], blf[ni], acc_s[mi][ni], 0, 0, 0);
                        acc_s[mi][ni] = __builtin_amdgcn_mfma_f32_16x16x32_bf16(qh[mi][ks], bhf[ni], acc_s[mi][ni], 0, 0, 0);
                    }
            }
            // ---- online softmax (rows: qq*4+v within 16-block; cols: ni*16+mrow) ----
            const bool diag = (kt >= 2 * qt);
#pragma unroll
            for (int mi = 0; mi < 2; mi++) {
#pragma unroll
                for (int v = 0; v < 4; v++) {
                    int rq = q0 + w * 32 + mi * 16 + qq * 4 + v;
                    float sv[4];
                    float rmax = -1e30f;
#pragma unroll
                    for (int ni = 0; ni < 4; ni++) {
                        float s = acc_s[mi][ni][v];
                        if (diag && (k0 + ni * 16 + mrow) > rq) s = -1e30f;
                        sv[ni] = s;
                        rmax = fmaxf(rmax, s);
                    }
#pragma unroll
                    for (int off = 1; off < 16; off <<= 1) rmax = fmaxf(rmax, __shfl_xor(rmax, off));
                    float mo = m_r[mi][v];
                    float mn = fmaxf(mo, rmax);
                    float al = __expf(mo - mn);
                    m_r[mi][v] = mn;
                    int rl = w * 32 + mi * 16 + qq * 4 + v;
                    int t7 = (rl & 7) << 3;
                    float rs = 0.f;
#pragma unroll
                    for (int ni = 0; ni < 4; ni++) {
                        float p = __expf(sv[ni] - mn);
                        bf16_t ph = (bf16_t)p;
                        Ph[rl][(ni * 16 + mrow) ^ t7] = ph;
                        rs += (float)ph;            // denominator from same rounded P -> consistent weights
                    }
#pragma unroll
                    for (int off = 1; off < 16; off <<= 1) rs += __shfl_xor(rs, off);
                    l_r[mi][v] = l_r[mi][v] * al + rs;
#pragma unroll
                    for (int ni = 0; ni < 4; ni++) acc_o[mi][ni][v] *= al;
                }
            }
            // ---- O += P @ V (bf16x2: P@Vl + P@Vh). P rows read by owning wave only. ----
#pragma unroll
            for (int ks = 0; ks < 2; ks++) {
                const int rc = ks * 32 + qq * 8;
                bf16x8 pah[2], vhf[4], vlf[4];
#pragma unroll
                for (int mi = 0; mi < 2; mi++) {
                    int rowp = w * 32 + mi * 16 + mrow;
                    int cp = rc ^ ((rowp & 7) << 3);
                    pah[mi] = *(const bf16x8*)&Ph[rowp][cp];
                }
#pragma unroll
                for (int ni = 0; ni < 4; ni++) {
                    int c = ni * 16 + mrow;
                    vhf[ni] = *(const bf16x8*)&Vth[c][rc];
                    vlf[ni] = *(const bf16x8*)&Vtl[c][rc];
                }
#pragma unroll
                for (int mi = 0; mi < 2; mi++)
#pragma unroll
                    for (int ni = 0; ni < 4; ni++) {
                        acc_o[mi][ni] = __builtin_amdgcn_mfma_f32_16x16x32_bf16(pah[mi], vlf[ni], acc_o[mi][ni], 0, 0, 0);
                        acc_o[mi][ni] = __builtin_amdgcn_mfma_f32_16x16x32_bf16(pah[mi], vhf[ni], acc_o[mi][ni], 0, 0, 0);
                    }
            }
        }
        __syncthreads();                 // all waves done reading LDS for tile kt
        if (kt < ktmax) {
            *(uint4*)&Kh[sr0][ssw0] = rKh0;  *(uint4*)&Kl[sr0][ssw0] = rKl0;
            *(uint4*)&Vth[sr0][sc80] = rVh0; *(uint4*)&Vtl[sr0][sc80] = rVl0;
            *(uint4*)&Kh[sr1][ssw1] = rKh1;  *(uint4*)&Kl[sr1][ssw1] = rKl1;
            *(uint4*)&Vth[sr1][sc81] = rVh1; *(uint4*)&Vtl[sr1][sc81] = rVl1;
            __syncthreads();             // LDS ready for tile kt+1
        }
    }
    // ---- epilogue: normalize, split hi/lo, store ----
#pragma unroll
    for (int mi = 0; mi < 2; mi++) {
#pragma unroll
        for (int v = 0; v < 4; v++) {
            int rq = q0 + w * 32 + mi * 16 + qq * 4 + v;
            float inv = 1.f / l_r[mi][v];
            size_t base = (size_t)(b * S_ + rq) * 1024 + h * 64;
#pragma unroll
            for (int ni = 0; ni < 4; ni++) {
                float val = acc_o[mi][ni][v] * inv;
                bf16_t hh, ll; split2(val, hh, ll);
                Ohi[base + ni * 16 + mrow] = hh;
                Olo[base + ni * 16 + mrow] = ll;
            }
        }
    }
}

// ---------------- gate: affinities + top-2 membership -> priority [NR][T] ----------------
__global__ __launch_bounds__(256) void gate_kernel(const float* __restrict__ xn2, const float* __restrict__ Wg,
                                                   const float* __restrict__ bias, float* __restrict__ pri) {
    __shared__ float red[256][8];
    int t = blockIdx.x, tid = threadIdx.x;
    float acc[7] = {0.f, 0.f, 0.f, 0.f, 0.f, 0.f, 0.f};
    for (int d = tid; d < D_; d += 256) {
        float xv = xn2[(size_t)t * D_ + d];
        const float* wr = Wg + d * 7;
#pragma unroll
        for (int e = 0; e < 7; e++) acc[e] = fmaf(xv, wr[e], acc[e]);
    }
#pragma unroll
    for (int e = 0; e < 7; e++) red[tid][e] = acc[e];
    __syncthreads();
    for (int s2 = 128; s2 > 0; s2 >>= 1) {
        if (tid < s2) {
#pragma unroll
            for (int e = 0; e < 7; e++) red[tid][e] += red[tid + s2][e];
        }
        __syncthreads();
    }
    if (tid == 0) {
        float a[7];
#pragma unroll
        for (int e = 0; e < 7; e++) a[e] = 1.f / (1.f + expf(-(red[0][e] + bias[e])));
        int e1 = 0;
#pragma unroll
        for (int e = 1; e < 7; e++) if (a[e] > a[e1]) e1 = e;     // strict > : lowest-index tiebreak
        int e2 = -1;
#pragma unroll
        for (int e = 0; e < 7; e++) if (e != e1 && (e2 < 0 || a[e] > a[e2])) e2 = e;
#pragma unroll
        for (int e = 0; e < 7; e++) pri[(size_t)e * T_ + t] = (e == e1 || e == e2) ? a[e] : -1.f;
    }
}

// ---------------- exact top-585 via 32-step binary threshold search (order-free slots) ----------------
__global__ __launch_bounds__(1024) void select_kernel(const float* __restrict__ pri, int* __restrict__ sel_idx,
                                                      float* __restrict__ sel_w, int* __restrict__ inv_cnt,
                                                      int* __restrict__ inv_pair) {
    __shared__ u32 keys[T_];        // 16 KB: float bits (monotone for positive floats); 0 = invalid
    __shared__ int redc[16];
    __shared__ int bcast;
    __shared__ int ctr;
    const int e = blockIdx.x, tid = threadIdx.x;
    const int lane = tid & 63, wid = tid >> 6;
#pragma unroll
    for (int i = 0; i < 4; i++) {
        int idx = tid + i * 1024;
        float p = pri[(size_t)e * T_ + idx];
        keys[idx] = (p > 0.f) ? __float_as_uint(p) : 0u;
    }
    if (tid == 0) ctr = 0;
    __syncthreads();

    u32 myk[4];
#pragma unroll
    for (int i = 0; i < 4; i++) myk[i] = keys[tid + i * 1024];

    // binary search: p = max t with count(keys >= t) >= CAP  (= CAP-th largest key, or 0 if < CAP valid)
    u32 p = 0;
    for (int b = 31; b >= 0; b--) {
        u32 t = p | (1u << b);
        int cnt = 0;
#pragma unroll
        for (int i = 0; i < 4; i++) cnt += (myk[i] >= t) ? 1 : 0;
#pragma unroll
        for (int off = 32; off > 0; off >>= 1) cnt += __shfl_down(cnt, off);
        if (lane == 0) redc[wid] = cnt;
        __syncthreads();
        if (tid == 0) {
            int tot = 0;
#pragma unroll
            for (int k2 = 0; k2 < 16; k2++) tot += redc[k2];
            bcast = tot;
        }
        __syncthreads();
        if (bcast >= CAP_) p = t;
        __syncthreads();
    }
    // count strictly greater
    {
        int cnt = 0;
#pragma unroll
        for (int i = 0; i < 4; i++) cnt += (myk[i] > p) ? 1 : 0;
#pragma unroll
        for (int off = 32; off > 0; off >>= 1) cnt += __shfl_down(cnt, off);
        if (lane == 0) redc[wid] = cnt;
        __syncthreads();
        if (tid == 0) {
            int tot = 0;
#pragma unroll
            for (int k2 = 0; k2 < 16; k2++) tot += redc[k2];
            bcast = tot;
        }
        __syncthreads();
    }
    int cntGT = bcast;
    int quota = CAP_ - cntGT;   // slots left for keys == p (>=1 when p>0)

    // assignment: kept = (k > p) or (k == p, p>0, index-rank < quota)
#pragma unroll
    for (int i = 0; i < 4; i++) {
        int idx = tid + i * 1024;
        u32 k = myk[i];
        bool kept = false;
        if (k > p) kept = true;
        else if (k == p && p != 0u) {
            int rank = 0;
            for (int j = 0; j < idx; j++) rank += (keys[j] == p) ? 1 : 0;
            kept = (rank < quota);
        }
        if (kept) {
            int s = atomicAdd(&ctr, 1);
            sel_idx[e * CAP_ + s] = idx;
            sel_w[e * CAP_ + s] = __uint_as_float(k);
            int pos = atomicAdd(&inv_cnt[idx], 1);
            inv_pair[idx * 2 + pos] = e * CAP_ + s;
        }
    }
    __syncthreads();
    for (int s = ctr + tid; s < CAP_; s += 1024) {  // unfilled slots -> token 0, weight 0
        sel_idx[e * CAP_ + s] = 0;
        sel_w[e * CAP_ + s] = 0.f;
    }
}

// ---------------- transpose + convert: out[z][n][k] = (bf16) in[z][k][nbase+n] ----------------
__global__ __launch_bounds__(256) void packT_kernel(const float* __restrict__ in, bf16_t* __restrict__ out,
                                                    int K, int N, int nbase,
                                                    long long inStride, long long outStride) {
    __shared__ float tile[32][33];
    const int z = blockIdx.z;
    const int k0 = blockIdx.x * 32, n0 = blockIdx.y * 32;
    const int rr = threadIdx.x >> 5, cc = threadIdx.x & 31;
    const float* inz = in + (size_t)z * inStride;
#pragma unroll
    for (int it = 0; it < 4; it++) {
        int k = k0 + rr + it * 8;
        tile[rr + it * 8][cc] = inz[(size_t)k * N + nbase + n0 + cc];
    }
    __syncthreads();
    bf16_t* outz = out + (size_t)z * outStride;
#pragma unroll
    for (int it = 0; it < 4; it++) {
        int nl = n0 + rr + it * 8;
        outz[(size_t)nl * K + k0 + cc] = (bf16_t)tile[cc][rr + it * 8];
    }
}

// ---------------- bf16 MFMA GEMM (single precision pass, experts): C = gather(A) @ Bt^T (*scale) ----------------
template <bool GATHER, bool SCALE, bool OUTBF16>
__global__ __launch_bounds__(256) void mfma_gemm_kernel(const bf16_t* __restrict__ A, const bf16_t* __restrict__ Bt,
                                                        void* __restrict__ Cv,
                                                        const int* __restrict__ gidx, const float* __restrict__ scale,
                                                        int M, int K, int lda, int ldc,
                                                        long long strideA, long long strideBt, long long strideC,
                                                        int gstride) {
    __shared__ __align__(16) bf16_t As[128 * 32];
    __shared__ __align__(16) bf16_t Bs[128 * 32];
    const int tid = threadIdx.x;
    const int lane = tid & 63, w = tid >> 6;
    const int wm = (w & 1) * 64, wn = (w >> 1) * 64;
    const int z = blockIdx.z;
    const int m0 = blockIdx.y * 128, n0 = blockIdx.x * 128;
    const bf16_t* Az = A + (GATHER ? 0 : (size_t)z * strideA);
    const bf16_t* Bz = Bt + (size_t)z * strideBt;

    int arow[2];
#pragma unroll
    for (int i = 0; i < 2; i++) {
        int chunk = tid + i * 256;
        int r = m0 + (chunk >> 2);
        if (r > M - 1) r = M - 1;
        arow[i] = GATHER ? gidx[z * gstride + r] : r;
    }

    f32x4 acc[4][4];
#pragma unroll
    for (int mi = 0; mi < 4; mi++)
#pragma unroll
        for (int ni = 0; ni < 4; ni++) { f32x4 zz = {0.f, 0.f, 0.f, 0.f}; acc[mi][ni] = zz; }

    const int mrow = lane & 15, q = lane >> 4;
    for (int k0 = 0; k0 < K; k0 += 32) {
#pragma unroll
        for (int i = 0; i < 2; i++) {
            int chunk = tid + i * 256;
            int row = chunk >> 2, koff = (chunk & 3) * 8;
            *(uint4*)(As + row * 32 + koff) = *(const uint4*)(Az + (size_t)arow[i] * lda + k0 + koff);
            *(uint4*)(Bs + row * 32 + koff) = *(const uint4*)(Bz + (size_t)(n0 + row) * K + k0 + koff);
        }
        __syncthreads();
        bf16x8 af[4], bfr[4];
#pragma unroll
        for (int mi = 0; mi < 4; mi++)
            af[mi] = *(const bf16x8*)(As + (wm + mi * 16 + mrow) * 32 + q * 8);
#pragma unroll
        for (int ni = 0; ni < 4; ni++)
            bfr[ni] = *(const bf16x8*)(Bs + (wn + ni * 16 + mrow) * 32 + q * 8);
#pragma unroll
        for (int mi = 0; mi < 4; mi++)
#pragma unroll
            for (int ni = 0; ni < 4; ni++)
                acc[mi][ni] = __builtin_amdgcn_mfma_f32_16x16x32_bf16(af[mi], bfr[ni], acc[mi][ni], 0, 0, 0);
        __syncthreads();
    }
#pragma unroll
    for (int mi = 0; mi < 4; mi++) {
        int rbase = m0 + wm + mi * 16 + q * 4;
#pragma unroll
        for (int v = 0; v < 4; v++) {
            int r = rbase + v;
            if (r < M) {
                float sc = SCALE ? scale[z * gstride + r] : 1.f;
#pragma unroll
                for (int ni = 0; ni < 4; ni++) {
                    int c = n0 + wn + ni * 16 + mrow;
                    float val = acc[mi][ni][v];
                    if (SCALE) val *= sc;
                    size_t off = (size_t)z * strideC + (size_t)r * ldc + c;
                    if (OUTBF16) ((bf16_t*)Cv)[off] = (bf16_t)val;
                    else         ((float*)Cv)[off] = val;
                }
            }
        }
    }
}

// ---------------- SwiGLU elementwise ----------------
__global__ __launch_bounds__(256) void swiglu_kernel(const bf16_t* __restrict__ h, bf16_t* __restrict__ act,
                                                     int rows) {
    int i8 = blockIdx.x * 256 + threadIdx.x;
    int total = rows * 128;
    if (i8 >= total) return;
    int r = i8 >> 7, f = (i8 & 127) * 8;
    bf16x8 h1 = *(const bf16x8*)(h + (size_t)r * 2048 + f);
    bf16x8 h2 = *(const bf16x8*)(h + (size_t)r * 2048 + 1024 + f);
    bf16x8 o;
#pragma unroll
    for (int j = 0; j < 8; j++) {
        float a = (float)h1[j], g = (float)h2[j];
        o[j] = (bf16_t)(a * g / (1.f + __expf(-g)));
    }
    *(bf16x8*)(act + (size_t)r * 1024 + f) = o;
}

// ---------------- final combine: out = x1 + shared + sum routed ----------------
__global__ __launch_bounds__(256) void final_kernel(const float* __restrict__ x1, const float* __restrict__ sh,
                                                    const float* __restrict__ eout, const int* __restrict__ icnt,
                                                    const int* __restrict__ ipair, float* __restrict__ out) {
    int t = blockIdx.x, c = threadIdx.x * 4;
    float4 v = *(const float4*)(x1 + (size_t)t * D_ + c);
    float4 s2 = *(const float4*)(sh + (size_t)t * D_ + c);
    v.x += s2.x; v.y += s2.y; v.z += s2.z; v.w += s2.w;
    int n = icnt[t];
    for (int p = 0; p < n; p++) {
        int row = ipair[t * 2 + p];
        float4 ev = *(const float4*)(eout + (size_t)row * D_ + c);
        v.x += ev.x; v.y += ev.y; v.z += ev.z; v.w += ev.w;
    }
    *(float4*)(out + (size_t)t * D_ + c) = v;
}

// ---------------- launch ----------------
extern "C" void kernel_launch(void* const* d_in, const int* in_sizes, int n_in,
                              void* d_out, int out_size, void* d_ws, size_t ws_size,
                              hipStream_t stream) {
    (void)in_sizes; (void)n_in; (void)out_size; (void)ws_size;
    const float* x       = (const float*)d_in[0];
    const float* Wq_lat  = (const float*)d_in[2];
    const float* Wkv_lat = (const float*)d_in[3];
    const float* Wrot_q  = (const float*)d_in[4];
    const float* Wrot_k  = (const float*)d_in[5];
    const float* Wq_up   = (const float*)d_in[6];
    const float* Wk_up   = (const float*)d_in[7];
    const float* Wv_up   = (const float*)d_in[8];
    const float* Wout    = (const float*)d_in[9];
    const float* n1w     = (const float*)d_in[10];
    const float* n2w     = (const float*)d_in[11];
    const float* Ws1     = (const float*)d_in[12];
    const float* Ws2     = (const float*)d_in[13];
    const float* Wr1     = (const float*)d_in[14];
    const float* Wr2     = (const float*)d_in[15];
    const float* Wgate   = (const float*)d_in[16];
    const float* ebias   = (const float*)d_in[17];
    float* out = (float*)d_out;

    char* wsb = (char*)d_ws;
    // phase-1 pointers
    bf16_t* xnhi = (bf16_t*)(wsb + OFF_R0);
    bf16_t* xnlo = (bf16_t*)(wsb + OFF_R0 + 8 * MB_);
    bf16_t* zlhi = (bf16_t*)(wsb + OFF_R1);
    bf16_t* zllo = (bf16_t*)(wsb + OFF_R1 + 6 * MB_);
    float*  plat = (float*)(wsb + OFF_PLAT);
    float*  pqc  = (float*)(wsb + OFF_PQC);
    float*  pkv  = (float*)(wsb + OFF_PKV);
    bf16_t* plth = (bf16_t*)(wsb + OFF_PLTH);
    bf16_t* pltl = (bf16_t*)(wsb + OFF_PLTL);
    bf16_t* pqth = (bf16_t*)(wsb + OFF_PQTH);
    bf16_t* pqtl = (bf16_t*)(wsb + OFF_PQTL);
    bf16_t* pkth = (bf16_t*)(wsb + OFF_PKTH);
    bf16_t* pktl = (bf16_t*)(wsb + OFF_PKTL);
    bf16_t* woth = (bf16_t*)(wsb + OFF_WOTH);
    bf16_t* wotl = (bf16_t*)(wsb + OFF_WOTL);
    float*  qb   = (float*)(wsb + OFF_R2);
    float*  kvb  = (float*)(wsb + OFF_R3);
    bf16_t* khig = (bf16_t*)(wsb + OFF_KHI);
    bf16_t* klog = (bf16_t*)(wsb + OFF_KLO);
    bf16_t* vthig = (bf16_t*)(wsb + OFF_VTHI);
    bf16_t* vtlog = (bf16_t*)(wsb + OFF_VTLO);
    bf16_t* atth = (bf16_t*)(wsb + OFF_R0);            // att splits reuse R0 (xn dead after zlat GEMM)
    bf16_t* attl = (bf16_t*)(wsb + OFF_R0 + 8 * MB_);
    float*  x1   = (float*)(wsb + OFF_X1);
    float*  cost = (float*)(wsb + OFF_COS);
    float*  sint = (float*)(wsb + OFF_SIN);
    // phase-2 pointers
    float*  xn2  = (float*)(wsb + OFF_R0);             // f32 for gate (att splits dead after Wout GEMM)
    bf16_t* Wr2T = (bf16_t*)(wsb + OFF_R0);            // after gate
    bf16_t* xnb  = (bf16_t*)(wsb + OFF_R1);
    bf16_t* Ws1T = (bf16_t*)(wsb + OFF_R1 + 8 * MB_);
    bf16_t* hbuf = (bf16_t*)(wsb + OFF_R2);
    bf16_t* actb = (bf16_t*)(wsb + OFF_R3);
    float*  eout = (float*)(wsb + OFF_R3 + 8 * MB_);
    bf16_t* Wr1H = (bf16_t*)(wsb + OFF_R4);
    float*  shout = (float*)(wsb + OFF_R4);
    bf16_t* Ws2T = (bf16_t*)(wsb + OFF_WS2T);
    float*  pri  = (float*)(wsb + OFF_PRI);
    int*    seli = (int*)(wsb + OFF_SELI);
    float*  selw = (float*)(wsb + OFF_SELW);
    int*    icnt = (int*)(wsb + OFF_ICNT);
    int*    ipr  = (int*)(wsb + OFF_IPR);

    // --- sublayer 1: attention path (bf16x3 MFMA GEMMs, MFMA flash attention) ---
    rmsnorm_kernel<0><<<T_, 256, 0, stream>>>(x, n1w, nullptr, xnhi, xnlo);
    pack_w_kernel<<<7168, 256, 0, stream>>>(Wq_lat, Wkv_lat, Wq_up, Wrot_q, Wk_up, Wrot_k, Wv_up,
                                            plat, pqc, pkv);
    rope_table_kernel<<<(S_ * 16) / 256, 256, 0, stream>>>(cost, sint);
    packTsplit_kernel<<<dim3(32, 24), 256, 0, stream>>>(plat, plth, pltl, 1024, 768);
    packTsplit_kernel<<<dim3(16, 32), 256, 0, stream>>>(pqc, pqth, pqtl, 512, 1024);
    packTsplit_kernel<<<dim3(8, 64), 256, 0, stream>>>(pkv, pkth, pktl, 256, 2048);
    packTsplit_kernel<<<dim3(32, 32), 256, 0, stream>>>(Wout, woth, wotl, 1024, 1024);
    // zlat = xn @ PLAT : 4096x768x1024, split output
    mfma3_gemm_kernel<false, 1><<<dim3(6, 32), 256, 0, stream>>>(
        xnhi, xnlo, plth, pltl, nullptr, zlhi, zllo, nullptr, 1024, 1024, 768);
    // q = zlat[:, :512] @ PQC : 4096x1024x512, f32 out
    mfma3_gemm_kernel<false, 0><<<dim3(8, 32), 256, 0, stream>>>(
        zlhi, zllo, pqth, pqtl, qb, nullptr, nullptr, nullptr, 512, 768, 1024);
    // k|v = zlat[:, 512:768] @ PKV : 4096x2048x256, f32 out
    mfma3_gemm_kernel<false, 0><<<dim3(16, 32), 256, 0, stream>>>(
        zlhi + 512, zllo + 512, pkth, pktl, kvb, nullptr, nullptr, nullptr, 256, 768, 2048);
    rope_apply_kernel<<<(T_ * H_) / 256, 256, 0, stream>>>(qb, kvb, cost, sint);
    // pre-split K/V to bf16 hi/lo planes (hoists conversion out of the flash loop)
    kpack_kernel<<<(T_ * 1024 / 4) / 256, 256, 0, stream>>>(kvb, khig, klog);
    vtrans_kernel<<<dim3(64, 32, 2), 256, 0, stream>>>(kvb, vthig, vtlog);
    attn_mfma_kernel<<<dim3(512), 256, 0, stream>>>(qb, khig, klog, vthig, vtlog, atth, attl);
    // x1 = att @ Wout + x : 4096x1024x1024
    mfma3_gemm_kernel<true, 0><<<dim3(8, 32), 256, 0, stream>>>(
        atth, attl, woth, wotl, x1, nullptr, nullptr, x, 1024, 1024, 1024);

    // --- sublayer 2: MoE ---
    rmsnorm_kernel<1><<<T_, 256, 0, stream>>>(x1, n2w, xn2, xnb, nullptr);
    hipMemsetAsync(icnt, 0, T_ * sizeof(int), stream);
    gate_kernel<<<T_, 256, 0, stream>>>(xn2, Wgate, ebias, pri);           // fp32 gate
    select_kernel<<<NR_, 1024, 0, stream>>>(pri, seli, selw, icnt, ipr);   // exact top-CAP

    // weight packs (R0 free after gate)
    packT_kernel<<<dim3(32, 32, 7), 256, 0, stream>>>(Wr2, Wr2T, 1024, 1024, 0,
                                                      (long long)1024 * 1024, (long long)1024 * 1024);
    packT_kernel<<<dim3(32, 64, 1), 256, 0, stream>>>(Ws1, Ws1T, 1024, 2048, 0, 0, 0);
    packT_kernel<<<dim3(32, 32, 1), 256, 0, stream>>>(Ws2, Ws2T, 1024, 1024, 0, 0, 0);

    // routed experts (Wr1 halves staged through R4)
    packT_kernel<<<dim3(32, 32, 7), 256, 0, stream>>>(Wr1, Wr1H, 1024, 2048, 0,
                                                      (long long)1024 * 2048, (long long)1024 * 1024);
    mfma_gemm_kernel<true, false, true><<<dim3(8, 5, 7), 256, 0, stream>>>(
        xnb, Wr1H, hbuf, seli, nullptr, CAP_, 1024, 1024, 2048,
        0, (long long)1024 * 1024, (long long)CAP_ * 2048, CAP_);
    packT_kernel<<<dim3(32, 32, 7), 256, 0, stream>>>(Wr1, Wr1H, 1024, 2048, 1024,
                                                      (long long)1024 * 2048, (long long)1024 * 1024);
    mfma_gemm_kernel<true, false, true><<<dim3(8, 5, 7), 256, 0, stream>>>(
        xnb, Wr1H, hbuf + 1024, seli, nullptr, CAP_, 1024, 1024, 2048,
        0, (long long)1024 * 1024, (long long)CAP_ * 2048, CAP_);
    swiglu_kernel<<<(NR_ * CAP_ * 128 + 255) / 256, 256, 0, stream>>>(hbuf, actb, NR_ * CAP_);
    mfma_gemm_kernel<false, true, false><<<dim3(8, 5, 7), 256, 0, stream>>>(
        actb, Wr2T, eout, nullptr, selw, CAP_, 1024, 1024, 1024,
        (long long)CAP_ * 1024, (long long)1024 * 1024, (long long)CAP_ * 1024, CAP_);

    // shared expert (R4 free -> shout)
    mfma_gemm_kernel<false, false, true><<<dim3(16, 32, 1), 256, 0, stream>>>(
        xnb, Ws1T, hbuf, nullptr, nullptr, T_, 1024, 1024, 2048, 0, 0, 0, 0);
    swiglu_kernel<<<(T_ * 128 + 255) / 256, 256, 0, stream>>>(hbuf, actb, T_);
    mfma_gemm_kernel<false, false, false><<<dim3(8, 32, 1), 256, 0, stream>>>(
        actb, Ws2T, shout, nullptr, nullptr, T_, 1024, 1024, 1024, 0, 0, 0, 0);

    // combine
    final_kernel<<<T_, 256, 0, stream>>>(x1, shout, eout, icnt, ipr, out);
}

// Round 5
// 798.661 us; speedup vs baseline: 1.0592x; 1.0540x over previous
//
#include <hip/hip_runtime.h>
#include <cstdint>
#include <cstddef>

// ---------------- static problem config ----------------
#define B_   2
#define S_   2048
#define D_   1024
#define T_   4096          // B*S
#define H_   16
#define HD_  64
#define LQ_  512
#define LKV_ 256
#define FF_  1024
#define NR_  7
#define CAP_ 585

typedef unsigned int   u32;
typedef unsigned long long u64;
typedef __bf16 bf16_t;
typedef __bf16 bf16x8 __attribute__((ext_vector_type(8)));
typedef __bf16 bf16x4 __attribute__((ext_vector_type(4)));
typedef float  f32x4  __attribute__((ext_vector_type(4)));

// ---------------- workspace layout (bytes), regions phase-reused, ~111 MB ----------------
static constexpr size_t MB_ = 1024 * 1024;
static constexpr size_t KB_ = 1024;
// R0 0-16M: xn hi(8M)+lo(8M) -> att hi+lo -> xn2 f32 -> Wr2T bf16 (14.7M)
static constexpr size_t OFF_R0   = 0;
// R1 16-28M: zlat hi(6M)+lo(6M) -> Vthi bf16 8M (attn) -> xnb bf16 8M + Ws1T 4M
static constexpr size_t OFF_R1   = 16 * MB_;
// R2 28-44M: PLAT/PQC/PKV f32 temps (7M) -> q f32 16M -> hbuf bf16 16M
static constexpr size_t OFF_R2   = 28 * MB_;
// R3 44-76M: kv f32 32M -> actb bf16 8M + eout f32 16.8M
static constexpr size_t OFF_R3   = 44 * MB_;
// R4 76-92M: WoutT splits (4M) + packT temps -> Vtlo (8M @ 80M) -> Wr1H bf16 14.7M -> shout f32 16M
static constexpr size_t OFF_R4   = 76 * MB_;
static constexpr size_t OFF_X1   = 92 * MB_;             // Khi/Klo (attn) -> [T][D] f32 x1
static constexpr size_t OFF_PRI  = 108 * MB_;            // [NR][T] f32 (128K)
static constexpr size_t OFF_SELI = OFF_PRI + 128 * KB_;  // [NR][CAP] int
static constexpr size_t OFF_SELW = OFF_SELI + 32 * KB_;  // [NR][CAP] f32
static constexpr size_t OFF_ICNT = OFF_SELW + 32 * KB_;  // [T] int
static constexpr size_t OFF_IPR  = OFF_ICNT + 32 * KB_;  // [T][2] int
static constexpr size_t OFF_COS  = OFF_IPR + 64 * KB_;   // [S][16] f32
static constexpr size_t OFF_SIN  = OFF_COS + 128 * KB_;  // [S][16] f32
static constexpr size_t OFF_WS2T = 109 * MB_;            // Ws2T bf16 2M -> ends 111M
// sub-offsets
static constexpr size_t OFF_PLAT = OFF_R2;               // [1024][768] f32 (3M)
static constexpr size_t OFF_PQC  = OFF_R2 + 3 * MB_;     // [512][1024] f32 (2M)
static constexpr size_t OFF_PKV  = OFF_R2 + 5 * MB_;     // [256][2048] f32 (2M)
// R4 internals: WoutT survives through attn; PLT/PQT/PKT dead after q/kv GEMMs
static constexpr size_t OFF_WOTH = OFF_R4;                    // 76M, 2M (needed after attn)
static constexpr size_t OFF_WOTL = OFF_R4 + 2 * MB_;          // 78M, 2M
static constexpr size_t OFF_PLTH = OFF_R4 + 4 * MB_;          // 80M, 1.5M (dead after zlat GEMM)
static constexpr size_t OFF_PLTL = OFF_R4 + 5632 * KB_;       // 81.5M
static constexpr size_t OFF_PQTH = OFF_R4 + 7 * MB_;          // 83M, 1M (dead after q GEMM)
static constexpr size_t OFF_PQTL = OFF_R4 + 8 * MB_;          // 84M
static constexpr size_t OFF_PKTH = OFF_R4 + 9 * MB_;          // 85M, 1M (dead after kv GEMM)
static constexpr size_t OFF_PKTL = OFF_R4 + 10 * MB_;         // 86M -> ends 87M
// attention bf16 planes (alive only during attn)
static constexpr size_t OFF_VTHI = OFF_R1;                    // 16M, 8M (over dead zlat)
static constexpr size_t OFF_VTLO = OFF_R4 + 4 * MB_;          // 80M, 8M (over dead PLT/PQT/PKT + free)
static constexpr size_t OFF_KHI  = OFF_X1;                    // 92M, 8M (x1 written after attn)
static constexpr size_t OFF_KLO  = OFF_X1 + 8 * MB_;          // 100M, 8M

__device__ __forceinline__ void split2(float v, bf16_t& h, bf16_t& l) {
    h = (bf16_t)v;
    l = (bf16_t)(v - (float)h);
}

// ---------------- RMSNorm: MODE 0 -> emit hi/lo bf16 planes; MODE 1 -> emit f32 + single bf16 ----------------
template <int MODE>
__global__ __launch_bounds__(256) void rmsnorm_kernel(const float* __restrict__ x,
                                                      const float* __restrict__ w,
                                                      float* __restrict__ outf,
                                                      bf16_t* __restrict__ o1,
                                                      bf16_t* __restrict__ o2) {
    int t = blockIdx.x;
    int c = threadIdx.x * 4;
    float4 f = *(const float4*)(x + (size_t)t * D_ + c);
    float ss = f.x * f.x + f.y * f.y + f.z * f.z + f.w * f.w;
#pragma unroll
    for (int off = 32; off > 0; off >>= 1) ss += __shfl_down(ss, off);
    __shared__ float red[4];
    int lane = threadIdx.x & 63, wid = threadIdx.x >> 6;
    if (lane == 0) red[wid] = ss;
    __syncthreads();
    float tot = red[0] + red[1] + red[2] + red[3];
    float inv = 1.f / sqrtf(tot * (1.f / D_) + 1e-6f);
    float4 wv = *(const float4*)(w + c);
    float v[4];
    v[0] = f.x * inv * wv.x; v[1] = f.y * inv * wv.y;
    v[2] = f.z * inv * wv.z; v[3] = f.w * inv * wv.w;
    if (MODE == 0) {
        bf16x4 hv, lv;
#pragma unroll
        for (int j = 0; j < 4; j++) { bf16_t h, l; split2(v[j], h, l); hv[j] = h; lv[j] = l; }
        *(bf16x4*)(o1 + (size_t)t * D_ + c) = hv;
        *(bf16x4*)(o2 + (size_t)t * D_ + c) = lv;
    } else {
        float4 o; o.x = v[0]; o.y = v[1]; o.z = v[2]; o.w = v[3];
        *(float4*)(outf + (size_t)t * D_ + c) = o;
        bf16x4 bv;
#pragma unroll
        for (int j = 0; j < 4; j++) bv[j] = (bf16_t)v[j];
        *(bf16x4*)(o1 + (size_t)t * D_ + c) = bv;
    }
}

// ---------------- pack fp32 attention weights into [K][N] fused layouts ----------------
__global__ __launch_bounds__(256) void pack_w_kernel(const float* __restrict__ Wq_lat, const float* __restrict__ Wkv_lat,
                                                     const float* __restrict__ Wq_up, const float* __restrict__ Wrot_q,
                                                     const float* __restrict__ Wk_up, const float* __restrict__ Wrot_k,
                                                     const float* __restrict__ Wv_up,
                                                     float* __restrict__ PLAT, float* __restrict__ PQC,
                                                     float* __restrict__ PKV) {
    int i = blockIdx.x * 256 + threadIdx.x;
    const int NL = 1024 * 768;
    const int NQ = 512 * 1024;
    if (i < NL) {
        int k = i / 768, c = i - k * 768;
        PLAT[i] = (c < 512) ? Wq_lat[k * 512 + c] : Wkv_lat[k * 256 + (c - 512)];
    } else if (i < NL + NQ) {
        int i2 = i - NL;
        int k = i2 >> 10, c = i2 & 1023, h = c >> 6, j = c & 63;
        PQC[i2] = (j < 32) ? Wq_up[k * 1024 + c] : Wrot_q[k * 1024 + h * 64 + (j - 32)];
    } else {
        int i3 = i - NL - NQ;
        int k = i3 >> 11, c = i3 & 2047;
        if (c < 1024) {
            int h = c >> 6, j = c & 63;
            PKV[i3] = (j < 32) ? Wk_up[k * 1024 + c] : Wrot_k[k * 1024 + h * 64 + (j - 32)];
        } else {
            PKV[i3] = Wv_up[k * 1024 + (c - 1024)];
        }
    }
}

// ---------------- transpose + split: in [K][N] f32 -> outhi/outlo [N][K] bf16 ----------------
__global__ __launch_bounds__(256) void packTsplit_kernel(const float* __restrict__ in,
                                                         bf16_t* __restrict__ outhi, bf16_t* __restrict__ outlo,
                                                         int K, int N) {
    __shared__ float tile[32][33];
    const int k0 = blockIdx.x * 32, n0 = blockIdx.y * 32;
    const int rr = threadIdx.x >> 5, cc = threadIdx.x & 31;
#pragma unroll
    for (int it = 0; it < 4; it++) {
        int k = k0 + rr + it * 8;
        tile[rr + it * 8][cc] = in[(size_t)k * N + n0 + cc];
    }
    __syncthreads();
#pragma unroll
    for (int it = 0; it < 4; it++) {
        int nl = n0 + rr + it * 8;
        float v = tile[cc][rr + it * 8];
        bf16_t h, l; split2(v, h, l);
        outhi[(size_t)nl * K + k0 + cc] = h;
        outlo[(size_t)nl * K + k0 + cc] = l;
    }
}

// ---------------- rope tables ----------------
__global__ __launch_bounds__(256) void rope_table_kernel(float* __restrict__ ct, float* __restrict__ st) {
    int i = blockIdx.x * 256 + threadIdx.x;   // S_*16
    if (i >= S_ * 16) return;
    int s = i >> 4, j = i & 15;
    float inv = 1.f / powf(10000.f, (float)j * (1.f / 16.f));
    float fr = (float)s * inv;
    ct[i] = cosf(fr);
    st[i] = sinf(fr);
}

// apply rope in place: q [T][1024], k = cols 0..1023 of kv [T][2048]; rot dims = h*64+32..63
__global__ __launch_bounds__(256) void rope_apply_kernel(float* __restrict__ q, float* __restrict__ kv,
                                                         const float* __restrict__ ct, const float* __restrict__ st) {
    int gid = blockIdx.x * 256 + threadIdx.x;
    if (gid >= T_ * H_) return;
    int t = gid >> 4, h = gid & 15;
    int s = t & (S_ - 1);
    float c[16], sn[16];
#pragma unroll
    for (int j = 0; j < 16; j += 4) {
        *(float4*)&c[j]  = *(const float4*)(ct + s * 16 + j);
        *(float4*)&sn[j] = *(const float4*)(st + s * 16 + j);
    }
#pragma unroll
    for (int a2 = 0; a2 < 2; a2++) {
        float* p = a2 ? (kv + (size_t)t * 2048 + h * 64 + 32)
                      : (q  + (size_t)t * 1024 + h * 64 + 32);
        float r[32], o2[32];
#pragma unroll
        for (int j2 = 0; j2 < 32; j2 += 4) *(float4*)&r[j2] = *(const float4*)(p + j2);
#pragma unroll
        for (int i = 0; i < 16; i++) {
            o2[i]      = r[i] * c[i] - r[i + 16] * sn[i];
            o2[i + 16] = r[i + 16] * c[i] + r[i] * sn[i];
        }
#pragma unroll
        for (int j2 = 0; j2 < 32; j2 += 4) *(float4*)(p + j2) = *(const float4*)&o2[j2];
    }
}

// ---------------- K planes: kv f32 [T][2048] cols h*64+d -> Khi/Klo [(b*16+h)][s][64] bf16 ----------------
__global__ __launch_bounds__(256) void kpack_kernel(const float* __restrict__ kv,
                                                    bf16_t* __restrict__ Khi, bf16_t* __restrict__ Klo) {
    int i = blockIdx.x * 256 + threadIdx.x;      // T_*1024/4 threads
    int idx = i * 4;                             // output element index
    int d = idx & 63;
    int s = (idx >> 6) & (S_ - 1);
    int bh = idx >> 17;                          // b*16+h  (2^17 = S_*64)
    int b = bh >> 4, h = bh & 15;
    size_t src = ((size_t)(b * S_ + s)) * 2048 + h * 64 + d;
    float4 v = *(const float4*)(kv + src);
    bf16x4 hv, lv; bf16_t hh, ll;
    split2(v.x, hh, ll); hv[0] = hh; lv[0] = ll;
    split2(v.y, hh, ll); hv[1] = hh; lv[1] = ll;
    split2(v.z, hh, ll); hv[2] = hh; lv[2] = ll;
    split2(v.w, hh, ll); hv[3] = hh; lv[3] = ll;
    *(bf16x4*)(Khi + idx) = hv;
    *(bf16x4*)(Klo + idx) = lv;
}

// ---------------- V planes: kv f32 [b][s][1024 + hd] -> Vthi/Vtlo [b*1024+hd][S] bf16 (transposed) ----------------
__global__ __launch_bounds__(256) void vtrans_kernel(const float* __restrict__ kv,
                                                     bf16_t* __restrict__ Vthi, bf16_t* __restrict__ Vtlo) {
    __shared__ float tile[32][33];
    const int bz = blockIdx.z;
    const int s0 = blockIdx.x * 32, hd0 = blockIdx.y * 32;
    const int rr = threadIdx.x >> 5, cc = threadIdx.x & 31;
    const float* inb = kv + (size_t)bz * S_ * 2048 + 1024;
#pragma unroll
    for (int it = 0; it < 4; it++) {
        int s = s0 + rr + it * 8;
        tile[rr + it * 8][cc] = inb[(size_t)s * 2048 + hd0 + cc];
    }
    __syncthreads();
    bf16_t* oh = Vthi + (size_t)bz * 1024 * S_;
    bf16_t* ol = Vtlo + (size_t)bz * 1024 * S_;
#pragma unroll
    for (int it = 0; it < 4; it++) {
        int hd = hd0 + rr + it * 8;
        float v = tile[cc][rr + it * 8];
        bf16_t hh, ll; split2(v, hh, ll);
        oh[(size_t)hd * S_ + s0 + cc] = hh;
        ol[(size_t)hd * S_ + s0 + cc] = ll;
    }
}

// ---------------- bf16x3 MFMA GEMM (near-fp32): C = (Ah+Al)@(Bh+Bl)^T (+resid) ----------------
// M fixed = 4096 (full rows). EMIT: 0 = f32 out, 1 = hi/lo split out.
template <bool RESID, int EMIT>
__global__ __launch_bounds__(256) void mfma3_gemm_kernel(const bf16_t* __restrict__ Ah, const bf16_t* __restrict__ Al,
                                                         const bf16_t* __restrict__ Bh, const bf16_t* __restrict__ Bl,
                                                         float* __restrict__ Cf,
                                                         bf16_t* __restrict__ Chi, bf16_t* __restrict__ Clo,
                                                         const float* __restrict__ resid,
                                                         int K, int lda, int ldc) {
    __shared__ __align__(16) bf16_t Ash[128 * 32];
    __shared__ __align__(16) bf16_t Asl[128 * 32];
    __shared__ __align__(16) bf16_t Bsh[128 * 32];
    __shared__ __align__(16) bf16_t Bsl[128 * 32];
    const int tid = threadIdx.x;
    const int lane = tid & 63, w = tid >> 6;
    const int wm = (w & 1) * 64, wn = (w >> 1) * 64;
    const int m0 = blockIdx.y * 128, n0 = blockIdx.x * 128;

    f32x4 acc[4][4];
#pragma unroll
    for (int mi = 0; mi < 4; mi++)
#pragma unroll
        for (int ni = 0; ni < 4; ni++) { f32x4 zz = {0.f, 0.f, 0.f, 0.f}; acc[mi][ni] = zz; }

    const int mrow = lane & 15, q = lane >> 4;
    for (int k0 = 0; k0 < K; k0 += 32) {
#pragma unroll
        for (int i = 0; i < 2; i++) {
            int chunk = tid + i * 256;
            int row = chunk >> 2, koff = (chunk & 3) * 8;
            size_t aoff = (size_t)(m0 + row) * lda + k0 + koff;
            size_t boff = (size_t)(n0 + row) * K + k0 + koff;
            *(uint4*)(Ash + row * 32 + koff) = *(const uint4*)(Ah + aoff);
            *(uint4*)(Asl + row * 32 + koff) = *(const uint4*)(Al + aoff);
            *(uint4*)(Bsh + row * 32 + koff) = *(const uint4*)(Bh + boff);
            *(uint4*)(Bsl + row * 32 + koff) = *(const uint4*)(Bl + boff);
        }
        __syncthreads();
        bf16x8 ah[4], al[4], bh[4], bl[4];
#pragma unroll
        for (int mi = 0; mi < 4; mi++) {
            ah[mi] = *(const bf16x8*)(Ash + (wm + mi * 16 + mrow) * 32 + q * 8);
            al[mi] = *(const bf16x8*)(Asl + (wm + mi * 16 + mrow) * 32 + q * 8);
        }
#pragma unroll
        for (int ni = 0; ni < 4; ni++) {
            bh[ni] = *(const bf16x8*)(Bsh + (wn + ni * 16 + mrow) * 32 + q * 8);
            bl[ni] = *(const bf16x8*)(Bsl + (wn + ni * 16 + mrow) * 32 + q * 8);
        }
#pragma unroll
        for (int mi = 0; mi < 4; mi++)
#pragma unroll
            for (int ni = 0; ni < 4; ni++) {
                acc[mi][ni] = __builtin_amdgcn_mfma_f32_16x16x32_bf16(al[mi], bh[ni], acc[mi][ni], 0, 0, 0);
                acc[mi][ni] = __builtin_amdgcn_mfma_f32_16x16x32_bf16(ah[mi], bl[ni], acc[mi][ni], 0, 0, 0);
                acc[mi][ni] = __builtin_amdgcn_mfma_f32_16x16x32_bf16(ah[mi], bh[ni], acc[mi][ni], 0, 0, 0);
            }
        __syncthreads();
    }
    // epilogue: C/D layout col = lane&15, row = (lane>>4)*4 + v
#pragma unroll
    for (int mi = 0; mi < 4; mi++) {
        int rbase = m0 + wm + mi * 16 + q * 4;
#pragma unroll
        for (int v = 0; v < 4; v++) {
            int r = rbase + v;
#pragma unroll
            for (int ni = 0; ni < 4; ni++) {
                int c = n0 + wn + ni * 16 + mrow;
                float val = acc[mi][ni][v];
                if (RESID) val += resid[(size_t)r * ldc + c];
                if (EMIT == 0) {
                    Cf[(size_t)r * ldc + c] = val;
                } else {
                    bf16_t h, l; split2(val, h, l);
                    Chi[(size_t)r * ldc + c] = h;
                    Clo[(size_t)r * ldc + c] = l;
                }
            }
        }
    }
}

// ---------------- MFMA flash attention (causal), bf16x3 QK / bf16x2 PV, K/V pre-split planes ----------------
// grid: 1024 = 32 q-tiles (64 rows) x 32 bh, balanced so each CU's 4 co-resident blocks sum to 66 work-units.
// 4 waves, wave w owns q rows [w*16, w*16+16). LDS: 5 x [64][64] bf16, all XOR-swizzled = 40 KB -> 4 blocks/CU.
__global__ __launch_bounds__(256, 4) void attn_mfma_kernel(const float* __restrict__ Q,
                                                        const bf16_t* __restrict__ Khig, const bf16_t* __restrict__ Klog,
                                                        const bf16_t* __restrict__ Vthig, const bf16_t* __restrict__ Vtlog,
                                                        bf16_t* __restrict__ Ohi, bf16_t* __restrict__ Olo) {
    __shared__ __align__(16) bf16_t Kh[64][64];
    __shared__ __align__(16) bf16_t Kl[64][64];
    __shared__ __align__(16) bf16_t Vth[64][64];   // Vth[d][k] (transposed), XOR-swizzled
    __shared__ __align__(16) bf16_t Vtl[64][64];
    __shared__ __align__(16) bf16_t Ph[64][64];    // P rounded to bf16, XOR-swizzled cols

    const int tid = threadIdx.x;
    const int lane = tid & 63, w = tid >> 6;
    const int mrow = lane & 15, qq = lane >> 4;
    const int j = blockIdx.x;
    // balanced (qt, bh) mapping: groups of 256; per-rank qt sums to const 66 work-units across the 4 groups
    const int g = j >> 8, c5 = j & 255, rk = c5 >> 5, bh = c5 & 31;
    const int qt = (g == 0) ? (31 - rk) : (g == 1) ? rk : (g == 2) ? (23 - rk) : (8 + rk);
    const int b = bh >> 4, h = bh & 15;
    const int q0 = qt * 64;
    const float*  Qb  = Q + (size_t)b * S_ * 1024 + h * 64;
    const bf16_t* Khb = Khig + (size_t)bh * S_ * 64;
    const bf16_t* Klb = Klog + (size_t)bh * S_ * 64;
    const bf16_t* Vhb = Vthig + (size_t)(b * 1024 + h * 64) * S_;
    const bf16_t* Vlb = Vtlog + (size_t)(b * 1024 + h * 64) * S_;

    // ---- Q fragments in registers, pre-scaled by 1/sqrt(HD)=0.125 (exact), hi/lo split ----
    bf16x8 qh[2], ql[2];                           // [ks]
    {
        int r = q0 + w * 16 + mrow;
#pragma unroll
        for (int ks = 0; ks < 2; ks++) {
            const float* p = Qb + (size_t)r * 1024 + ks * 32 + qq * 8;
            float4 a = *(const float4*)p;
            float4 b2 = *(const float4*)(p + 4);
            float vals[8] = {a.x, a.y, a.z, a.w, b2.x, b2.y, b2.z, b2.w};
#pragma unroll
            for (int jj = 0; jj < 8; jj++) {
                bf16_t hh, ll; split2(vals[jj] * 0.125f, hh, ll);
                qh[ks][jj] = hh; ql[ks][jj] = ll;
            }
        }
    }

    f32x4 acc_o[4];
    float m_r[4], l_r[4];
#pragma unroll
    for (int ni = 0; ni < 4; ni++) { f32x4 zz = {0.f, 0.f, 0.f, 0.f}; acc_o[ni] = zz; }
#pragma unroll
    for (int v = 0; v < 4; v++) { m_r[v] = -1e30f; l_r[v] = 0.f; }

    for (int kt = 0; kt <= qt; kt++) {
        const int k0 = kt * 64;
        // ---- stage K and V (both XOR-swizzled) from bf16 planes ----
#pragma unroll
        for (int i = 0; i < 2; i++) {
            int cc = tid + i * 256;                // 512 chunks of 8 bf16 per plane
            int rr = cc >> 3, c8 = (cc & 7) * 8;
            int csw = c8 ^ ((rr & 7) << 3);
            *(uint4*)&Kh[rr][csw] = *(const uint4*)(Khb + (size_t)(k0 + rr) * 64 + c8);
            *(uint4*)&Kl[rr][csw] = *(const uint4*)(Klb + (size_t)(k0 + rr) * 64 + c8);
            *(uint4*)&Vth[rr][csw] = *(const uint4*)(Vhb + (size_t)rr * S_ + k0 + c8);
            *(uint4*)&Vtl[rr][csw] = *(const uint4*)(Vlb + (size_t)rr * S_ + k0 + c8);
        }
        __syncthreads();

        // ---- S = Q @ K^T (bf16x3) ----
        f32x4 acc_s[4];
#pragma unroll
        for (int ni = 0; ni < 4; ni++) { f32x4 zz = {0.f, 0.f, 0.f, 0.f}; acc_s[ni] = zz; }
#pragma unroll
        for (int ks = 0; ks < 2; ks++) {
            const int c0 = ks * 32 + qq * 8;
            bf16x8 bhf[4], blf[4];
#pragma unroll
            for (int ni = 0; ni < 4; ni++) {
                int row = ni * 16 + mrow;
                int cs = c0 ^ ((row & 7) << 3);
                bhf[ni] = *(const bf16x8*)&Kh[row][cs];
                blf[ni] = *(const bf16x8*)&Kl[row][cs];
            }
#pragma unroll
            for (int ni = 0; ni < 4; ni++) {
                acc_s[ni] = __builtin_amdgcn_mfma_f32_16x16x32_bf16(ql[ks], bhf[ni], acc_s[ni], 0, 0, 0);
                acc_s[ni] = __builtin_amdgcn_mfma_f32_16x16x32_bf16(qh[ks], blf[ni], acc_s[ni], 0, 0, 0);
                acc_s[ni] = __builtin_amdgcn_mfma_f32_16x16x32_bf16(qh[ks], bhf[ni], acc_s[ni], 0, 0, 0);
            }
        }
        // ---- online softmax (rows: w*16 + qq*4+v; cols: ni*16+mrow) ----
        const bool diag = (kt == qt);
#pragma unroll
        for (int v = 0; v < 4; v++) {
            int rloc = w * 16 + qq * 4 + v;        // row within 64-row q tile
            float sv[4];
            float rmax = -1e30f;
#pragma unroll
            for (int ni = 0; ni < 4; ni++) {
                float s = acc_s[ni][v];
                if (diag && (ni * 16 + mrow) > rloc) s = -1e30f;
                sv[ni] = s;
                rmax = fmaxf(rmax, s);
            }
#pragma unroll
            for (int off = 1; off < 16; off <<= 1) rmax = fmaxf(rmax, __shfl_xor(rmax, off));
            float mo = m_r[v];
            float mn = fmaxf(mo, rmax);
            float al = __expf(mo - mn);
            m_r[v] = mn;
            int t7 = (rloc & 7) << 3;
            float rs = 0.f;
#pragma unroll
            for (int ni = 0; ni < 4; ni++) {
                float p = __expf(sv[ni] - mn);
                bf16_t ph = (bf16_t)p;
                Ph[rloc][(ni * 16 + mrow) ^ t7] = ph;
                rs += (float)ph;                   // denominator from same rounded P -> consistent weights
            }
#pragma unroll
            for (int off = 1; off < 16; off <<= 1) rs += __shfl_xor(rs, off);
            l_r[v] = l_r[v] * al + rs;
#pragma unroll
            for (int ni = 0; ni < 4; ni++) acc_o[ni][v] *= al;
        }
        // ---- O += P @ V (bf16x2: P@Vl + P@Vh). P rows read by owning wave only. ----
#pragma unroll
        for (int ks = 0; ks < 2; ks++) {
            const int rc = ks * 32 + qq * 8;
            bf16x8 pah, vhf[4], vlf[4];
            {
                int rowp = w * 16 + mrow;
                int cp = rc ^ ((rowp & 7) << 3);
                pah = *(const bf16x8*)&Ph[rowp][cp];
            }
#pragma unroll
            for (int ni = 0; ni < 4; ni++) {
                int cv = ni * 16 + mrow;
                int vs = rc ^ ((cv & 7) << 3);
                vhf[ni] = *(const bf16x8*)&Vth[cv][vs];
                vlf[ni] = *(const bf16x8*)&Vtl[cv][vs];
            }
#pragma unroll
            for (int ni = 0; ni < 4; ni++) {
                acc_o[ni] = __builtin_amdgcn_mfma_f32_16x16x32_bf16(pah, vlf[ni], acc_o[ni], 0, 0, 0);
                acc_o[ni] = __builtin_amdgcn_mfma_f32_16x16x32_bf16(pah, vhf[ni], acc_o[ni], 0, 0, 0);
            }
        }
        __syncthreads();
    }
    // ---- epilogue: normalize, split hi/lo, store ----
#pragma unroll
    for (int v = 0; v < 4; v++) {
        int rq = q0 + w * 16 + qq * 4 + v;
        float inv = 1.f / l_r[v];
        size_t base = (size_t)(b * S_ + rq) * 1024 + h * 64;
#pragma unroll
        for (int ni = 0; ni < 4; ni++) {
            float val = acc_o[ni][v] * inv;
            bf16_t hh, ll; split2(val, hh, ll);
            Ohi[base + ni * 16 + mrow] = hh;
            Olo[base + ni * 16 + mrow] = ll;
        }
    }
}

// ---------------- gate: affinities + top-2 membership -> priority [NR][T] ----------------
__global__ __launch_bounds__(256) void gate_kernel(const float* __restrict__ xn2, const float* __restrict__ Wg,
                                                   const float* __restrict__ bias, float* __restrict__ pri) {
    __shared__ float red[256][8];
    int t = blockIdx.x, tid = threadIdx.x;
    float acc[7] = {0.f, 0.f, 0.f, 0.f, 0.f, 0.f, 0.f};
    for (int d = tid; d < D_; d += 256) {
        float xv = xn2[(size_t)t * D_ + d];
        const float* wr = Wg + d * 7;
#pragma unroll
        for (int e = 0; e < 7; e++) acc[e] = fmaf(xv, wr[e], acc[e]);
    }
#pragma unroll
    for (int e = 0; e < 7; e++) red[tid][e] = acc[e];
    __syncthreads();
    for (int s2 = 128; s2 > 0; s2 >>= 1) {
        if (tid < s2) {
#pragma unroll
            for (int e = 0; e < 7; e++) red[tid][e] += red[tid + s2][e];
        }
        __syncthreads();
    }
    if (tid == 0) {
        float a[7];
#pragma unroll
        for (int e = 0; e < 7; e++) a[e] = 1.f / (1.f + expf(-(red[0][e] + bias[e])));
        int e1 = 0;
#pragma unroll
        for (int e = 1; e < 7; e++) if (a[e] > a[e1]) e1 = e;     // strict > : lowest-index tiebreak
        int e2 = -1;
#pragma unroll
        for (int e = 0; e < 7; e++) if (e != e1 && (e2 < 0 || a[e] > a[e2])) e2 = e;
#pragma unroll
        for (int e = 0; e < 7; e++) pri[(size_t)e * T_ + t] = (e == e1 || e == e2) ? a[e] : -1.f;
    }
}

// ---------------- exact top-585 via 32-step binary threshold search (order-free slots) ----------------
__global__ __launch_bounds__(1024) void select_kernel(const float* __restrict__ pri, int* __restrict__ sel_idx,
                                                      float* __restrict__ sel_w, int* __restrict__ inv_cnt,
                                                      int* __restrict__ inv_pair) {
    __shared__ u32 keys[T_];        // 16 KB: float bits (monotone for positive floats); 0 = invalid
    __shared__ int redc[16];
    __shared__ int bcast;
    __shared__ int ctr;
    const int e = blockIdx.x, tid = threadIdx.x;
    const int lane = tid & 63, wid = tid >> 6;
#pragma unroll
    for (int i = 0; i < 4; i++) {
        int idx = tid + i * 1024;
        float p = pri[(size_t)e * T_ + idx];
        keys[idx] = (p > 0.f) ? __float_as_uint(p) : 0u;
    }
    if (tid == 0) ctr = 0;
    __syncthreads();

    u32 myk[4];
#pragma unroll
    for (int i = 0; i < 4; i++) myk[i] = keys[tid + i * 1024];

    // binary search: p = max t with count(keys >= t) >= CAP  (= CAP-th largest key, or 0 if < CAP valid)
    u32 p = 0;
    for (int b = 31; b >= 0; b--) {
        u32 t = p | (1u << b);
        int cnt = 0;
#pragma unroll
        for (int i = 0; i < 4; i++) cnt += (myk[i] >= t) ? 1 : 0;
#pragma unroll
        for (int off = 32; off > 0; off >>= 1) cnt += __shfl_down(cnt, off);
        if (lane == 0) redc[wid] = cnt;
        __syncthreads();
        if (tid == 0) {
            int tot = 0;
#pragma unroll
            for (int k2 = 0; k2 < 16; k2++) tot += redc[k2];
            bcast = tot;
        }
        __syncthreads();
        if (bcast >= CAP_) p = t;
        __syncthreads();
    }
    // count strictly greater
    {
        int cnt = 0;
#pragma unroll
        for (int i = 0; i < 4; i++) cnt += (myk[i] > p) ? 1 : 0;
#pragma unroll
        for (int off = 32; off > 0; off >>= 1) cnt += __shfl_down(cnt, off);
        if (lane == 0) redc[wid] = cnt;
        __syncthreads();
        if (tid == 0) {
            int tot = 0;
#pragma unroll
            for (int k2 = 0; k2 < 16; k2++) tot += redc[k2];
            bcast = tot;
        }
        __syncthreads();
    }
    int cntGT = bcast;
    int quota = CAP_ - cntGT;   // slots left for keys == p (>=1 when p>0)

    // assignment: kept = (k > p) or (k == p, p>0, index-rank < quota)
#pragma unroll
    for (int i = 0; i < 4; i++) {
        int idx = tid + i * 1024;
        u32 k = myk[i];
        bool kept = false;
        if (k > p) kept = true;
        else if (k == p && p != 0u) {
            int rank = 0;
            for (int j = 0; j < idx; j++) rank += (keys[j] == p) ? 1 : 0;
            kept = (rank < quota);
        }
        if (kept) {
            int s = atomicAdd(&ctr, 1);
            sel_idx[e * CAP_ + s] = idx;
            sel_w[e * CAP_ + s] = __uint_as_float(k);
            int pos = atomicAdd(&inv_cnt[idx], 1);
            inv_pair[idx * 2 + pos] = e * CAP_ + s;
        }
    }
    __syncthreads();
    for (int s = ctr + tid; s < CAP_; s += 1024) {  // unfilled slots -> token 0, weight 0
        sel_idx[e * CAP_ + s] = 0;
        sel_w[e * CAP_ + s] = 0.f;
    }
}

// ---------------- transpose + convert: out[z][n][k] = (bf16) in[z][k][nbase+n] ----------------
__global__ __launch_bounds__(256) void packT_kernel(const float* __restrict__ in, bf16_t* __restrict__ out,
                                                    int K, int N, int nbase,
                                                    long long inStride, long long outStride) {
    __shared__ float tile[32][33];
    const int z = blockIdx.z;
    const int k0 = blockIdx.x * 32, n0 = blockIdx.y * 32;
    const int rr = threadIdx.x >> 5, cc = threadIdx.x & 31;
    const float* inz = in + (size_t)z * inStride;
#pragma unroll
    for (int it = 0; it < 4; it++) {
        int k = k0 + rr + it * 8;
        tile[rr + it * 8][cc] = inz[(size_t)k * N + nbase + n0 + cc];
    }
    __syncthreads();
    bf16_t* outz = out + (size_t)z * outStride;
#pragma unroll
    for (int it = 0; it < 4; it++) {
        int nl = n0 + rr + it * 8;
        outz[(size_t)nl * K + k0 + cc] = (bf16_t)tile[cc][rr + it * 8];
    }
}

// ---------------- bf16 MFMA GEMM (single precision pass, experts): C = gather(A) @ Bt^T (*scale) ----------------
template <bool GATHER, bool SCALE, bool OUTBF16>
__global__ __launch_bounds__(256) void mfma_gemm_kernel(const bf16_t* __restrict__ A, const bf16_t* __restrict__ Bt,
                                                        void* __restrict__ Cv,
                                                        const int* __restrict__ gidx, const float* __restrict__ scale,
                                                        int M, int K, int lda, int ldc,
                                                        long long strideA, long long strideBt, long long strideC,
                                                        int gstride) {
    __shared__ __align__(16) bf16_t As[128 * 32];
    __shared__ __align__(16) bf16_t Bs[128 * 32];
    const int tid = threadIdx.x;
    const int lane = tid & 63, w = tid >> 6;
    const int wm = (w & 1) * 64, wn = (w >> 1) * 64;
    const int z = blockIdx.z;
    const int m0 = blockIdx.y * 128, n0 = blockIdx.x * 128;
    const bf16_t* Az = A + (GATHER ? 0 : (size_t)z * strideA);
    const bf16_t* Bz = Bt + (size_t)z * strideBt;

    int arow[2];
#pragma unroll
    for (int i = 0; i < 2; i++) {
        int chunk = tid + i * 256;
        int r = m0 + (chunk >> 2);
        if (r > M - 1) r = M - 1;
        arow[i] = GATHER ? gidx[z * gstride + r] : r;
    }

    f32x4 acc[4][4];
#pragma unroll
    for (int mi = 0; mi < 4; mi++)
#pragma unroll
        for (int ni = 0; ni < 4; ni++) { f32x4 zz = {0.f, 0.f, 0.f, 0.f}; acc[mi][ni] = zz; }

    const int mrow = lane & 15, q = lane >> 4;
    for (int k0 = 0; k0 < K; k0 += 32) {
#pragma unroll
        for (int i = 0; i < 2; i++) {
            int chunk = tid + i * 256;
            int row = chunk >> 2, koff = (chunk & 3) * 8;
            *(uint4*)(As + row * 32 + koff) = *(const uint4*)(Az + (size_t)arow[i] * lda + k0 + koff);
            *(uint4*)(Bs + row * 32 + koff) = *(const uint4*)(Bz + (size_t)(n0 + row) * K + k0 + koff);
        }
        __syncthreads();
        bf16x8 af[4], bfr[4];
#pragma unroll
        for (int mi = 0; mi < 4; mi++)
            af[mi] = *(const bf16x8*)(As + (wm + mi * 16 + mrow) * 32 + q * 8);
#pragma unroll
        for (int ni = 0; ni < 4; ni++)
            bfr[ni] = *(const bf16x8*)(Bs + (wn + ni * 16 + mrow) * 32 + q * 8);
#pragma unroll
        for (int mi = 0; mi < 4; mi++)
#pragma unroll
            for (int ni = 0; ni < 4; ni++)
                acc[mi][ni] = __builtin_amdgcn_mfma_f32_16x16x32_bf16(af[mi], bfr[ni], acc[mi][ni], 0, 0, 0);
        __syncthreads();
    }
#pragma unroll
    for (int mi = 0; mi < 4; mi++) {
        int rbase = m0 + wm + mi * 16 + q * 4;
#pragma unroll
        for (int v = 0; v < 4; v++) {
            int r = rbase + v;
            if (r < M) {
                float sc = SCALE ? scale[z * gstride + r] : 1.f;
#pragma unroll
                for (int ni = 0; ni < 4; ni++) {
                    int c = n0 + wn + ni * 16 + mrow;
                    float val = acc[mi][ni][v];
                    if (SCALE) val *= sc;
                    size_t off = (size_t)z * strideC + (size_t)r * ldc + c;
                    if (OUTBF16) ((bf16_t*)Cv)[off] = (bf16_t)val;
                    else         ((float*)Cv)[off] = val;
                }
            }
        }
    }
}

// ---------------- SwiGLU elementwise ----------------
__global__ __launch_bounds__(256) void swiglu_kernel(const bf16_t* __restrict__ h, bf16_t* __restrict__ act,
                                                     int rows) {
    int i8 = blockIdx.x * 256 + threadIdx.x;
    int total = rows * 128;
    if (i8 >= total) return;
    int r = i8 >> 7, f = (i8 & 127) * 8;
    bf16x8 h1 = *(const bf16x8*)(h + (size_t)r * 2048 + f);
    bf16x8 h2 = *(const bf16x8*)(h + (size_t)r * 2048 + 1024 + f);
    bf16x8 o;
#pragma unroll
    for (int j = 0; j < 8; j++) {
        float a = (float)h1[j], g = (float)h2[j];
        o[j] = (bf16_t)(a * g / (1.f + __expf(-g)));
    }
    *(bf16x8*)(act + (size_t)r * 1024 + f) = o;
}

// ---------------- final combine: out = x1 + shared + sum routed ----------------
__global__ __launch_bounds__(256) void final_kernel(const float* __restrict__ x1, const float* __restrict__ sh,
                                                    const float* __restrict__ eout, const int* __restrict__ icnt,
                                                    const int* __restrict__ ipair, float* __restrict__ out) {
    int t = blockIdx.x, c = threadIdx.x * 4;
    float4 v = *(const float4*)(x1 + (size_t)t * D_ + c);
    float4 s2 = *(const float4*)(sh + (size_t)t * D_ + c);
    v.x += s2.x; v.y += s2.y; v.z += s2.z; v.w += s2.w;
    int n = icnt[t];
    for (int p = 0; p < n; p++) {
        int row = ipair[t * 2 + p];
        float4 ev = *(const float4*)(eout + (size_t)row * D_ + c);
        v.x += ev.x; v.y += ev.y; v.z += ev.z; v.w += ev.w;
    }
    *(float4*)(out + (size_t)t * D_ + c) = v;
}

// ---------------- launch ----------------
extern "C" void kernel_launch(void* const* d_in, const int* in_sizes, int n_in,
                              void* d_out, int out_size, void* d_ws, size_t ws_size,
                              hipStream_t stream) {
    (void)in_sizes; (void)n_in; (void)out_size; (void)ws_size;
    const float* x       = (const float*)d_in[0];
    const float* Wq_lat  = (const float*)d_in[2];
    const float* Wkv_lat = (const float*)d_in[3];
    const float* Wrot_q  = (const float*)d_in[4];
    const float* Wrot_k  = (const float*)d_in[5];
    const float* Wq_up   = (const float*)d_in[6];
    const float* Wk_up   = (const float*)d_in[7];
    const float* Wv_up   = (const float*)d_in[8];
    const float* Wout    = (const float*)d_in[9];
    const float* n1w     = (const float*)d_in[10];
    const float* n2w     = (const float*)d_in[11];
    const float* Ws1     = (const float*)d_in[12];
    const float* Ws2     = (const float*)d_in[13];
    const float* Wr1     = (const float*)d_in[14];
    const float* Wr2     = (const float*)d_in[15];
    const float* Wgate   = (const float*)d_in[16];
    const float* ebias   = (const float*)d_in[17];
    float* out = (float*)d_out;

    char* wsb = (char*)d_ws;
    // phase-1 pointers
    bf16_t* xnhi = (bf16_t*)(wsb + OFF_R0);
    bf16_t* xnlo = (bf16_t*)(wsb + OFF_R0 + 8 * MB_);
    bf16_t* zlhi = (bf16_t*)(wsb + OFF_R1);
    bf16_t* zllo = (bf16_t*)(wsb + OFF_R1 + 6 * MB_);
    float*  plat = (float*)(wsb + OFF_PLAT);
    float*  pqc  = (float*)(wsb + OFF_PQC);
    float*  pkv  = (float*)(wsb + OFF_PKV);
    bf16_t* plth = (bf16_t*)(wsb + OFF_PLTH);
    bf16_t* pltl = (bf16_t*)(wsb + OFF_PLTL);
    bf16_t* pqth = (bf16_t*)(wsb + OFF_PQTH);
    bf16_t* pqtl = (bf16_t*)(wsb + OFF_PQTL);
    bf16_t* pkth = (bf16_t*)(wsb + OFF_PKTH);
    bf16_t* pktl = (bf16_t*)(wsb + OFF_PKTL);
    bf16_t* woth = (bf16_t*)(wsb + OFF_WOTH);
    bf16_t* wotl = (bf16_t*)(wsb + OFF_WOTL);
    float*  qb   = (float*)(wsb + OFF_R2);
    float*  kvb  = (float*)(wsb + OFF_R3);
    bf16_t* khig = (bf16_t*)(wsb + OFF_KHI);
    bf16_t* klog = (bf16_t*)(wsb + OFF_KLO);
    bf16_t* vthig = (bf16_t*)(wsb + OFF_VTHI);
    bf16_t* vtlog = (bf16_t*)(wsb + OFF_VTLO);
    bf16_t* atth = (bf16_t*)(wsb + OFF_R0);            // att splits reuse R0 (xn dead after zlat GEMM)
    bf16_t* attl = (bf16_t*)(wsb + OFF_R0 + 8 * MB_);
    float*  x1   = (float*)(wsb + OFF_X1);
    float*  cost = (float*)(wsb + OFF_COS);
    float*  sint = (float*)(wsb + OFF_SIN);
    // phase-2 pointers
    float*  xn2  = (float*)(wsb + OFF_R0);             // f32 for gate (att splits dead after Wout GEMM)
    bf16_t* Wr2T = (bf16_t*)(wsb + OFF_R0);            // after gate
    bf16_t* xnb  = (bf16_t*)(wsb + OFF_R1);
    bf16_t* Ws1T = (bf16_t*)(wsb + OFF_R1 + 8 * MB_);
    bf16_t* hbuf = (bf16_t*)(wsb + OFF_R2);
    bf16_t* actb = (bf16_t*)(wsb + OFF_R3);
    float*  eout = (float*)(wsb + OFF_R3 + 8 * MB_);
    bf16_t* Wr1H = (bf16_t*)(wsb + OFF_R4);
    float*  shout = (float*)(wsb + OFF_R4);
    bf16_t* Ws2T = (bf16_t*)(wsb + OFF_WS2T);
    float*  pri  = (float*)(wsb + OFF_PRI);
    int*    seli = (int*)(wsb + OFF_SELI);
    float*  selw = (float*)(wsb + OFF_SELW);
    int*    icnt = (int*)(wsb + OFF_ICNT);
    int*    ipr  = (int*)(wsb + OFF_IPR);

    // --- sublayer 1: attention path (bf16x3 MFMA GEMMs, MFMA flash attention) ---
    rmsnorm_kernel<0><<<T_, 256, 0, stream>>>(x, n1w, nullptr, xnhi, xnlo);
    pack_w_kernel<<<7168, 256, 0, stream>>>(Wq_lat, Wkv_lat, Wq_up, Wrot_q, Wk_up, Wrot_k, Wv_up,
                                            plat, pqc, pkv);
    rope_table_kernel<<<(S_ * 16) / 256, 256, 0, stream>>>(cost, sint);
    packTsplit_kernel<<<dim3(32, 24), 256, 0, stream>>>(plat, plth, pltl, 1024, 768);
    packTsplit_kernel<<<dim3(16, 32), 256, 0, stream>>>(pqc, pqth, pqtl, 512, 1024);
    packTsplit_kernel<<<dim3(8, 64), 256, 0, stream>>>(pkv, pkth, pktl, 256, 2048);
    packTsplit_kernel<<<dim3(32, 32), 256, 0, stream>>>(Wout, woth, wotl, 1024, 1024);
    // zlat = xn @ PLAT : 4096x768x1024, split output
    mfma3_gemm_kernel<false, 1><<<dim3(6, 32), 256, 0, stream>>>(
        xnhi, xnlo, plth, pltl, nullptr, zlhi, zllo, nullptr, 1024, 1024, 768);
    // q = zlat[:, :512] @ PQC : 4096x1024x512, f32 out
    mfma3_gemm_kernel<false, 0><<<dim3(8, 32), 256, 0, stream>>>(
        zlhi, zllo, pqth, pqtl, qb, nullptr, nullptr, nullptr, 512, 768, 1024);
    // k|v = zlat[:, 512:768] @ PKV : 4096x2048x256, f32 out
    mfma3_gemm_kernel<false, 0><<<dim3(16, 32), 256, 0, stream>>>(
        zlhi + 512, zllo + 512, pkth, pktl, kvb, nullptr, nullptr, nullptr, 256, 768, 2048);
    rope_apply_kernel<<<(T_ * H_) / 256, 256, 0, stream>>>(qb, kvb, cost, sint);
    // pre-split K/V to bf16 hi/lo planes (hoists conversion out of the flash loop)
    kpack_kernel<<<(T_ * 1024 / 4) / 256, 256, 0, stream>>>(kvb, khig, klog);
    vtrans_kernel<<<dim3(64, 32, 2), 256, 0, stream>>>(kvb, vthig, vtlog);
    attn_mfma_kernel<<<dim3(1024), 256, 0, stream>>>(qb, khig, klog, vthig, vtlog, atth, attl);
    // x1 = att @ Wout + x : 4096x1024x1024
    mfma3_gemm_kernel<true, 0><<<dim3(8, 32), 256, 0, stream>>>(
        atth, attl, woth, wotl, x1, nullptr, nullptr, x, 1024, 1024, 1024);

    // --- sublayer 2: MoE ---
    rmsnorm_kernel<1><<<T_, 256, 0, stream>>>(x1, n2w, xn2, xnb, nullptr);
    hipMemsetAsync(icnt, 0, T_ * sizeof(int), stream);
    gate_kernel<<<T_, 256, 0, stream>>>(xn2, Wgate, ebias, pri);           // fp32 gate
    select_kernel<<<NR_, 1024, 0, stream>>>(pri, seli, selw, icnt, ipr);   // exact top-CAP

    // weight packs (R0 free after gate)
    packT_kernel<<<dim3(32, 32, 7), 256, 0, stream>>>(Wr2, Wr2T, 1024, 1024, 0,
                                                      (long long)1024 * 1024, (long long)1024 * 1024);
    packT_kernel<<<dim3(32, 64, 1), 256, 0, stream>>>(Ws1, Ws1T, 1024, 2048, 0, 0, 0);
    packT_kernel<<<dim3(32, 32, 1), 256, 0, stream>>>(Ws2, Ws2T, 1024, 1024, 0, 0, 0);

    // routed experts (Wr1 halves staged through R4)
    packT_kernel<<<dim3(32, 32, 7), 256, 0, stream>>>(Wr1, Wr1H, 1024, 2048, 0,
                                                      (long long)1024 * 2048, (long long)1024 * 1024);
    mfma_gemm_kernel<true, false, true><<<dim3(8, 5, 7), 256, 0, stream>>>(
        xnb, Wr1H, hbuf, seli, nullptr, CAP_, 1024, 1024, 2048,
        0, (long long)1024 * 1024, (long long)CAP_ * 2048, CAP_);
    packT_kernel<<<dim3(32, 32, 7), 256, 0, stream>>>(Wr1, Wr1H, 1024, 2048, 1024,
                                                      (long long)1024 * 2048, (long long)1024 * 1024);
    mfma_gemm_kernel<true, false, true><<<dim3(8, 5, 7), 256, 0, stream>>>(
        xnb, Wr1H, hbuf + 1024, seli, nullptr, CAP_, 1024, 1024, 2048,
        0, (long long)1024 * 1024, (long long)CAP_ * 2048, CAP_);
    swiglu_kernel<<<(NR_ * CAP_ * 128 + 255) / 256, 256, 0, stream>>>(hbuf, actb, NR_ * CAP_);
    mfma_gemm_kernel<false, true, false><<<dim3(8, 5, 7), 256, 0, stream>>>(
        actb, Wr2T, eout, nullptr, selw, CAP_, 1024, 1024, 1024,
        (long long)CAP_ * 1024, (long long)1024 * 1024, (long long)CAP_ * 1024, CAP_);

    // shared expert (R4 free -> shout)
    mfma_gemm_kernel<false, false, true><<<dim3(16, 32, 1), 256, 0, stream>>>(
        xnb, Ws1T, hbuf, nullptr, nullptr, T_, 1024, 1024, 2048, 0, 0, 0, 0);
    swiglu_kernel<<<(T_ * 128 + 255) / 256, 256, 0, stream>>>(hbuf, actb, T_);
    mfma_gemm_kernel<false, false, false><<<dim3(8, 32, 1), 256, 0, stream>>>(
        actb, Ws2T, shout, nullptr, nullptr, T_, 1024, 1024, 1024, 0, 0, 0, 0);

    // combine
    final_kernel<<<T_, 256, 0, stream>>>(x1, shout, eout, icnt, ipr, out);
}

// Round 6
// 697.012 us; speedup vs baseline: 1.2136x; 1.1458x over previous
//
#include <hip/hip_runtime.h>
#include <cstdint>
#include <cstddef>

// ---------------- static problem config ----------------
#define B_   2
#define S_   2048
#define D_   1024
#define T_   4096          // B*S
#define H_   16
#define HD_  64
#define LQ_  512
#define LKV_ 256
#define FF_  1024
#define NR_  7
#define CAP_ 585

typedef unsigned int   u32;
typedef unsigned long long u64;
typedef __bf16 bf16_t;
typedef __bf16 bf16x8 __attribute__((ext_vector_type(8)));
typedef __bf16 bf16x4 __attribute__((ext_vector_type(4)));
typedef float  f32x4  __attribute__((ext_vector_type(4)));

// ---------------- workspace layout (bytes), regions phase-reused, ~111 MB ----------------
static constexpr size_t MB_ = 1024 * 1024;
static constexpr size_t KB_ = 1024;
// R0 0-16M: xn hi(8M)+lo(8M) -> att hi+lo -> xn2 f32 -> Wr2T bf16 (14.7M)
static constexpr size_t OFF_R0   = 0;
// R1 16-28M: zlat hi(6M)+lo(6M) -> Vthi bf16 8M (attn) -> xnb bf16 8M + Ws1T 4M
static constexpr size_t OFF_R1   = 16 * MB_;
// R2 28-44M: PLAT/PQC/PKV f32 temps (7M) -> q f32 16M -> hbuf bf16 16M
static constexpr size_t OFF_R2   = 28 * MB_;
// R3 44-76M: kv f32 32M -> actb bf16 8M + eout f32 16.8M
static constexpr size_t OFF_R3   = 44 * MB_;
// R4 76-92M: WoutT splits (4M) + packT temps -> Vtlo (8M @ 80M) -> Wr1H bf16 14.7M -> shout f32 16M
static constexpr size_t OFF_R4   = 76 * MB_;
static constexpr size_t OFF_X1   = 92 * MB_;             // Khi/Klo (attn) -> [T][D] f32 x1
static constexpr size_t OFF_PRI  = 108 * MB_;            // [NR][T] f32 (128K)
static constexpr size_t OFF_SELI = OFF_PRI + 128 * KB_;  // [NR][CAP] int
static constexpr size_t OFF_SELW = OFF_SELI + 32 * KB_;  // [NR][CAP] f32
static constexpr size_t OFF_ICNT = OFF_SELW + 32 * KB_;  // [T] int
static constexpr size_t OFF_IPR  = OFF_ICNT + 32 * KB_;  // [T][2] int
static constexpr size_t OFF_COS  = OFF_IPR + 64 * KB_;   // [S][16] f32
static constexpr size_t OFF_SIN  = OFF_COS + 128 * KB_;  // [S][16] f32
static constexpr size_t OFF_WS2T = 109 * MB_;            // Ws2T bf16 2M -> ends 111M
// sub-offsets
static constexpr size_t OFF_PLAT = OFF_R2;               // [1024][768] f32 (3M)
static constexpr size_t OFF_PQC  = OFF_R2 + 3 * MB_;     // [512][1024] f32 (2M)
static constexpr size_t OFF_PKV  = OFF_R2 + 5 * MB_;     // [256][2048] f32 (2M)
// R4 internals: WoutT survives through attn; PLT/PQT/PKT dead after q/kv GEMMs
static constexpr size_t OFF_WOTH = OFF_R4;                    // 76M, 2M (needed after attn)
static constexpr size_t OFF_WOTL = OFF_R4 + 2 * MB_;          // 78M, 2M
static constexpr size_t OFF_PLTH = OFF_R4 + 4 * MB_;          // 80M, 1.5M (dead after zlat GEMM)
static constexpr size_t OFF_PLTL = OFF_R4 + 5632 * KB_;       // 81.5M
static constexpr size_t OFF_PQTH = OFF_R4 + 7 * MB_;          // 83M, 1M (dead after q GEMM)
static constexpr size_t OFF_PQTL = OFF_R4 + 8 * MB_;          // 84M
static constexpr size_t OFF_PKTH = OFF_R4 + 9 * MB_;          // 85M, 1M (dead after kv GEMM)
static constexpr size_t OFF_PKTL = OFF_R4 + 10 * MB_;         // 86M -> ends 87M
// attention bf16 planes (alive only during attn)
static constexpr size_t OFF_VTHI = OFF_R1;                    // 16M, 8M (over dead zlat)
static constexpr size_t OFF_VTLO = OFF_R4 + 4 * MB_;          // 80M, 8M (over dead PLT/PQT/PKT + free)
static constexpr size_t OFF_KHI  = OFF_X1;                    // 92M, 8M (x1 written after attn)
static constexpr size_t OFF_KLO  = OFF_X1 + 8 * MB_;          // 100M, 8M

__device__ __forceinline__ void split2(float v, bf16_t& h, bf16_t& l) {
    h = (bf16_t)v;
    l = (bf16_t)(v - (float)h);
}

// ---------------- RMSNorm: MODE 0 -> emit hi/lo bf16 planes; MODE 1 -> emit f32 + single bf16 ----------------
template <int MODE>
__global__ __launch_bounds__(256) void rmsnorm_kernel(const float* __restrict__ x,
                                                      const float* __restrict__ w,
                                                      float* __restrict__ outf,
                                                      bf16_t* __restrict__ o1,
                                                      bf16_t* __restrict__ o2) {
    int t = blockIdx.x;
    int c = threadIdx.x * 4;
    float4 f = *(const float4*)(x + (size_t)t * D_ + c);
    float ss = f.x * f.x + f.y * f.y + f.z * f.z + f.w * f.w;
#pragma unroll
    for (int off = 32; off > 0; off >>= 1) ss += __shfl_down(ss, off);
    __shared__ float red[4];
    int lane = threadIdx.x & 63, wid = threadIdx.x >> 6;
    if (lane == 0) red[wid] = ss;
    __syncthreads();
    float tot = red[0] + red[1] + red[2] + red[3];
    float inv = 1.f / sqrtf(tot * (1.f / D_) + 1e-6f);
    float4 wv = *(const float4*)(w + c);
    float v[4];
    v[0] = f.x * inv * wv.x; v[1] = f.y * inv * wv.y;
    v[2] = f.z * inv * wv.z; v[3] = f.w * inv * wv.w;
    if (MODE == 0) {
        bf16x4 hv, lv;
#pragma unroll
        for (int j = 0; j < 4; j++) { bf16_t h, l; split2(v[j], h, l); hv[j] = h; lv[j] = l; }
        *(bf16x4*)(o1 + (size_t)t * D_ + c) = hv;
        *(bf16x4*)(o2 + (size_t)t * D_ + c) = lv;
    } else {
        float4 o; o.x = v[0]; o.y = v[1]; o.z = v[2]; o.w = v[3];
        *(float4*)(outf + (size_t)t * D_ + c) = o;
        bf16x4 bv;
#pragma unroll
        for (int j = 0; j < 4; j++) bv[j] = (bf16_t)v[j];
        *(bf16x4*)(o1 + (size_t)t * D_ + c) = bv;
    }
}

// ---------------- pack fp32 attention weights into [K][N] fused layouts ----------------
__global__ __launch_bounds__(256) void pack_w_kernel(const float* __restrict__ Wq_lat, const float* __restrict__ Wkv_lat,
                                                     const float* __restrict__ Wq_up, const float* __restrict__ Wrot_q,
                                                     const float* __restrict__ Wk_up, const float* __restrict__ Wrot_k,
                                                     const float* __restrict__ Wv_up,
                                                     float* __restrict__ PLAT, float* __restrict__ PQC,
                                                     float* __restrict__ PKV) {
    int i = blockIdx.x * 256 + threadIdx.x;
    const int NL = 1024 * 768;
    const int NQ = 512 * 1024;
    if (i < NL) {
        int k = i / 768, c = i - k * 768;
        PLAT[i] = (c < 512) ? Wq_lat[k * 512 + c] : Wkv_lat[k * 256 + (c - 512)];
    } else if (i < NL + NQ) {
        int i2 = i - NL;
        int k = i2 >> 10, c = i2 & 1023, h = c >> 6, j = c & 63;
        PQC[i2] = (j < 32) ? Wq_up[k * 1024 + c] : Wrot_q[k * 1024 + h * 64 + (j - 32)];
    } else {
        int i3 = i - NL - NQ;
        int k = i3 >> 11, c = i3 & 2047;
        if (c < 1024) {
            int h = c >> 6, j = c & 63;
            PKV[i3] = (j < 32) ? Wk_up[k * 1024 + c] : Wrot_k[k * 1024 + h * 64 + (j - 32)];
        } else {
            PKV[i3] = Wv_up[k * 1024 + (c - 1024)];
        }
    }
}

// ---------------- transpose + split: in [K][N] f32 -> outhi/outlo [N][K] bf16 ----------------
__global__ __launch_bounds__(256) void packTsplit_kernel(const float* __restrict__ in,
                                                         bf16_t* __restrict__ outhi, bf16_t* __restrict__ outlo,
                                                         int K, int N) {
    __shared__ float tile[32][33];
    const int k0 = blockIdx.x * 32, n0 = blockIdx.y * 32;
    const int rr = threadIdx.x >> 5, cc = threadIdx.x & 31;
#pragma unroll
    for (int it = 0; it < 4; it++) {
        int k = k0 + rr + it * 8;
        tile[rr + it * 8][cc] = in[(size_t)k * N + n0 + cc];
    }
    __syncthreads();
#pragma unroll
    for (int it = 0; it < 4; it++) {
        int nl = n0 + rr + it * 8;
        float v = tile[cc][rr + it * 8];
        bf16_t h, l; split2(v, h, l);
        outhi[(size_t)nl * K + k0 + cc] = h;
        outlo[(size_t)nl * K + k0 + cc] = l;
    }
}

// ---------------- rope tables ----------------
__global__ __launch_bounds__(256) void rope_table_kernel(float* __restrict__ ct, float* __restrict__ st) {
    int i = blockIdx.x * 256 + threadIdx.x;   // S_*16
    if (i >= S_ * 16) return;
    int s = i >> 4, j = i & 15;
    float inv = 1.f / powf(10000.f, (float)j * (1.f / 16.f));
    float fr = (float)s * inv;
    ct[i] = cosf(fr);
    st[i] = sinf(fr);
}

// apply rope in place: q [T][1024], k = cols 0..1023 of kv [T][2048]; rot dims = h*64+32..63
__global__ __launch_bounds__(256) void rope_apply_kernel(float* __restrict__ q, float* __restrict__ kv,
                                                         const float* __restrict__ ct, const float* __restrict__ st) {
    int gid = blockIdx.x * 256 + threadIdx.x;
    if (gid >= T_ * H_) return;
    int t = gid >> 4, h = gid & 15;
    int s = t & (S_ - 1);
    float c[16], sn[16];
#pragma unroll
    for (int j = 0; j < 16; j += 4) {
        *(float4*)&c[j]  = *(const float4*)(ct + s * 16 + j);
        *(float4*)&sn[j] = *(const float4*)(st + s * 16 + j);
    }
#pragma unroll
    for (int a2 = 0; a2 < 2; a2++) {
        float* p = a2 ? (kv + (size_t)t * 2048 + h * 64 + 32)
                      : (q  + (size_t)t * 1024 + h * 64 + 32);
        float r[32], o2[32];
#pragma unroll
        for (int j2 = 0; j2 < 32; j2 += 4) *(float4*)&r[j2] = *(const float4*)(p + j2);
#pragma unroll
        for (int i = 0; i < 16; i++) {
            o2[i]      = r[i] * c[i] - r[i + 16] * sn[i];
            o2[i + 16] = r[i + 16] * c[i] + r[i] * sn[i];
        }
#pragma unroll
        for (int j2 = 0; j2 < 32; j2 += 4) *(float4*)(p + j2) = *(const float4*)&o2[j2];
    }
}

// ---------------- K planes: kv f32 [T][2048] cols h*64+d -> Khi/Klo [(b*16+h)][s][64] bf16 ----------------
__global__ __launch_bounds__(256) void kpack_kernel(const float* __restrict__ kv,
                                                    bf16_t* __restrict__ Khi, bf16_t* __restrict__ Klo) {
    int i = blockIdx.x * 256 + threadIdx.x;      // T_*1024/4 threads
    int idx = i * 4;                             // output element index
    int d = idx & 63;
    int s = (idx >> 6) & (S_ - 1);
    int bh = idx >> 17;                          // b*16+h  (2^17 = S_*64)
    int b = bh >> 4, h = bh & 15;
    size_t src = ((size_t)(b * S_ + s)) * 2048 + h * 64 + d;
    float4 v = *(const float4*)(kv + src);
    bf16x4 hv, lv; bf16_t hh, ll;
    split2(v.x, hh, ll); hv[0] = hh; lv[0] = ll;
    split2(v.y, hh, ll); hv[1] = hh; lv[1] = ll;
    split2(v.z, hh, ll); hv[2] = hh; lv[2] = ll;
    split2(v.w, hh, ll); hv[3] = hh; lv[3] = ll;
    *(bf16x4*)(Khi + idx) = hv;
    *(bf16x4*)(Klo + idx) = lv;
}

// ---------------- V planes: kv f32 [b][s][1024 + hd] -> Vthi/Vtlo [b*1024+hd][S] bf16 (transposed) ----------------
__global__ __launch_bounds__(256) void vtrans_kernel(const float* __restrict__ kv,
                                                     bf16_t* __restrict__ Vthi, bf16_t* __restrict__ Vtlo) {
    __shared__ float tile[32][33];
    const int bz = blockIdx.z;
    const int s0 = blockIdx.x * 32, hd0 = blockIdx.y * 32;
    const int rr = threadIdx.x >> 5, cc = threadIdx.x & 31;
    const float* inb = kv + (size_t)bz * S_ * 2048 + 1024;
#pragma unroll
    for (int it = 0; it < 4; it++) {
        int s = s0 + rr + it * 8;
        tile[rr + it * 8][cc] = inb[(size_t)s * 2048 + hd0 + cc];
    }
    __syncthreads();
    bf16_t* oh = Vthi + (size_t)bz * 1024 * S_;
    bf16_t* ol = Vtlo + (size_t)bz * 1024 * S_;
#pragma unroll
    for (int it = 0; it < 4; it++) {
        int hd = hd0 + rr + it * 8;
        float v = tile[cc][rr + it * 8];
        bf16_t hh, ll; split2(v, hh, ll);
        oh[(size_t)hd * S_ + s0 + cc] = hh;
        ol[(size_t)hd * S_ + s0 + cc] = ll;
    }
}

// ---------------- bf16x3 MFMA GEMM (near-fp32): C = (Ah+Al)@(Bh+Bl)^T (+resid) ----------------
// M fixed = 4096 (full rows). EMIT: 0 = f32 out, 1 = hi/lo split out.
template <bool RESID, int EMIT>
__global__ __launch_bounds__(256) void mfma3_gemm_kernel(const bf16_t* __restrict__ Ah, const bf16_t* __restrict__ Al,
                                                         const bf16_t* __restrict__ Bh, const bf16_t* __restrict__ Bl,
                                                         float* __restrict__ Cf,
                                                         bf16_t* __restrict__ Chi, bf16_t* __restrict__ Clo,
                                                         const float* __restrict__ resid,
                                                         int K, int lda, int ldc) {
    __shared__ __align__(16) bf16_t Ash[128 * 32];
    __shared__ __align__(16) bf16_t Asl[128 * 32];
    __shared__ __align__(16) bf16_t Bsh[128 * 32];
    __shared__ __align__(16) bf16_t Bsl[128 * 32];
    const int tid = threadIdx.x;
    const int lane = tid & 63, w = tid >> 6;
    const int wm = (w & 1) * 64, wn = (w >> 1) * 64;
    const int m0 = blockIdx.y * 128, n0 = blockIdx.x * 128;

    f32x4 acc[4][4];
#pragma unroll
    for (int mi = 0; mi < 4; mi++)
#pragma unroll
        for (int ni = 0; ni < 4; ni++) { f32x4 zz = {0.f, 0.f, 0.f, 0.f}; acc[mi][ni] = zz; }

    const int mrow = lane & 15, q = lane >> 4;
    for (int k0 = 0; k0 < K; k0 += 32) {
#pragma unroll
        for (int i = 0; i < 2; i++) {
            int chunk = tid + i * 256;
            int row = chunk >> 2, koff = (chunk & 3) * 8;
            size_t aoff = (size_t)(m0 + row) * lda + k0 + koff;
            size_t boff = (size_t)(n0 + row) * K + k0 + koff;
            *(uint4*)(Ash + row * 32 + koff) = *(const uint4*)(Ah + aoff);
            *(uint4*)(Asl + row * 32 + koff) = *(const uint4*)(Al + aoff);
            *(uint4*)(Bsh + row * 32 + koff) = *(const uint4*)(Bh + boff);
            *(uint4*)(Bsl + row * 32 + koff) = *(const uint4*)(Bl + boff);
        }
        __syncthreads();
        bf16x8 ah[4], al[4], bh[4], bl[4];
#pragma unroll
        for (int mi = 0; mi < 4; mi++) {
            ah[mi] = *(const bf16x8*)(Ash + (wm + mi * 16 + mrow) * 32 + q * 8);
            al[mi] = *(const bf16x8*)(Asl + (wm + mi * 16 + mrow) * 32 + q * 8);
        }
#pragma unroll
        for (int ni = 0; ni < 4; ni++) {
            bh[ni] = *(const bf16x8*)(Bsh + (wn + ni * 16 + mrow) * 32 + q * 8);
            bl[ni] = *(const bf16x8*)(Bsl + (wn + ni * 16 + mrow) * 32 + q * 8);
        }
#pragma unroll
        for (int mi = 0; mi < 4; mi++)
#pragma unroll
            for (int ni = 0; ni < 4; ni++) {
                acc[mi][ni] = __builtin_amdgcn_mfma_f32_16x16x32_bf16(al[mi], bh[ni], acc[mi][ni], 0, 0, 0);
                acc[mi][ni] = __builtin_amdgcn_mfma_f32_16x16x32_bf16(ah[mi], bl[ni], acc[mi][ni], 0, 0, 0);
                acc[mi][ni] = __builtin_amdgcn_mfma_f32_16x16x32_bf16(ah[mi], bh[ni], acc[mi][ni], 0, 0, 0);
            }
        __syncthreads();
    }
    // epilogue: C/D layout col = lane&15, row = (lane>>4)*4 + v
#pragma unroll
    for (int mi = 0; mi < 4; mi++) {
        int rbase = m0 + wm + mi * 16 + q * 4;
#pragma unroll
        for (int v = 0; v < 4; v++) {
            int r = rbase + v;
#pragma unroll
            for (int ni = 0; ni < 4; ni++) {
                int c = n0 + wn + ni * 16 + mrow;
                float val = acc[mi][ni][v];
                if (RESID) val += resid[(size_t)r * ldc + c];
                if (EMIT == 0) {
                    Cf[(size_t)r * ldc + c] = val;
                } else {
                    bf16_t h, l; split2(val, h, l);
                    Chi[(size_t)r * ldc + c] = h;
                    Clo[(size_t)r * ldc + c] = l;
                }
            }
        }
    }
}

// ---------------- MFMA flash attention (causal), bf16x3 QK / bf16x2 PV, K/V pre-split planes ----------------
// grid: 1024 = 32 q-tiles (64 rows) x 32 bh, balanced so each CU's 4 co-resident blocks sum to 66 work-units.
// 4 waves, wave w owns q rows [w*16, w*16+16). LDS: 5 x [64][64] bf16, all XOR-swizzled = 40 KB -> 4 blocks/CU.
__global__ __launch_bounds__(256, 4) void attn_mfma_kernel(const float* __restrict__ Q,
                                                        const bf16_t* __restrict__ Khig, const bf16_t* __restrict__ Klog,
                                                        const bf16_t* __restrict__ Vthig, const bf16_t* __restrict__ Vtlog,
                                                        bf16_t* __restrict__ Ohi, bf16_t* __restrict__ Olo) {
    __shared__ __align__(16) bf16_t Kh[64][64];
    __shared__ __align__(16) bf16_t Kl[64][64];
    __shared__ __align__(16) bf16_t Vth[64][64];   // Vth[d][k] (transposed), XOR-swizzled
    __shared__ __align__(16) bf16_t Vtl[64][64];
    __shared__ __align__(16) bf16_t Ph[64][64];    // P rounded to bf16, XOR-swizzled cols

    const int tid = threadIdx.x;
    const int lane = tid & 63, w = tid >> 6;
    const int mrow = lane & 15, qq = lane >> 4;
    const int j = blockIdx.x;
    // balanced (qt, bh) mapping: groups of 256; per-rank qt sums to const 66 work-units across the 4 groups
    const int g = j >> 8, c5 = j & 255, rk = c5 >> 5, bh = c5 & 31;
    const int qt = (g == 0) ? (31 - rk) : (g == 1) ? rk : (g == 2) ? (23 - rk) : (8 + rk);
    const int b = bh >> 4, h = bh & 15;
    const int q0 = qt * 64;
    const float*  Qb  = Q + (size_t)b * S_ * 1024 + h * 64;
    const bf16_t* Khb = Khig + (size_t)bh * S_ * 64;
    const bf16_t* Klb = Klog + (size_t)bh * S_ * 64;
    const bf16_t* Vhb = Vthig + (size_t)(b * 1024 + h * 64) * S_;
    const bf16_t* Vlb = Vtlog + (size_t)(b * 1024 + h * 64) * S_;

    // ---- Q fragments in registers, pre-scaled by 1/sqrt(HD)=0.125 (exact), hi/lo split ----
    bf16x8 qh[2], ql[2];                           // [ks]
    {
        int r = q0 + w * 16 + mrow;
#pragma unroll
        for (int ks = 0; ks < 2; ks++) {
            const float* p = Qb + (size_t)r * 1024 + ks * 32 + qq * 8;
            float4 a = *(const float4*)p;
            float4 b2 = *(const float4*)(p + 4);
            float vals[8] = {a.x, a.y, a.z, a.w, b2.x, b2.y, b2.z, b2.w};
#pragma unroll
            for (int jj = 0; jj < 8; jj++) {
                bf16_t hh, ll; split2(vals[jj] * 0.125f, hh, ll);
                qh[ks][jj] = hh; ql[ks][jj] = ll;
            }
        }
    }

    f32x4 acc_o[4];
    float m_r[4], l_r[4];
#pragma unroll
    for (int ni = 0; ni < 4; ni++) { f32x4 zz = {0.f, 0.f, 0.f, 0.f}; acc_o[ni] = zz; }
#pragma unroll
    for (int v = 0; v < 4; v++) { m_r[v] = -1e30f; l_r[v] = 0.f; }

    for (int kt = 0; kt <= qt; kt++) {
        const int k0 = kt * 64;
        // ---- stage K and V (both XOR-swizzled) from bf16 planes ----
#pragma unroll
        for (int i = 0; i < 2; i++) {
            int cc = tid + i * 256;                // 512 chunks of 8 bf16 per plane
            int rr = cc >> 3, c8 = (cc & 7) * 8;
            int csw = c8 ^ ((rr & 7) << 3);
            *(uint4*)&Kh[rr][csw] = *(const uint4*)(Khb + (size_t)(k0 + rr) * 64 + c8);
            *(uint4*)&Kl[rr][csw] = *(const uint4*)(Klb + (size_t)(k0 + rr) * 64 + c8);
            *(uint4*)&Vth[rr][csw] = *(const uint4*)(Vhb + (size_t)rr * S_ + k0 + c8);
            *(uint4*)&Vtl[rr][csw] = *(const uint4*)(Vlb + (size_t)rr * S_ + k0 + c8);
        }
        __syncthreads();

        // ---- S = Q @ K^T (bf16x3) ----
        f32x4 acc_s[4];
#pragma unroll
        for (int ni = 0; ni < 4; ni++) { f32x4 zz = {0.f, 0.f, 0.f, 0.f}; acc_s[ni] = zz; }
#pragma unroll
        for (int ks = 0; ks < 2; ks++) {
            const int c0 = ks * 32 + qq * 8;
            bf16x8 bhf[4], blf[4];
#pragma unroll
            for (int ni = 0; ni < 4; ni++) {
                int row = ni * 16 + mrow;
                int cs = c0 ^ ((row & 7) << 3);
                bhf[ni] = *(const bf16x8*)&Kh[row][cs];
                blf[ni] = *(const bf16x8*)&Kl[row][cs];
            }
#pragma unroll
            for (int ni = 0; ni < 4; ni++) {
                acc_s[ni] = __builtin_amdgcn_mfma_f32_16x16x32_bf16(ql[ks], bhf[ni], acc_s[ni], 0, 0, 0);
                acc_s[ni] = __builtin_amdgcn_mfma_f32_16x16x32_bf16(qh[ks], blf[ni], acc_s[ni], 0, 0, 0);
                acc_s[ni] = __builtin_amdgcn_mfma_f32_16x16x32_bf16(qh[ks], bhf[ni], acc_s[ni], 0, 0, 0);
            }
        }
        // ---- online softmax (rows: w*16 + qq*4+v; cols: ni*16+mrow) ----
        const bool diag = (kt == qt);
#pragma unroll
        for (int v = 0; v < 4; v++) {
            int rloc = w * 16 + qq * 4 + v;        // row within 64-row q tile
            float sv[4];
            float rmax = -1e30f;
#pragma unroll
            for (int ni = 0; ni < 4; ni++) {
                float s = acc_s[ni][v];
                if (diag && (ni * 16 + mrow) > rloc) s = -1e30f;
                sv[ni] = s;
                rmax = fmaxf(rmax, s);
            }
#pragma unroll
            for (int off = 1; off < 16; off <<= 1) rmax = fmaxf(rmax, __shfl_xor(rmax, off));
            float mo = m_r[v];
            float mn = fmaxf(mo, rmax);
            float al = __expf(mo - mn);
            m_r[v] = mn;
            int t7 = (rloc & 7) << 3;
            float rs = 0.f;
#pragma unroll
            for (int ni = 0; ni < 4; ni++) {
                float p = __expf(sv[ni] - mn);
                bf16_t ph = (bf16_t)p;
                Ph[rloc][(ni * 16 + mrow) ^ t7] = ph;
                rs += (float)ph;                   // denominator from same rounded P -> consistent weights
            }
#pragma unroll
            for (int off = 1; off < 16; off <<= 1) rs += __shfl_xor(rs, off);
            l_r[v] = l_r[v] * al + rs;
#pragma unroll
            for (int ni = 0; ni < 4; ni++) acc_o[ni][v] *= al;
        }
        // ---- O += P @ V (bf16x2: P@Vl + P@Vh). P rows read by owning wave only. ----
#pragma unroll
        for (int ks = 0; ks < 2; ks++) {
            const int rc = ks * 32 + qq * 8;
            bf16x8 pah, vhf[4], vlf[4];
            {
                int rowp = w * 16 + mrow;
                int cp = rc ^ ((rowp & 7) << 3);
                pah = *(const bf16x8*)&Ph[rowp][cp];
            }
#pragma unroll
            for (int ni = 0; ni < 4; ni++) {
                int cv = ni * 16 + mrow;
                int vs = rc ^ ((cv & 7) << 3);
                vhf[ni] = *(const bf16x8*)&Vth[cv][vs];
                vlf[ni] = *(const bf16x8*)&Vtl[cv][vs];
            }
#pragma unroll
            for (int ni = 0; ni < 4; ni++) {
                acc_o[ni] = __builtin_amdgcn_mfma_f32_16x16x32_bf16(pah, vlf[ni], acc_o[ni], 0, 0, 0);
                acc_o[ni] = __builtin_amdgcn_mfma_f32_16x16x32_bf16(pah, vhf[ni], acc_o[ni], 0, 0, 0);
            }
        }
        __syncthreads();
    }
    // ---- epilogue: normalize, split hi/lo, store ----
#pragma unroll
    for (int v = 0; v < 4; v++) {
        int rq = q0 + w * 16 + qq * 4 + v;
        float inv = 1.f / l_r[v];
        size_t base = (size_t)(b * S_ + rq) * 1024 + h * 64;
#pragma unroll
        for (int ni = 0; ni < 4; ni++) {
            float val = acc_o[ni][v] * inv;
            bf16_t hh, ll; split2(val, hh, ll);
            Ohi[base + ni * 16 + mrow] = hh;
            Olo[base + ni * 16 + mrow] = ll;
        }
    }
}

// ---------------- gate: affinities + top-2 membership -> priority [NR][T] ----------------
__global__ __launch_bounds__(256) void gate_kernel(const float* __restrict__ xn2, const float* __restrict__ Wg,
                                                   const float* __restrict__ bias, float* __restrict__ pri) {
    __shared__ float red[256][8];
    int t = blockIdx.x, tid = threadIdx.x;
    float acc[7] = {0.f, 0.f, 0.f, 0.f, 0.f, 0.f, 0.f};
    for (int d = tid; d < D_; d += 256) {
        float xv = xn2[(size_t)t * D_ + d];
        const float* wr = Wg + d * 7;
#pragma unroll
        for (int e = 0; e < 7; e++) acc[e] = fmaf(xv, wr[e], acc[e]);
    }
#pragma unroll
    for (int e = 0; e < 7; e++) red[tid][e] = acc[e];
    __syncthreads();
    for (int s2 = 128; s2 > 0; s2 >>= 1) {
        if (tid < s2) {
#pragma unroll
            for (int e = 0; e < 7; e++) red[tid][e] += red[tid + s2][e];
        }
        __syncthreads();
    }
    if (tid == 0) {
        float a[7];
#pragma unroll
        for (int e = 0; e < 7; e++) a[e] = 1.f / (1.f + expf(-(red[0][e] + bias[e])));
        int e1 = 0;
#pragma unroll
        for (int e = 1; e < 7; e++) if (a[e] > a[e1]) e1 = e;     // strict > : lowest-index tiebreak
        int e2 = -1;
#pragma unroll
        for (int e = 0; e < 7; e++) if (e != e1 && (e2 < 0 || a[e] > a[e2])) e2 = e;
#pragma unroll
        for (int e = 0; e < 7; e++) pri[(size_t)e * T_ + t] = (e == e1 || e == e2) ? a[e] : -1.f;
    }
}

// ---------------- exact top-585: 32-step binary threshold search, 1 barrier/bit, ballot tie-rank ----------------
// Tie-break order (slot i, wave wid, lane) == idx order (idx = i*1024 + wid*64 + lane) -> matches stable top_k.
__global__ __launch_bounds__(1024) void select_kernel(const float* __restrict__ pri, int* __restrict__ sel_idx,
                                                      float* __restrict__ sel_w, int* __restrict__ inv_cnt,
                                                      int* __restrict__ inv_pair) {
    __shared__ int wcnt[2][16];     // parity double-buffered per-wave counts
    __shared__ int wtot[4][16];     // eq-to-threshold counts per (slot, wave)
    __shared__ int wpre[4][16];     // exclusive prefix of wtot in (slot-major, wave) order
    __shared__ int ctr;
    const int e = blockIdx.x, tid = threadIdx.x;
    const int lane = tid & 63, wid = tid >> 6;

    u32 myk[4];
#pragma unroll
    for (int i = 0; i < 4; i++) {
        float pv = pri[(size_t)e * T_ + tid + i * 1024];
        myk[i] = (pv > 0.f) ? __float_as_uint(pv) : 0u;
    }
    if (tid == 0) ctr = 0;

    // binary search: p = max t with count(keys >= t) >= CAP.  One barrier per bit.
    // Buffer parity alternates; reuse of a buffer is separated by the intervening iteration's barrier.
    u32 p = 0;
    for (int b = 31; b >= 0; b--) {
        u32 t = p | (1u << b);
        int cnt = 0;
#pragma unroll
        for (int i = 0; i < 4; i++) cnt += (myk[i] >= t) ? 1 : 0;
#pragma unroll
        for (int off = 32; off > 0; off >>= 1) cnt += __shfl_xor(cnt, off);
        if (lane == 0) wcnt[b & 1][wid] = cnt;
        __syncthreads();
        int tot = 0;
#pragma unroll
        for (int k2 = 0; k2 < 16; k2++) tot += wcnt[b & 1][k2];
        if (tot >= CAP_) p = t;
    }
    // count strictly greater (buffer 1: last written at b=1, safe — b=0's barrier separates)
    int cntGT;
    {
        int cnt = 0;
#pragma unroll
        for (int i = 0; i < 4; i++) cnt += (myk[i] > p) ? 1 : 0;
#pragma unroll
        for (int off = 32; off > 0; off >>= 1) cnt += __shfl_xor(cnt, off);
        if (lane == 0) wcnt[1][wid] = cnt;
        __syncthreads();
        int g2 = 0;
#pragma unroll
        for (int k2 = 0; k2 < 16; k2++) g2 += wcnt[1][k2];
        cntGT = g2;
    }
    int quota = CAP_ - cntGT;   // slots left for keys == p (>=1 when p>0)

    // ballot-based rank among keys == p, in idx order (slot-major, wave, lane)
    int eqpre[4];
#pragma unroll
    for (int i = 0; i < 4; i++) {
        bool eq = (myk[i] == p) && (p != 0u);
        u64 mask = __ballot(eq);
        eqpre[i] = (int)__popcll(mask & ((1ull << lane) - 1ull));
        if (lane == 0) wtot[i][wid] = (int)__popcll(mask);
    }
    __syncthreads();
    if (tid < 64) {
        int v = wtot[tid >> 4][tid & 15];
        int inc = v;
#pragma unroll
        for (int off = 1; off < 64; off <<= 1) {
            int n = __shfl_up(inc, off);
            if (lane >= off) inc += n;
        }
        wpre[tid >> 4][tid & 15] = inc - v;    // exclusive prefix
    }
    __syncthreads();

    // assignment: kept = (k > p) or (k == p, p>0, rank < quota)
#pragma unroll
    for (int i = 0; i < 4; i++) {
        int idx = tid + i * 1024;
        u32 k = myk[i];
        bool kept = (k > p);
        if (!kept && k == p && p != 0u) kept = (wpre[i][wid] + eqpre[i] < quota);
        if (kept) {
            int s = atomicAdd(&ctr, 1);
            sel_idx[e * CAP_ + s] = idx;
            sel_w[e * CAP_ + s] = __uint_as_float(k);
            int pos = atomicAdd(&inv_cnt[idx], 1);
            inv_pair[idx * 2 + pos] = e * CAP_ + s;
        }
    }
    __syncthreads();
    for (int s = ctr + tid; s < CAP_; s += 1024) {  // unfilled slots -> token 0, weight 0
        sel_idx[e * CAP_ + s] = 0;
        sel_w[e * CAP_ + s] = 0.f;
    }
}

// ---------------- transpose + convert: out[z][n][k] = (bf16) in[z][k][nbase+n] ----------------
__global__ __launch_bounds__(256) void packT_kernel(const float* __restrict__ in, bf16_t* __restrict__ out,
                                                    int K, int N, int nbase,
                                                    long long inStride, long long outStride) {
    __shared__ float tile[32][33];
    const int z = blockIdx.z;
    const int k0 = blockIdx.x * 32, n0 = blockIdx.y * 32;
    const int rr = threadIdx.x >> 5, cc = threadIdx.x & 31;
    const float* inz = in + (size_t)z * inStride;
#pragma unroll
    for (int it = 0; it < 4; it++) {
        int k = k0 + rr + it * 8;
        tile[rr + it * 8][cc] = inz[(size_t)k * N + nbase + n0 + cc];
    }
    __syncthreads();
    bf16_t* outz = out + (size_t)z * outStride;
#pragma unroll
    for (int it = 0; it < 4; it++) {
        int nl = n0 + rr + it * 8;
        outz[(size_t)nl * K + k0 + cc] = (bf16_t)tile[cc][rr + it * 8];
    }
}

// ---------------- bf16 MFMA GEMM (single precision pass, experts): C = gather(A) @ Bt^T (*scale) ----------------
template <bool GATHER, bool SCALE, bool OUTBF16>
__global__ __launch_bounds__(256) void mfma_gemm_kernel(const bf16_t* __restrict__ A, const bf16_t* __restrict__ Bt,
                                                        void* __restrict__ Cv,
                                                        const int* __restrict__ gidx, const float* __restrict__ scale,
                                                        int M, int K, int lda, int ldc,
                                                        long long strideA, long long strideBt, long long strideC,
                                                        int gstride) {
    __shared__ __align__(16) bf16_t As[128 * 32];
    __shared__ __align__(16) bf16_t Bs[128 * 32];
    const int tid = threadIdx.x;
    const int lane = tid & 63, w = tid >> 6;
    const int wm = (w & 1) * 64, wn = (w >> 1) * 64;
    const int z = blockIdx.z;
    const int m0 = blockIdx.y * 128, n0 = blockIdx.x * 128;
    const bf16_t* Az = A + (GATHER ? 0 : (size_t)z * strideA);
    const bf16_t* Bz = Bt + (size_t)z * strideBt;

    int arow[2];
#pragma unroll
    for (int i = 0; i < 2; i++) {
        int chunk = tid + i * 256;
        int r = m0 + (chunk >> 2);
        if (r > M - 1) r = M - 1;
        arow[i] = GATHER ? gidx[z * gstride + r] : r;
    }

    f32x4 acc[4][4];
#pragma unroll
    for (int mi = 0; mi < 4; mi++)
#pragma unroll
        for (int ni = 0; ni < 4; ni++) { f32x4 zz = {0.f, 0.f, 0.f, 0.f}; acc[mi][ni] = zz; }

    const int mrow = lane & 15, q = lane >> 4;
    for (int k0 = 0; k0 < K; k0 += 32) {
#pragma unroll
        for (int i = 0; i < 2; i++) {
            int chunk = tid + i * 256;
            int row = chunk >> 2, koff = (chunk & 3) * 8;
            *(uint4*)(As + row * 32 + koff) = *(const uint4*)(Az + (size_t)arow[i] * lda + k0 + koff);
            *(uint4*)(Bs + row * 32 + koff) = *(const uint4*)(Bz + (size_t)(n0 + row) * K + k0 + koff);
        }
        __syncthreads();
        bf16x8 af[4], bfr[4];
#pragma unroll
        for (int mi = 0; mi < 4; mi++)
            af[mi] = *(const bf16x8*)(As + (wm + mi * 16 + mrow) * 32 + q * 8);
#pragma unroll
        for (int ni = 0; ni < 4; ni++)
            bfr[ni] = *(const bf16x8*)(Bs + (wn + ni * 16 + mrow) * 32 + q * 8);
#pragma unroll
        for (int mi = 0; mi < 4; mi++)
#pragma unroll
            for (int ni = 0; ni < 4; ni++)
                acc[mi][ni] = __builtin_amdgcn_mfma_f32_16x16x32_bf16(af[mi], bfr[ni], acc[mi][ni], 0, 0, 0);
        __syncthreads();
    }
#pragma unroll
    for (int mi = 0; mi < 4; mi++) {
        int rbase = m0 + wm + mi * 16 + q * 4;
#pragma unroll
        for (int v = 0; v < 4; v++) {
            int r = rbase + v;
            if (r < M) {
                float sc = SCALE ? scale[z * gstride + r] : 1.f;
#pragma unroll
                for (int ni = 0; ni < 4; ni++) {
                    int c = n0 + wn + ni * 16 + mrow;
                    float val = acc[mi][ni][v];
                    if (SCALE) val *= sc;
                    size_t off = (size_t)z * strideC + (size_t)r * ldc + c;
                    if (OUTBF16) ((bf16_t*)Cv)[off] = (bf16_t)val;
                    else         ((float*)Cv)[off] = val;
                }
            }
        }
    }
}

// ---------------- SwiGLU elementwise ----------------
__global__ __launch_bounds__(256) void swiglu_kernel(const bf16_t* __restrict__ h, bf16_t* __restrict__ act,
                                                     int rows) {
    int i8 = blockIdx.x * 256 + threadIdx.x;
    int total = rows * 128;
    if (i8 >= total) return;
    int r = i8 >> 7, f = (i8 & 127) * 8;
    bf16x8 h1 = *(const bf16x8*)(h + (size_t)r * 2048 + f);
    bf16x8 h2 = *(const bf16x8*)(h + (size_t)r * 2048 + 1024 + f);
    bf16x8 o;
#pragma unroll
    for (int j = 0; j < 8; j++) {
        float a = (float)h1[j], g = (float)h2[j];
        o[j] = (bf16_t)(a * g / (1.f + __expf(-g)));
    }
    *(bf16x8*)(act + (size_t)r * 1024 + f) = o;
}

// ---------------- final combine: out = x1 + shared + sum routed ----------------
__global__ __launch_bounds__(256) void final_kernel(const float* __restrict__ x1, const float* __restrict__ sh,
                                                    const float* __restrict__ eout, const int* __restrict__ icnt,
                                                    const int* __restrict__ ipair, float* __restrict__ out) {
    int t = blockIdx.x, c = threadIdx.x * 4;
    float4 v = *(const float4*)(x1 + (size_t)t * D_ + c);
    float4 s2 = *(const float4*)(sh + (size_t)t * D_ + c);
    v.x += s2.x; v.y += s2.y; v.z += s2.z; v.w += s2.w;
    int n = icnt[t];
    for (int p = 0; p < n; p++) {
        int row = ipair[t * 2 + p];
        float4 ev = *(const float4*)(eout + (size_t)row * D_ + c);
        v.x += ev.x; v.y += ev.y; v.z += ev.z; v.w += ev.w;
    }
    *(float4*)(out + (size_t)t * D_ + c) = v;
}

// ---------------- launch ----------------
extern "C" void kernel_launch(void* const* d_in, const int* in_sizes, int n_in,
                              void* d_out, int out_size, void* d_ws, size_t ws_size,
                              hipStream_t stream) {
    (void)in_sizes; (void)n_in; (void)out_size; (void)ws_size;
    const float* x       = (const float*)d_in[0];
    const float* Wq_lat  = (const float*)d_in[2];
    const float* Wkv_lat = (const float*)d_in[3];
    const float* Wrot_q  = (const float*)d_in[4];
    const float* Wrot_k  = (const float*)d_in[5];
    const float* Wq_up   = (const float*)d_in[6];
    const float* Wk_up   = (const float*)d_in[7];
    const float* Wv_up   = (const float*)d_in[8];
    const float* Wout    = (const float*)d_in[9];
    const float* n1w     = (const float*)d_in[10];
    const float* n2w     = (const float*)d_in[11];
    const float* Ws1     = (const float*)d_in[12];
    const float* Ws2     = (const float*)d_in[13];
    const float* Wr1     = (const float*)d_in[14];
    const float* Wr2     = (const float*)d_in[15];
    const float* Wgate   = (const float*)d_in[16];
    const float* ebias   = (const float*)d_in[17];
    float* out = (float*)d_out;

    char* wsb = (char*)d_ws;
    // phase-1 pointers
    bf16_t* xnhi = (bf16_t*)(wsb + OFF_R0);
    bf16_t* xnlo = (bf16_t*)(wsb + OFF_R0 + 8 * MB_);
    bf16_t* zlhi = (bf16_t*)(wsb + OFF_R1);
    bf16_t* zllo = (bf16_t*)(wsb + OFF_R1 + 6 * MB_);
    float*  plat = (float*)(wsb + OFF_PLAT);
    float*  pqc  = (float*)(wsb + OFF_PQC);
    float*  pkv  = (float*)(wsb + OFF_PKV);
    bf16_t* plth = (bf16_t*)(wsb + OFF_PLTH);
    bf16_t* pltl = (bf16_t*)(wsb + OFF_PLTL);
    bf16_t* pqth = (bf16_t*)(wsb + OFF_PQTH);
    bf16_t* pqtl = (bf16_t*)(wsb + OFF_PQTL);
    bf16_t* pkth = (bf16_t*)(wsb + OFF_PKTH);
    bf16_t* pktl = (bf16_t*)(wsb + OFF_PKTL);
    bf16_t* woth = (bf16_t*)(wsb + OFF_WOTH);
    bf16_t* wotl = (bf16_t*)(wsb + OFF_WOTL);
    float*  qb   = (float*)(wsb + OFF_R2);
    float*  kvb  = (float*)(wsb + OFF_R3);
    bf16_t* khig = (bf16_t*)(wsb + OFF_KHI);
    bf16_t* klog = (bf16_t*)(wsb + OFF_KLO);
    bf16_t* vthig = (bf16_t*)(wsb + OFF_VTHI);
    bf16_t* vtlog = (bf16_t*)(wsb + OFF_VTLO);
    bf16_t* atth = (bf16_t*)(wsb + OFF_R0);            // att splits reuse R0 (xn dead after zlat GEMM)
    bf16_t* attl = (bf16_t*)(wsb + OFF_R0 + 8 * MB_);
    float*  x1   = (float*)(wsb + OFF_X1);
    float*  cost = (float*)(wsb + OFF_COS);
    float*  sint = (float*)(wsb + OFF_SIN);
    // phase-2 pointers
    float*  xn2  = (float*)(wsb + OFF_R0);             // f32 for gate (att splits dead after Wout GEMM)
    bf16_t* Wr2T = (bf16_t*)(wsb + OFF_R0);            // after gate
    bf16_t* xnb  = (bf16_t*)(wsb + OFF_R1);
    bf16_t* Ws1T = (bf16_t*)(wsb + OFF_R1 + 8 * MB_);
    bf16_t* hbuf = (bf16_t*)(wsb + OFF_R2);
    bf16_t* actb = (bf16_t*)(wsb + OFF_R3);
    float*  eout = (float*)(wsb + OFF_R3 + 8 * MB_);
    bf16_t* Wr1H = (bf16_t*)(wsb + OFF_R4);
    float*  shout = (float*)(wsb + OFF_R4);
    bf16_t* Ws2T = (bf16_t*)(wsb + OFF_WS2T);
    float*  pri  = (float*)(wsb + OFF_PRI);
    int*    seli = (int*)(wsb + OFF_SELI);
    float*  selw = (float*)(wsb + OFF_SELW);
    int*    icnt = (int*)(wsb + OFF_ICNT);
    int*    ipr  = (int*)(wsb + OFF_IPR);

    // --- sublayer 1: attention path (bf16x3 MFMA GEMMs, MFMA flash attention) ---
    rmsnorm_kernel<0><<<T_, 256, 0, stream>>>(x, n1w, nullptr, xnhi, xnlo);
    pack_w_kernel<<<7168, 256, 0, stream>>>(Wq_lat, Wkv_lat, Wq_up, Wrot_q, Wk_up, Wrot_k, Wv_up,
                                            plat, pqc, pkv);
    rope_table_kernel<<<(S_ * 16) / 256, 256, 0, stream>>>(cost, sint);
    packTsplit_kernel<<<dim3(32, 24), 256, 0, stream>>>(plat, plth, pltl, 1024, 768);
    packTsplit_kernel<<<dim3(16, 32), 256, 0, stream>>>(pqc, pqth, pqtl, 512, 1024);
    packTsplit_kernel<<<dim3(8, 64), 256, 0, stream>>>(pkv, pkth, pktl, 256, 2048);
    packTsplit_kernel<<<dim3(32, 32), 256, 0, stream>>>(Wout, woth, wotl, 1024, 1024);
    // zlat = xn @ PLAT : 4096x768x1024, split output
    mfma3_gemm_kernel<false, 1><<<dim3(6, 32), 256, 0, stream>>>(
        xnhi, xnlo, plth, pltl, nullptr, zlhi, zllo, nullptr, 1024, 1024, 768);
    // q = zlat[:, :512] @ PQC : 4096x1024x512, f32 out
    mfma3_gemm_kernel<false, 0><<<dim3(8, 32), 256, 0, stream>>>(
        zlhi, zllo, pqth, pqtl, qb, nullptr, nullptr, nullptr, 512, 768, 1024);
    // k|v = zlat[:, 512:768] @ PKV : 4096x2048x256, f32 out
    mfma3_gemm_kernel<false, 0><<<dim3(16, 32), 256, 0, stream>>>(
        zlhi + 512, zllo + 512, pkth, pktl, kvb, nullptr, nullptr, nullptr, 256, 768, 2048);
    rope_apply_kernel<<<(T_ * H_) / 256, 256, 0, stream>>>(qb, kvb, cost, sint);
    // pre-split K/V to bf16 hi/lo planes (hoists conversion out of the flash loop)
    kpack_kernel<<<(T_ * 1024 / 4) / 256, 256, 0, stream>>>(kvb, khig, klog);
    vtrans_kernel<<<dim3(64, 32, 2), 256, 0, stream>>>(kvb, vthig, vtlog);
    attn_mfma_kernel<<<dim3(1024), 256, 0, stream>>>(qb, khig, klog, vthig, vtlog, atth, attl);
    // x1 = att @ Wout + x : 4096x1024x1024
    mfma3_gemm_kernel<true, 0><<<dim3(8, 32), 256, 0, stream>>>(
        atth, attl, woth, wotl, x1, nullptr, nullptr, x, 1024, 1024, 1024);

    // --- sublayer 2: MoE ---
    rmsnorm_kernel<1><<<T_, 256, 0, stream>>>(x1, n2w, xn2, xnb, nullptr);
    hipMemsetAsync(icnt, 0, T_ * sizeof(int), stream);
    gate_kernel<<<T_, 256, 0, stream>>>(xn2, Wgate, ebias, pri);           // fp32 gate
    select_kernel<<<NR_, 1024, 0, stream>>>(pri, seli, selw, icnt, ipr);   // exact top-CAP

    // weight packs (R0 free after gate)
    packT_kernel<<<dim3(32, 32, 7), 256, 0, stream>>>(Wr2, Wr2T, 1024, 1024, 0,
                                                      (long long)1024 * 1024, (long long)1024 * 1024);
    packT_kernel<<<dim3(32, 64, 1), 256, 0, stream>>>(Ws1, Ws1T, 1024, 2048, 0, 0, 0);
    packT_kernel<<<dim3(32, 32, 1), 256, 0, stream>>>(Ws2, Ws2T, 1024, 1024, 0, 0, 0);

    // routed experts (Wr1 halves staged through R4)
    packT_kernel<<<dim3(32, 32, 7), 256, 0, stream>>>(Wr1, Wr1H, 1024, 2048, 0,
                                                      (long long)1024 * 2048, (long long)1024 * 1024);
    mfma_gemm_kernel<true, false, true><<<dim3(8, 5, 7), 256, 0, stream>>>(
        xnb, Wr1H, hbuf, seli, nullptr, CAP_, 1024, 1024, 2048,
        0, (long long)1024 * 1024, (long long)CAP_ * 2048, CAP_);
    packT_kernel<<<dim3(32, 32, 7), 256, 0, stream>>>(Wr1, Wr1H, 1024, 2048, 1024,
                                                      (long long)1024 * 2048, (long long)1024 * 1024);
    mfma_gemm_kernel<true, false, true><<<dim3(8, 5, 7), 256, 0, stream>>>(
        xnb, Wr1H, hbuf + 1024, seli, nullptr, CAP_, 1024, 1024, 2048,
        0, (long long)1024 * 1024, (long long)CAP_ * 2048, CAP_);
    swiglu_kernel<<<(NR_ * CAP_ * 128 + 255) / 256, 256, 0, stream>>>(hbuf, actb, NR_ * CAP_);
    mfma_gemm_kernel<false, true, false><<<dim3(8, 5, 7), 256, 0, stream>>>(
        actb, Wr2T, eout, nullptr, selw, CAP_, 1024, 1024, 1024,
        (long long)CAP_ * 1024, (long long)1024 * 1024, (long long)CAP_ * 1024, CAP_);

    // shared expert (R4 free -> shout)
    mfma_gemm_kernel<false, false, true><<<dim3(16, 32, 1), 256, 0, stream>>>(
        xnb, Ws1T, hbuf, nullptr, nullptr, T_, 1024, 1024, 2048, 0, 0, 0, 0);
    swiglu_kernel<<<(T_ * 128 + 255) / 256, 256, 0, stream>>>(hbuf, actb, T_);
    mfma_gemm_kernel<false, false, false><<<dim3(8, 32, 1), 256, 0, stream>>>(
        actb, Ws2T, shout, nullptr, nullptr, T_, 1024, 1024, 1024, 0, 0, 0, 0);

    // combine
    final_kernel<<<T_, 256, 0, stream>>>(x1, shout, eout, icnt, ipr, out);
}

// Round 7
// 689.077 us; speedup vs baseline: 1.2276x; 1.0115x over previous
//
#include <hip/hip_runtime.h>
#include <cstdint>
#include <cstddef>

// ---------------- static problem config ----------------
#define B_   2
#define S_   2048
#define D_   1024
#define T_   4096          // B*S
#define H_   16
#define HD_  64
#define LQ_  512
#define LKV_ 256
#define FF_  1024
#define NR_  7
#define CAP_ 585

typedef unsigned int   u32;
typedef unsigned long long u64;
typedef __bf16 bf16_t;
typedef __bf16 bf16x8 __attribute__((ext_vector_type(8)));
typedef __bf16 bf16x4 __attribute__((ext_vector_type(4)));
typedef float  f32x4  __attribute__((ext_vector_type(4)));

// async global->LDS, 16B per lane; LDS dest must be wave-uniform base + lane*16 (linear layouts only)
#define GLL16(g, l) __builtin_amdgcn_global_load_lds((__attribute__((address_space(1))) const void*)(g), \
                                                     (__attribute__((address_space(3))) void*)(l), 16, 0, 0)

// ---------------- workspace layout (bytes), regions phase-reused, ~111 MB ----------------
static constexpr size_t MB_ = 1024 * 1024;
static constexpr size_t KB_ = 1024;
// R0 0-16M: xn hi(8M)+lo(8M) -> att hi+lo -> xn2 f32 -> Wr2T bf16 (14.7M)
static constexpr size_t OFF_R0   = 0;
// R1 16-28M: zlat hi(6M)+lo(6M) -> Vthi bf16 8M (attn) -> xnb bf16 8M + Ws1T 4M
static constexpr size_t OFF_R1   = 16 * MB_;
// R2 28-44M: PLAT/PQC/PKV f32 temps (7M) -> q f32 16M -> hbuf bf16 16M
static constexpr size_t OFF_R2   = 28 * MB_;
// R3 44-76M: kv f32 32M -> actb bf16 8M + eout f32 16.8M
static constexpr size_t OFF_R3   = 44 * MB_;
// R4 76-92M: WoutT splits (4M) + packT temps -> Vtlo (8M @ 80M) -> Wr1H bf16 14.7M -> shout f32 16M
static constexpr size_t OFF_R4   = 76 * MB_;
static constexpr size_t OFF_X1   = 92 * MB_;             // Khi/Klo (attn) -> [T][D] f32 x1
static constexpr size_t OFF_PRI  = 108 * MB_;            // [NR][T] f32 (128K)
static constexpr size_t OFF_SELI = OFF_PRI + 128 * KB_;  // [NR][CAP] int
static constexpr size_t OFF_SELW = OFF_SELI + 32 * KB_;  // [NR][CAP] f32
static constexpr size_t OFF_ICNT = OFF_SELW + 32 * KB_;  // [T] int
static constexpr size_t OFF_IPR  = OFF_ICNT + 32 * KB_;  // [T][2] int
static constexpr size_t OFF_COS  = OFF_IPR + 64 * KB_;   // [S][16] f32
static constexpr size_t OFF_SIN  = OFF_COS + 128 * KB_;  // [S][16] f32
static constexpr size_t OFF_WS2T = 109 * MB_;            // Ws2T bf16 2M -> ends 111M
// sub-offsets
static constexpr size_t OFF_PLAT = OFF_R2;               // [1024][768] f32 (3M)
static constexpr size_t OFF_PQC  = OFF_R2 + 3 * MB_;     // [512][1024] f32 (2M)
static constexpr size_t OFF_PKV  = OFF_R2 + 5 * MB_;     // [256][2048] f32 (2M)
// R4 internals: WoutT survives through attn; PLT/PQT/PKT dead after q/kv GEMMs
static constexpr size_t OFF_WOTH = OFF_R4;                    // 76M, 2M (needed after attn)
static constexpr size_t OFF_WOTL = OFF_R4 + 2 * MB_;          // 78M, 2M
static constexpr size_t OFF_PLTH = OFF_R4 + 4 * MB_;          // 80M, 1.5M (dead after zlat GEMM)
static constexpr size_t OFF_PLTL = OFF_R4 + 5632 * KB_;       // 81.5M
static constexpr size_t OFF_PQTH = OFF_R4 + 7 * MB_;          // 83M, 1M (dead after q GEMM)
static constexpr size_t OFF_PQTL = OFF_R4 + 8 * MB_;          // 84M
static constexpr size_t OFF_PKTH = OFF_R4 + 9 * MB_;          // 85M, 1M (dead after kv GEMM)
static constexpr size_t OFF_PKTL = OFF_R4 + 10 * MB_;         // 86M -> ends 87M
// attention bf16 planes (alive only during attn)
static constexpr size_t OFF_VTHI = OFF_R1;                    // 16M, 8M (over dead zlat)
static constexpr size_t OFF_VTLO = OFF_R4 + 4 * MB_;          // 80M, 8M (over dead PLT/PQT/PKT + free)
static constexpr size_t OFF_KHI  = OFF_X1;                    // 92M, 8M (x1 written after attn)
static constexpr size_t OFF_KLO  = OFF_X1 + 8 * MB_;          // 100M, 8M

__device__ __forceinline__ void split2(float v, bf16_t& h, bf16_t& l) {
    h = (bf16_t)v;
    l = (bf16_t)(v - (float)h);
}

// ---------------- RMSNorm: MODE 0 -> emit hi/lo bf16 planes; MODE 1 -> emit f32 + single bf16 ----------------
template <int MODE>
__global__ __launch_bounds__(256) void rmsnorm_kernel(const float* __restrict__ x,
                                                      const float* __restrict__ w,
                                                      float* __restrict__ outf,
                                                      bf16_t* __restrict__ o1,
                                                      bf16_t* __restrict__ o2) {
    int t = blockIdx.x;
    int c = threadIdx.x * 4;
    float4 f = *(const float4*)(x + (size_t)t * D_ + c);
    float ss = f.x * f.x + f.y * f.y + f.z * f.z + f.w * f.w;
#pragma unroll
    for (int off = 32; off > 0; off >>= 1) ss += __shfl_down(ss, off);
    __shared__ float red[4];
    int lane = threadIdx.x & 63, wid = threadIdx.x >> 6;
    if (lane == 0) red[wid] = ss;
    __syncthreads();
    float tot = red[0] + red[1] + red[2] + red[3];
    float inv = 1.f / sqrtf(tot * (1.f / D_) + 1e-6f);
    float4 wv = *(const float4*)(w + c);
    float v[4];
    v[0] = f.x * inv * wv.x; v[1] = f.y * inv * wv.y;
    v[2] = f.z * inv * wv.z; v[3] = f.w * inv * wv.w;
    if (MODE == 0) {
        bf16x4 hv, lv;
#pragma unroll
        for (int j = 0; j < 4; j++) { bf16_t h, l; split2(v[j], h, l); hv[j] = h; lv[j] = l; }
        *(bf16x4*)(o1 + (size_t)t * D_ + c) = hv;
        *(bf16x4*)(o2 + (size_t)t * D_ + c) = lv;
    } else {
        float4 o; o.x = v[0]; o.y = v[1]; o.z = v[2]; o.w = v[3];
        *(float4*)(outf + (size_t)t * D_ + c) = o;
        bf16x4 bv;
#pragma unroll
        for (int j = 0; j < 4; j++) bv[j] = (bf16_t)v[j];
        *(bf16x4*)(o1 + (size_t)t * D_ + c) = bv;
    }
}

// ---------------- pack fp32 attention weights into [K][N] fused layouts ----------------
__global__ __launch_bounds__(256) void pack_w_kernel(const float* __restrict__ Wq_lat, const float* __restrict__ Wkv_lat,
                                                     const float* __restrict__ Wq_up, const float* __restrict__ Wrot_q,
                                                     const float* __restrict__ Wk_up, const float* __restrict__ Wrot_k,
                                                     const float* __restrict__ Wv_up,
                                                     float* __restrict__ PLAT, float* __restrict__ PQC,
                                                     float* __restrict__ PKV) {
    int i = blockIdx.x * 256 + threadIdx.x;
    const int NL = 1024 * 768;
    const int NQ = 512 * 1024;
    if (i < NL) {
        int k = i / 768, c = i - k * 768;
        PLAT[i] = (c < 512) ? Wq_lat[k * 512 + c] : Wkv_lat[k * 256 + (c - 512)];
    } else if (i < NL + NQ) {
        int i2 = i - NL;
        int k = i2 >> 10, c = i2 & 1023, h = c >> 6, j = c & 63;
        PQC[i2] = (j < 32) ? Wq_up[k * 1024 + c] : Wrot_q[k * 1024 + h * 64 + (j - 32)];
    } else {
        int i3 = i - NL - NQ;
        int k = i3 >> 11, c = i3 & 2047;
        if (c < 1024) {
            int h = c >> 6, j = c & 63;
            PKV[i3] = (j < 32) ? Wk_up[k * 1024 + c] : Wrot_k[k * 1024 + h * 64 + (j - 32)];
        } else {
            PKV[i3] = Wv_up[k * 1024 + (c - 1024)];
        }
    }
}

// ---------------- transpose + split: in [K][N] f32 -> outhi/outlo [N][K] bf16 ----------------
__global__ __launch_bounds__(256) void packTsplit_kernel(const float* __restrict__ in,
                                                         bf16_t* __restrict__ outhi, bf16_t* __restrict__ outlo,
                                                         int K, int N) {
    __shared__ float tile[32][33];
    const int k0 = blockIdx.x * 32, n0 = blockIdx.y * 32;
    const int rr = threadIdx.x >> 5, cc = threadIdx.x & 31;
#pragma unroll
    for (int it = 0; it < 4; it++) {
        int k = k0 + rr + it * 8;
        tile[rr + it * 8][cc] = in[(size_t)k * N + n0 + cc];
    }
    __syncthreads();
#pragma unroll
    for (int it = 0; it < 4; it++) {
        int nl = n0 + rr + it * 8;
        float v = tile[cc][rr + it * 8];
        bf16_t h, l; split2(v, h, l);
        outhi[(size_t)nl * K + k0 + cc] = h;
        outlo[(size_t)nl * K + k0 + cc] = l;
    }
}

// ---------------- rope tables ----------------
__global__ __launch_bounds__(256) void rope_table_kernel(float* __restrict__ ct, float* __restrict__ st) {
    int i = blockIdx.x * 256 + threadIdx.x;   // S_*16
    if (i >= S_ * 16) return;
    int s = i >> 4, j = i & 15;
    float inv = 1.f / powf(10000.f, (float)j * (1.f / 16.f));
    float fr = (float)s * inv;
    ct[i] = cosf(fr);
    st[i] = sinf(fr);
}

// apply rope in place: q [T][1024], k = cols 0..1023 of kv [T][2048]; rot dims = h*64+32..63
__global__ __launch_bounds__(256) void rope_apply_kernel(float* __restrict__ q, float* __restrict__ kv,
                                                         const float* __restrict__ ct, const float* __restrict__ st) {
    int gid = blockIdx.x * 256 + threadIdx.x;
    if (gid >= T_ * H_) return;
    int t = gid >> 4, h = gid & 15;
    int s = t & (S_ - 1);
    float c[16], sn[16];
#pragma unroll
    for (int j = 0; j < 16; j += 4) {
        *(float4*)&c[j]  = *(const float4*)(ct + s * 16 + j);
        *(float4*)&sn[j] = *(const float4*)(st + s * 16 + j);
    }
#pragma unroll
    for (int a2 = 0; a2 < 2; a2++) {
        float* p = a2 ? (kv + (size_t)t * 2048 + h * 64 + 32)
                      : (q  + (size_t)t * 1024 + h * 64 + 32);
        float r[32], o2[32];
#pragma unroll
        for (int j2 = 0; j2 < 32; j2 += 4) *(float4*)&r[j2] = *(const float4*)(p + j2);
#pragma unroll
        for (int i = 0; i < 16; i++) {
            o2[i]      = r[i] * c[i] - r[i + 16] * sn[i];
            o2[i + 16] = r[i + 16] * c[i] + r[i] * sn[i];
        }
#pragma unroll
        for (int j2 = 0; j2 < 32; j2 += 4) *(float4*)(p + j2) = *(const float4*)&o2[j2];
    }
}

// ---------------- K planes: kv f32 [T][2048] cols h*64+d -> Khi/Klo [(b*16+h)][s][64] bf16 ----------------
__global__ __launch_bounds__(256) void kpack_kernel(const float* __restrict__ kv,
                                                    bf16_t* __restrict__ Khi, bf16_t* __restrict__ Klo) {
    int i = blockIdx.x * 256 + threadIdx.x;      // T_*1024/4 threads
    int idx = i * 4;                             // output element index
    int d = idx & 63;
    int s = (idx >> 6) & (S_ - 1);
    int bh = idx >> 17;                          // b*16+h  (2^17 = S_*64)
    int b = bh >> 4, h = bh & 15;
    size_t src = ((size_t)(b * S_ + s)) * 2048 + h * 64 + d;
    float4 v = *(const float4*)(kv + src);
    bf16x4 hv, lv; bf16_t hh, ll;
    split2(v.x, hh, ll); hv[0] = hh; lv[0] = ll;
    split2(v.y, hh, ll); hv[1] = hh; lv[1] = ll;
    split2(v.z, hh, ll); hv[2] = hh; lv[2] = ll;
    split2(v.w, hh, ll); hv[3] = hh; lv[3] = ll;
    *(bf16x4*)(Khi + idx) = hv;
    *(bf16x4*)(Klo + idx) = lv;
}

// ---------------- V planes: kv f32 [b][s][1024 + hd] -> Vthi/Vtlo [b*1024+hd][S] bf16 (transposed) ----------------
__global__ __launch_bounds__(256) void vtrans_kernel(const float* __restrict__ kv,
                                                     bf16_t* __restrict__ Vthi, bf16_t* __restrict__ Vtlo) {
    __shared__ float tile[32][33];
    const int bz = blockIdx.z;
    const int s0 = blockIdx.x * 32, hd0 = blockIdx.y * 32;
    const int rr = threadIdx.x >> 5, cc = threadIdx.x & 31;
    const float* inb = kv + (size_t)bz * S_ * 2048 + 1024;
#pragma unroll
    for (int it = 0; it < 4; it++) {
        int s = s0 + rr + it * 8;
        tile[rr + it * 8][cc] = inb[(size_t)s * 2048 + hd0 + cc];
    }
    __syncthreads();
    bf16_t* oh = Vthi + (size_t)bz * 1024 * S_;
    bf16_t* ol = Vtlo + (size_t)bz * 1024 * S_;
#pragma unroll
    for (int it = 0; it < 4; it++) {
        int hd = hd0 + rr + it * 8;
        float v = tile[cc][rr + it * 8];
        bf16_t hh, ll; split2(v, hh, ll);
        oh[(size_t)hd * S_ + s0 + cc] = hh;
        ol[(size_t)hd * S_ + s0 + cc] = ll;
    }
}

// ---------------- bf16x3 MFMA GEMM (near-fp32): C = (Ah+Al)@(Bh+Bl)^T (+resid) ----------------
// M fixed = 4096 (full rows). EMIT: 0 = f32 out, 1 = hi/lo split out. Staging via global_load_lds (async DMA).
template <bool RESID, int EMIT>
__global__ __launch_bounds__(256) void mfma3_gemm_kernel(const bf16_t* __restrict__ Ah, const bf16_t* __restrict__ Al,
                                                         const bf16_t* __restrict__ Bh, const bf16_t* __restrict__ Bl,
                                                         float* __restrict__ Cf,
                                                         bf16_t* __restrict__ Chi, bf16_t* __restrict__ Clo,
                                                         const float* __restrict__ resid,
                                                         int K, int lda, int ldc) {
    __shared__ __align__(16) bf16_t Ash[128 * 32];
    __shared__ __align__(16) bf16_t Asl[128 * 32];
    __shared__ __align__(16) bf16_t Bsh[128 * 32];
    __shared__ __align__(16) bf16_t Bsl[128 * 32];
    const int tid = threadIdx.x;
    const int lane = tid & 63, w = tid >> 6;
    const int wm = (w & 1) * 64, wn = (w >> 1) * 64;
    const int m0 = blockIdx.y * 128, n0 = blockIdx.x * 128;

    f32x4 acc[4][4];
#pragma unroll
    for (int mi = 0; mi < 4; mi++)
#pragma unroll
        for (int ni = 0; ni < 4; ni++) { f32x4 zz = {0.f, 0.f, 0.f, 0.f}; acc[mi][ni] = zz; }

    const int mrow = lane & 15, q = lane >> 4;
    for (int k0 = 0; k0 < K; k0 += 32) {
#pragma unroll
        for (int i = 0; i < 2; i++) {
            int chunk = tid + i * 256;
            int row = chunk >> 2, koff = (chunk & 3) * 8;
            size_t aoff = (size_t)(m0 + row) * lda + k0 + koff;
            size_t boff = (size_t)(n0 + row) * K + k0 + koff;
            GLL16(Ah + aoff, Ash + chunk * 8);
            GLL16(Al + aoff, Asl + chunk * 8);
            GLL16(Bh + boff, Bsh + chunk * 8);
            GLL16(Bl + boff, Bsl + chunk * 8);
        }
        __syncthreads();
        bf16x8 ah[4], al[4], bh[4], bl[4];
#pragma unroll
        for (int mi = 0; mi < 4; mi++) {
            ah[mi] = *(const bf16x8*)(Ash + (wm + mi * 16 + mrow) * 32 + q * 8);
            al[mi] = *(const bf16x8*)(Asl + (wm + mi * 16 + mrow) * 32 + q * 8);
        }
#pragma unroll
        for (int ni = 0; ni < 4; ni++) {
            bh[ni] = *(const bf16x8*)(Bsh + (wn + ni * 16 + mrow) * 32 + q * 8);
            bl[ni] = *(const bf16x8*)(Bsl + (wn + ni * 16 + mrow) * 32 + q * 8);
        }
#pragma unroll
        for (int mi = 0; mi < 4; mi++)
#pragma unroll
            for (int ni = 0; ni < 4; ni++) {
                acc[mi][ni] = __builtin_amdgcn_mfma_f32_16x16x32_bf16(al[mi], bh[ni], acc[mi][ni], 0, 0, 0);
                acc[mi][ni] = __builtin_amdgcn_mfma_f32_16x16x32_bf16(ah[mi], bl[ni], acc[mi][ni], 0, 0, 0);
                acc[mi][ni] = __builtin_amdgcn_mfma_f32_16x16x32_bf16(ah[mi], bh[ni], acc[mi][ni], 0, 0, 0);
            }
        __syncthreads();
    }
    // epilogue: C/D layout col = lane&15, row = (lane>>4)*4 + v
#pragma unroll
    for (int mi = 0; mi < 4; mi++) {
        int rbase = m0 + wm + mi * 16 + q * 4;
#pragma unroll
        for (int v = 0; v < 4; v++) {
            int r = rbase + v;
#pragma unroll
            for (int ni = 0; ni < 4; ni++) {
                int c = n0 + wn + ni * 16 + mrow;
                float val = acc[mi][ni][v];
                if (RESID) val += resid[(size_t)r * ldc + c];
                if (EMIT == 0) {
                    Cf[(size_t)r * ldc + c] = val;
                } else {
                    bf16_t h, l; split2(val, h, l);
                    Chi[(size_t)r * ldc + c] = h;
                    Clo[(size_t)r * ldc + c] = l;
                }
            }
        }
    }
}

// ---------------- MFMA flash attention (causal), bf16x3 QK / bf16x2 PV, K/V pre-split planes ----------------
// grid: 1024 = 32 q-tiles (64 rows) x 32 bh, balanced so each CU's 4 co-resident blocks sum to 66 work-units.
// 4 waves, wave w owns q rows [w*16, w*16+16). LDS: 5 x [64][64] bf16, all XOR-swizzled = 40 KB -> 4 blocks/CU.
__global__ __launch_bounds__(256, 4) void attn_mfma_kernel(const float* __restrict__ Q,
                                                        const bf16_t* __restrict__ Khig, const bf16_t* __restrict__ Klog,
                                                        const bf16_t* __restrict__ Vthig, const bf16_t* __restrict__ Vtlog,
                                                        bf16_t* __restrict__ Ohi, bf16_t* __restrict__ Olo) {
    __shared__ __align__(16) bf16_t Kh[64][64];
    __shared__ __align__(16) bf16_t Kl[64][64];
    __shared__ __align__(16) bf16_t Vth[64][64];   // Vth[d][k] (transposed), XOR-swizzled
    __shared__ __align__(16) bf16_t Vtl[64][64];
    __shared__ __align__(16) bf16_t Ph[64][64];    // P rounded to bf16, XOR-swizzled cols

    const int tid = threadIdx.x;
    const int lane = tid & 63, w = tid >> 6;
    const int mrow = lane & 15, qq = lane >> 4;
    const int j = blockIdx.x;
    // balanced (qt, bh) mapping: groups of 256; per-rank qt sums to const 66 work-units across the 4 groups
    const int g = j >> 8, c5 = j & 255, rk = c5 >> 5, bh = c5 & 31;
    const int qt = (g == 0) ? (31 - rk) : (g == 1) ? rk : (g == 2) ? (23 - rk) : (8 + rk);
    const int b = bh >> 4, h = bh & 15;
    const int q0 = qt * 64;
    const float*  Qb  = Q + (size_t)b * S_ * 1024 + h * 64;
    const bf16_t* Khb = Khig + (size_t)bh * S_ * 64;
    const bf16_t* Klb = Klog + (size_t)bh * S_ * 64;
    const bf16_t* Vhb = Vthig + (size_t)(b * 1024 + h * 64) * S_;
    const bf16_t* Vlb = Vtlog + (size_t)(b * 1024 + h * 64) * S_;

    // ---- Q fragments in registers, pre-scaled by 1/sqrt(HD)=0.125 (exact), hi/lo split ----
    bf16x8 qh[2], ql[2];                           // [ks]
    {
        int r = q0 + w * 16 + mrow;
#pragma unroll
        for (int ks = 0; ks < 2; ks++) {
            const float* p = Qb + (size_t)r * 1024 + ks * 32 + qq * 8;
            float4 a = *(const float4*)p;
            float4 b2 = *(const float4*)(p + 4);
            float vals[8] = {a.x, a.y, a.z, a.w, b2.x, b2.y, b2.z, b2.w};
#pragma unroll
            for (int jj = 0; jj < 8; jj++) {
                bf16_t hh, ll; split2(vals[jj] * 0.125f, hh, ll);
                qh[ks][jj] = hh; ql[ks][jj] = ll;
            }
        }
    }

    f32x4 acc_o[4];
    float m_r[4], l_r[4];
#pragma unroll
    for (int ni = 0; ni < 4; ni++) { f32x4 zz = {0.f, 0.f, 0.f, 0.f}; acc_o[ni] = zz; }
#pragma unroll
    for (int v = 0; v < 4; v++) { m_r[v] = -1e30f; l_r[v] = 0.f; }

    for (int kt = 0; kt <= qt; kt++) {
        const int k0 = kt * 64;
        // ---- stage K and V (both XOR-swizzled) from bf16 planes ----
#pragma unroll
        for (int i = 0; i < 2; i++) {
            int cc = tid + i * 256;                // 512 chunks of 8 bf16 per plane
            int rr = cc >> 3, c8 = (cc & 7) * 8;
            int csw = c8 ^ ((rr & 7) << 3);
            *(uint4*)&Kh[rr][csw] = *(const uint4*)(Khb + (size_t)(k0 + rr) * 64 + c8);
            *(uint4*)&Kl[rr][csw] = *(const uint4*)(Klb + (size_t)(k0 + rr) * 64 + c8);
            *(uint4*)&Vth[rr][csw] = *(const uint4*)(Vhb + (size_t)rr * S_ + k0 + c8);
            *(uint4*)&Vtl[rr][csw] = *(const uint4*)(Vlb + (size_t)rr * S_ + k0 + c8);
        }
        __syncthreads();

        // ---- S = Q @ K^T (bf16x3) ----
        f32x4 acc_s[4];
#pragma unroll
        for (int ni = 0; ni < 4; ni++) { f32x4 zz = {0.f, 0.f, 0.f, 0.f}; acc_s[ni] = zz; }
#pragma unroll
        for (int ks = 0; ks < 2; ks++) {
            const int c0 = ks * 32 + qq * 8;
            bf16x8 bhf[4], blf[4];
#pragma unroll
            for (int ni = 0; ni < 4; ni++) {
                int row = ni * 16 + mrow;
                int cs = c0 ^ ((row & 7) << 3);
                bhf[ni] = *(const bf16x8*)&Kh[row][cs];
                blf[ni] = *(const bf16x8*)&Kl[row][cs];
            }
#pragma unroll
            for (int ni = 0; ni < 4; ni++) {
                acc_s[ni] = __builtin_amdgcn_mfma_f32_16x16x32_bf16(ql[ks], bhf[ni], acc_s[ni], 0, 0, 0);
                acc_s[ni] = __builtin_amdgcn_mfma_f32_16x16x32_bf16(qh[ks], blf[ni], acc_s[ni], 0, 0, 0);
                acc_s[ni] = __builtin_amdgcn_mfma_f32_16x16x32_bf16(qh[ks], bhf[ni], acc_s[ni], 0, 0, 0);
            }
        }
        // ---- online softmax (rows: w*16 + qq*4+v; cols: ni*16+mrow) ----
        const bool diag = (kt == qt);
#pragma unroll
        for (int v = 0; v < 4; v++) {
            int rloc = w * 16 + qq * 4 + v;        // row within 64-row q tile
            float sv[4];
            float rmax = -1e30f;
#pragma unroll
            for (int ni = 0; ni < 4; ni++) {
                float s = acc_s[ni][v];
                if (diag && (ni * 16 + mrow) > rloc) s = -1e30f;
                sv[ni] = s;
                rmax = fmaxf(rmax, s);
            }
#pragma unroll
            for (int off = 1; off < 16; off <<= 1) rmax = fmaxf(rmax, __shfl_xor(rmax, off));
            float mo = m_r[v];
            float mn = fmaxf(mo, rmax);
            float al = __expf(mo - mn);
            m_r[v] = mn;
            int t7 = (rloc & 7) << 3;
            float rs = 0.f;
#pragma unroll
            for (int ni = 0; ni < 4; ni++) {
                float p = __expf(sv[ni] - mn);
                bf16_t ph = (bf16_t)p;
                Ph[rloc][(ni * 16 + mrow) ^ t7] = ph;
                rs += (float)ph;                   // denominator from same rounded P -> consistent weights
            }
#pragma unroll
            for (int off = 1; off < 16; off <<= 1) rs += __shfl_xor(rs, off);
            l_r[v] = l_r[v] * al + rs;
#pragma unroll
            for (int ni = 0; ni < 4; ni++) acc_o[ni][v] *= al;
        }
        // ---- O += P @ V (bf16x2: P@Vl + P@Vh). P rows read by owning wave only. ----
#pragma unroll
        for (int ks = 0; ks < 2; ks++) {
            const int rc = ks * 32 + qq * 8;
            bf16x8 pah, vhf[4], vlf[4];
            {
                int rowp = w * 16 + mrow;
                int cp = rc ^ ((rowp & 7) << 3);
                pah = *(const bf16x8*)&Ph[rowp][cp];
            }
#pragma unroll
            for (int ni = 0; ni < 4; ni++) {
                int cv = ni * 16 + mrow;
                int vs = rc ^ ((cv & 7) << 3);
                vhf[ni] = *(const bf16x8*)&Vth[cv][vs];
                vlf[ni] = *(const bf16x8*)&Vtl[cv][vs];
            }
#pragma unroll
            for (int ni = 0; ni < 4; ni++) {
                acc_o[ni] = __builtin_amdgcn_mfma_f32_16x16x32_bf16(pah, vlf[ni], acc_o[ni], 0, 0, 0);
                acc_o[ni] = __builtin_amdgcn_mfma_f32_16x16x32_bf16(pah, vhf[ni], acc_o[ni], 0, 0, 0);
            }
        }
        __syncthreads();
    }
    // ---- epilogue: normalize, split hi/lo, store ----
#pragma unroll
    for (int v = 0; v < 4; v++) {
        int rq = q0 + w * 16 + qq * 4 + v;
        float inv = 1.f / l_r[v];
        size_t base = (size_t)(b * S_ + rq) * 1024 + h * 64;
#pragma unroll
        for (int ni = 0; ni < 4; ni++) {
            float val = acc_o[ni][v] * inv;
            bf16_t hh, ll; split2(val, hh, ll);
            Ohi[base + ni * 16 + mrow] = hh;
            Olo[base + ni * 16 + mrow] = ll;
        }
    }
}

// ---------------- gate: affinities + top-2 membership -> priority [NR][T] ----------------
__global__ __launch_bounds__(256) void gate_kernel(const float* __restrict__ xn2, const float* __restrict__ Wg,
                                                   const float* __restrict__ bias, float* __restrict__ pri) {
    __shared__ float red[256][8];
    int t = blockIdx.x, tid = threadIdx.x;
    float acc[7] = {0.f, 0.f, 0.f, 0.f, 0.f, 0.f, 0.f};
    for (int d = tid; d < D_; d += 256) {
        float xv = xn2[(size_t)t * D_ + d];
        const float* wr = Wg + d * 7;
#pragma unroll
        for (int e = 0; e < 7; e++) acc[e] = fmaf(xv, wr[e], acc[e]);
    }
#pragma unroll
    for (int e = 0; e < 7; e++) red[tid][e] = acc[e];
    __syncthreads();
    for (int s2 = 128; s2 > 0; s2 >>= 1) {
        if (tid < s2) {
#pragma unroll
            for (int e = 0; e < 7; e++) red[tid][e] += red[tid + s2][e];
        }
        __syncthreads();
    }
    if (tid == 0) {
        float a[7];
#pragma unroll
        for (int e = 0; e < 7; e++) a[e] = 1.f / (1.f + expf(-(red[0][e] + bias[e])));
        int e1 = 0;
#pragma unroll
        for (int e = 1; e < 7; e++) if (a[e] > a[e1]) e1 = e;     // strict > : lowest-index tiebreak
        int e2 = -1;
#pragma unroll
        for (int e = 0; e < 7; e++) if (e != e1 && (e2 < 0 || a[e] > a[e2])) e2 = e;
#pragma unroll
        for (int e = 0; e < 7; e++) pri[(size_t)e * T_ + t] = (e == e1 || e == e2) ? a[e] : -1.f;
    }
}

// ---------------- exact top-585: 32-step binary threshold search, 1 barrier/bit, ballot tie-rank ----------------
// Tie-break order (slot i, wave wid, lane) == idx order (idx = i*1024 + wid*64 + lane) -> matches stable top_k.
__global__ __launch_bounds__(1024) void select_kernel(const float* __restrict__ pri, int* __restrict__ sel_idx,
                                                      float* __restrict__ sel_w, int* __restrict__ inv_cnt,
                                                      int* __restrict__ inv_pair) {
    __shared__ int wcnt[2][16];     // parity double-buffered per-wave counts
    __shared__ int wtot[4][16];     // eq-to-threshold counts per (slot, wave)
    __shared__ int wpre[4][16];     // exclusive prefix of wtot in (slot-major, wave) order
    __shared__ int ctr;
    const int e = blockIdx.x, tid = threadIdx.x;
    const int lane = tid & 63, wid = tid >> 6;

    u32 myk[4];
#pragma unroll
    for (int i = 0; i < 4; i++) {
        float pv = pri[(size_t)e * T_ + tid + i * 1024];
        myk[i] = (pv > 0.f) ? __float_as_uint(pv) : 0u;
    }
    if (tid == 0) ctr = 0;

    // binary search: p = max t with count(keys >= t) >= CAP.  One barrier per bit.
    u32 p = 0;
    for (int b = 31; b >= 0; b--) {
        u32 t = p | (1u << b);
        int cnt = 0;
#pragma unroll
        for (int i = 0; i < 4; i++) cnt += (myk[i] >= t) ? 1 : 0;
#pragma unroll
        for (int off = 32; off > 0; off >>= 1) cnt += __shfl_xor(cnt, off);
        if (lane == 0) wcnt[b & 1][wid] = cnt;
        __syncthreads();
        int tot = 0;
#pragma unroll
        for (int k2 = 0; k2 < 16; k2++) tot += wcnt[b & 1][k2];
        if (tot >= CAP_) p = t;
    }
    // count strictly greater
    int cntGT;
    {
        int cnt = 0;
#pragma unroll
        for (int i = 0; i < 4; i++) cnt += (myk[i] > p) ? 1 : 0;
#pragma unroll
        for (int off = 32; off > 0; off >>= 1) cnt += __shfl_xor(cnt, off);
        if (lane == 0) wcnt[1][wid] = cnt;
        __syncthreads();
        int g2 = 0;
#pragma unroll
        for (int k2 = 0; k2 < 16; k2++) g2 += wcnt[1][k2];
        cntGT = g2;
    }
    int quota = CAP_ - cntGT;   // slots left for keys == p (>=1 when p>0)

    // ballot-based rank among keys == p, in idx order (slot-major, wave, lane)
    int eqpre[4];
#pragma unroll
    for (int i = 0; i < 4; i++) {
        bool eq = (myk[i] == p) && (p != 0u);
        u64 mask = __ballot(eq);
        eqpre[i] = (int)__popcll(mask & ((1ull << lane) - 1ull));
        if (lane == 0) wtot[i][wid] = (int)__popcll(mask);
    }
    __syncthreads();
    if (tid < 64) {
        int v = wtot[tid >> 4][tid & 15];
        int inc = v;
#pragma unroll
        for (int off = 1; off < 64; off <<= 1) {
            int n = __shfl_up(inc, off);
            if (lane >= off) inc += n;
        }
        wpre[tid >> 4][tid & 15] = inc - v;    // exclusive prefix
    }
    __syncthreads();

    // assignment: kept = (k > p) or (k == p, p>0, rank < quota)
#pragma unroll
    for (int i = 0; i < 4; i++) {
        int idx = tid + i * 1024;
        u32 k = myk[i];
        bool kept = (k > p);
        if (!kept && k == p && p != 0u) kept = (wpre[i][wid] + eqpre[i] < quota);
        if (kept) {
            int s = atomicAdd(&ctr, 1);
            sel_idx[e * CAP_ + s] = idx;
            sel_w[e * CAP_ + s] = __uint_as_float(k);
            int pos = atomicAdd(&inv_cnt[idx], 1);
            inv_pair[idx * 2 + pos] = e * CAP_ + s;
        }
    }
    __syncthreads();
    for (int s = ctr + tid; s < CAP_; s += 1024) {  // unfilled slots -> token 0, weight 0
        sel_idx[e * CAP_ + s] = 0;
        sel_w[e * CAP_ + s] = 0.f;
    }
}

// ---------------- transpose + convert: out[z][n][k] = (bf16) in[z][k][nbase+n] ----------------
__global__ __launch_bounds__(256) void packT_kernel(const float* __restrict__ in, bf16_t* __restrict__ out,
                                                    int K, int N, int nbase,
                                                    long long inStride, long long outStride) {
    __shared__ float tile[32][33];
    const int z = blockIdx.z;
    const int k0 = blockIdx.x * 32, n0 = blockIdx.y * 32;
    const int rr = threadIdx.x >> 5, cc = threadIdx.x & 31;
    const float* inz = in + (size_t)z * inStride;
#pragma unroll
    for (int it = 0; it < 4; it++) {
        int k = k0 + rr + it * 8;
        tile[rr + it * 8][cc] = inz[(size_t)k * N + nbase + n0 + cc];
    }
    __syncthreads();
    bf16_t* outz = out + (size_t)z * outStride;
#pragma unroll
    for (int it = 0; it < 4; it++) {
        int nl = n0 + rr + it * 8;
        outz[(size_t)nl * K + k0 + cc] = (bf16_t)tile[cc][rr + it * 8];
    }
}

// ---------------- bf16 MFMA GEMM (single precision pass, experts): C = gather(A) @ Bt^T (*scale) ----------------
// Staging via global_load_lds (async DMA); gathered A rows are per-lane global sources (allowed).
template <bool GATHER, bool SCALE, bool OUTBF16>
__global__ __launch_bounds__(256) void mfma_gemm_kernel(const bf16_t* __restrict__ A, const bf16_t* __restrict__ Bt,
                                                        void* __restrict__ Cv,
                                                        const int* __restrict__ gidx, const float* __restrict__ scale,
                                                        int M, int K, int lda, int ldc,
                                                        long long strideA, long long strideBt, long long strideC,
                                                        int gstride) {
    __shared__ __align__(16) bf16_t As[128 * 32];
    __shared__ __align__(16) bf16_t Bs[128 * 32];
    const int tid = threadIdx.x;
    const int lane = tid & 63, w = tid >> 6;
    const int wm = (w & 1) * 64, wn = (w >> 1) * 64;
    const int z = blockIdx.z;
    const int m0 = blockIdx.y * 128, n0 = blockIdx.x * 128;
    const bf16_t* Az = A + (GATHER ? 0 : (size_t)z * strideA);
    const bf16_t* Bz = Bt + (size_t)z * strideBt;

    int arow[2];
#pragma unroll
    for (int i = 0; i < 2; i++) {
        int chunk = tid + i * 256;
        int r = m0 + (chunk >> 2);
        if (r > M - 1) r = M - 1;
        arow[i] = GATHER ? gidx[z * gstride + r] : r;
    }

    f32x4 acc[4][4];
#pragma unroll
    for (int mi = 0; mi < 4; mi++)
#pragma unroll
        for (int ni = 0; ni < 4; ni++) { f32x4 zz = {0.f, 0.f, 0.f, 0.f}; acc[mi][ni] = zz; }

    const int mrow = lane & 15, q = lane >> 4;
    for (int k0 = 0; k0 < K; k0 += 32) {
#pragma unroll
        for (int i = 0; i < 2; i++) {
            int chunk = tid + i * 256;
            int koff = (chunk & 3) * 8;
            GLL16(Az + (size_t)arow[i] * lda + k0 + koff, As + chunk * 8);
            GLL16(Bz + (size_t)(n0 + (chunk >> 2)) * K + k0 + koff, Bs + chunk * 8);
        }
        __syncthreads();
        bf16x8 af[4], bfr[4];
#pragma unroll
        for (int mi = 0; mi < 4; mi++)
            af[mi] = *(const bf16x8*)(As + (wm + mi * 16 + mrow) * 32 + q * 8);
#pragma unroll
        for (int ni = 0; ni < 4; ni++)
            bfr[ni] = *(const bf16x8*)(Bs + (wn + ni * 16 + mrow) * 32 + q * 8);
#pragma unroll
        for (int mi = 0; mi < 4; mi++)
#pragma unroll
            for (int ni = 0; ni < 4; ni++)
                acc[mi][ni] = __builtin_amdgcn_mfma_f32_16x16x32_bf16(af[mi], bfr[ni], acc[mi][ni], 0, 0, 0);
        __syncthreads();
    }
#pragma unroll
    for (int mi = 0; mi < 4; mi++) {
        int rbase = m0 + wm + mi * 16 + q * 4;
#pragma unroll
        for (int v = 0; v < 4; v++) {
            int r = rbase + v;
            if (r < M) {
                float sc = SCALE ? scale[z * gstride + r] : 1.f;
#pragma unroll
                for (int ni = 0; ni < 4; ni++) {
                    int c = n0 + wn + ni * 16 + mrow;
                    float val = acc[mi][ni][v];
                    if (SCALE) val *= sc;
                    size_t off = (size_t)z * strideC + (size_t)r * ldc + c;
                    if (OUTBF16) ((bf16_t*)Cv)[off] = (bf16_t)val;
                    else         ((float*)Cv)[off] = val;
                }
            }
        }
    }
}

// ---------------- SwiGLU elementwise ----------------
__global__ __launch_bounds__(256) void swiglu_kernel(const bf16_t* __restrict__ h, bf16_t* __restrict__ act,
                                                     int rows) {
    int i8 = blockIdx.x * 256 + threadIdx.x;
    int total = rows * 128;
    if (i8 >= total) return;
    int r = i8 >> 7, f = (i8 & 127) * 8;
    bf16x8 h1 = *(const bf16x8*)(h + (size_t)r * 2048 + f);
    bf16x8 h2 = *(const bf16x8*)(h + (size_t)r * 2048 + 1024 + f);
    bf16x8 o;
#pragma unroll
    for (int j = 0; j < 8; j++) {
        float a = (float)h1[j], g = (float)h2[j];
        o[j] = (bf16_t)(a * g / (1.f + __expf(-g)));
    }
    *(bf16x8*)(act + (size_t)r * 1024 + f) = o;
}

// ---------------- final combine: out = x1 + shared + sum routed ----------------
__global__ __launch_bounds__(256) void final_kernel(const float* __restrict__ x1, const float* __restrict__ sh,
                                                    const float* __restrict__ eout, const int* __restrict__ icnt,
                                                    const int* __restrict__ ipair, float* __restrict__ out) {
    int t = blockIdx.x, c = threadIdx.x * 4;
    float4 v = *(const float4*)(x1 + (size_t)t * D_ + c);
    float4 s2 = *(const float4*)(sh + (size_t)t * D_ + c);
    v.x += s2.x; v.y += s2.y; v.z += s2.z; v.w += s2.w;
    int n = icnt[t];
    for (int p = 0; p < n; p++) {
        int row = ipair[t * 2 + p];
        float4 ev = *(const float4*)(eout + (size_t)row * D_ + c);
        v.x += ev.x; v.y += ev.y; v.z += ev.z; v.w += ev.w;
    }
    *(float4*)(out + (size_t)t * D_ + c) = v;
}

// ---------------- launch ----------------
extern "C" void kernel_launch(void* const* d_in, const int* in_sizes, int n_in,
                              void* d_out, int out_size, void* d_ws, size_t ws_size,
                              hipStream_t stream) {
    (void)in_sizes; (void)n_in; (void)out_size; (void)ws_size;
    const float* x       = (const float*)d_in[0];
    const float* Wq_lat  = (const float*)d_in[2];
    const float* Wkv_lat = (const float*)d_in[3];
    const float* Wrot_q  = (const float*)d_in[4];
    const float* Wrot_k  = (const float*)d_in[5];
    const float* Wq_up   = (const float*)d_in[6];
    const float* Wk_up   = (const float*)d_in[7];
    const float* Wv_up   = (const float*)d_in[8];
    const float* Wout    = (const float*)d_in[9];
    const float* n1w     = (const float*)d_in[10];
    const float* n2w     = (const float*)d_in[11];
    const float* Ws1     = (const float*)d_in[12];
    const float* Ws2     = (const float*)d_in[13];
    const float* Wr1     = (const float*)d_in[14];
    const float* Wr2     = (const float*)d_in[15];
    const float* Wgate   = (const float*)d_in[16];
    const float* ebias   = (const float*)d_in[17];
    float* out = (float*)d_out;

    char* wsb = (char*)d_ws;
    // phase-1 pointers
    bf16_t* xnhi = (bf16_t*)(wsb + OFF_R0);
    bf16_t* xnlo = (bf16_t*)(wsb + OFF_R0 + 8 * MB_);
    bf16_t* zlhi = (bf16_t*)(wsb + OFF_R1);
    bf16_t* zllo = (bf16_t*)(wsb + OFF_R1 + 6 * MB_);
    float*  plat = (float*)(wsb + OFF_PLAT);
    float*  pqc  = (float*)(wsb + OFF_PQC);
    float*  pkv  = (float*)(wsb + OFF_PKV);
    bf16_t* plth = (bf16_t*)(wsb + OFF_PLTH);
    bf16_t* pltl = (bf16_t*)(wsb + OFF_PLTL);
    bf16_t* pqth = (bf16_t*)(wsb + OFF_PQTH);
    bf16_t* pqtl = (bf16_t*)(wsb + OFF_PQTL);
    bf16_t* pkth = (bf16_t*)(wsb + OFF_PKTH);
    bf16_t* pktl = (bf16_t*)(wsb + OFF_PKTL);
    bf16_t* woth = (bf16_t*)(wsb + OFF_WOTH);
    bf16_t* wotl = (bf16_t*)(wsb + OFF_WOTL);
    float*  qb   = (float*)(wsb + OFF_R2);
    float*  kvb  = (float*)(wsb + OFF_R3);
    bf16_t* khig = (bf16_t*)(wsb + OFF_KHI);
    bf16_t* klog = (bf16_t*)(wsb + OFF_KLO);
    bf16_t* vthig = (bf16_t*)(wsb + OFF_VTHI);
    bf16_t* vtlog = (bf16_t*)(wsb + OFF_VTLO);
    bf16_t* atth = (bf16_t*)(wsb + OFF_R0);            // att splits reuse R0 (xn dead after zlat GEMM)
    bf16_t* attl = (bf16_t*)(wsb + OFF_R0 + 8 * MB_);
    float*  x1   = (float*)(wsb + OFF_X1);
    float*  cost = (float*)(wsb + OFF_COS);
    float*  sint = (float*)(wsb + OFF_SIN);
    // phase-2 pointers
    float*  xn2  = (float*)(wsb + OFF_R0);             // f32 for gate (att splits dead after Wout GEMM)
    bf16_t* Wr2T = (bf16_t*)(wsb + OFF_R0);            // after gate
    bf16_t* xnb  = (bf16_t*)(wsb + OFF_R1);
    bf16_t* Ws1T = (bf16_t*)(wsb + OFF_R1 + 8 * MB_);
    bf16_t* hbuf = (bf16_t*)(wsb + OFF_R2);
    bf16_t* actb = (bf16_t*)(wsb + OFF_R3);
    float*  eout = (float*)(wsb + OFF_R3 + 8 * MB_);
    bf16_t* Wr1H = (bf16_t*)(wsb + OFF_R4);
    float*  shout = (float*)(wsb + OFF_R4);
    bf16_t* Ws2T = (bf16_t*)(wsb + OFF_WS2T);
    float*  pri  = (float*)(wsb + OFF_PRI);
    int*    seli = (int*)(wsb + OFF_SELI);
    float*  selw = (float*)(wsb + OFF_SELW);
    int*    icnt = (int*)(wsb + OFF_ICNT);
    int*    ipr  = (int*)(wsb + OFF_IPR);

    // --- sublayer 1: attention path (bf16x3 MFMA GEMMs, MFMA flash attention) ---
    rmsnorm_kernel<0><<<T_, 256, 0, stream>>>(x, n1w, nullptr, xnhi, xnlo);
    pack_w_kernel<<<7168, 256, 0, stream>>>(Wq_lat, Wkv_lat, Wq_up, Wrot_q, Wk_up, Wrot_k, Wv_up,
                                            plat, pqc, pkv);
    rope_table_kernel<<<(S_ * 16) / 256, 256, 0, stream>>>(cost, sint);
    packTsplit_kernel<<<dim3(32, 24), 256, 0, stream>>>(plat, plth, pltl, 1024, 768);
    packTsplit_kernel<<<dim3(16, 32), 256, 0, stream>>>(pqc, pqth, pqtl, 512, 1024);
    packTsplit_kernel<<<dim3(8, 64), 256, 0, stream>>>(pkv, pkth, pktl, 256, 2048);
    packTsplit_kernel<<<dim3(32, 32), 256, 0, stream>>>(Wout, woth, wotl, 1024, 1024);
    // zlat = xn @ PLAT : 4096x768x1024, split output
    mfma3_gemm_kernel<false, 1><<<dim3(6, 32), 256, 0, stream>>>(
        xnhi, xnlo, plth, pltl, nullptr, zlhi, zllo, nullptr, 1024, 1024, 768);
    // q = zlat[:, :512] @ PQC : 4096x1024x512, f32 out
    mfma3_gemm_kernel<false, 0><<<dim3(8, 32), 256, 0, stream>>>(
        zlhi, zllo, pqth, pqtl, qb, nullptr, nullptr, nullptr, 512, 768, 1024);
    // k|v = zlat[:, 512:768] @ PKV : 4096x2048x256, f32 out
    mfma3_gemm_kernel<false, 0><<<dim3(16, 32), 256, 0, stream>>>(
        zlhi + 512, zllo + 512, pkth, pktl, kvb, nullptr, nullptr, nullptr, 256, 768, 2048);
    rope_apply_kernel<<<(T_ * H_) / 256, 256, 0, stream>>>(qb, kvb, cost, sint);
    // pre-split K/V to bf16 hi/lo planes (hoists conversion out of the flash loop)
    kpack_kernel<<<(T_ * 1024 / 4) / 256, 256, 0, stream>>>(kvb, khig, klog);
    vtrans_kernel<<<dim3(64, 32, 2), 256, 0, stream>>>(kvb, vthig, vtlog);
    attn_mfma_kernel<<<dim3(1024), 256, 0, stream>>>(qb, khig, klog, vthig, vtlog, atth, attl);
    // x1 = att @ Wout + x : 4096x1024x1024
    mfma3_gemm_kernel<true, 0><<<dim3(8, 32), 256, 0, stream>>>(
        atth, attl, woth, wotl, x1, nullptr, nullptr, x, 1024, 1024, 1024);

    // --- sublayer 2: MoE ---
    rmsnorm_kernel<1><<<T_, 256, 0, stream>>>(x1, n2w, xn2, xnb, nullptr);
    hipMemsetAsync(icnt, 0, T_ * sizeof(int), stream);
    gate_kernel<<<T_, 256, 0, stream>>>(xn2, Wgate, ebias, pri);           // fp32 gate
    select_kernel<<<NR_, 1024, 0, stream>>>(pri, seli, selw, icnt, ipr);   // exact top-CAP

    // weight packs (R0 free after gate)
    packT_kernel<<<dim3(32, 32, 7), 256, 0, stream>>>(Wr2, Wr2T, 1024, 1024, 0,
                                                      (long long)1024 * 1024, (long long)1024 * 1024);
    packT_kernel<<<dim3(32, 64, 1), 256, 0, stream>>>(Ws1, Ws1T, 1024, 2048, 0, 0, 0);
    packT_kernel<<<dim3(32, 32, 1), 256, 0, stream>>>(Ws2, Ws2T, 1024, 1024, 0, 0, 0);

    // routed experts (Wr1 halves staged through R4)
    packT_kernel<<<dim3(32, 32, 7), 256, 0, stream>>>(Wr1, Wr1H, 1024, 2048, 0,
                                                      (long long)1024 * 2048, (long long)1024 * 1024);
    mfma_gemm_kernel<true, false, true><<<dim3(8, 5, 7), 256, 0, stream>>>(
        xnb, Wr1H, hbuf, seli, nullptr, CAP_, 1024, 1024, 2048,
        0, (long long)1024 * 1024, (long long)CAP_ * 2048, CAP_);
    packT_kernel<<<dim3(32, 32, 7), 256, 0, stream>>>(Wr1, Wr1H, 1024, 2048, 1024,
                                                      (long long)1024 * 2048, (long long)1024 * 1024);
    mfma_gemm_kernel<true, false, true><<<dim3(8, 5, 7), 256, 0, stream>>>(
        xnb, Wr1H, hbuf + 1024, seli, nullptr, CAP_, 1024, 1024, 2048,
        0, (long long)1024 * 1024, (long long)CAP_ * 2048, CAP_);
    swiglu_kernel<<<(NR_ * CAP_ * 128 + 255) / 256, 256, 0, stream>>>(hbuf, actb, NR_ * CAP_);
    mfma_gemm_kernel<false, true, false><<<dim3(8, 5, 7), 256, 0, stream>>>(
        actb, Wr2T, eout, nullptr, selw, CAP_, 1024, 1024, 1024,
        (long long)CAP_ * 1024, (long long)1024 * 1024, (long long)CAP_ * 1024, CAP_);

    // shared expert (R4 free -> shout)
    mfma_gemm_kernel<false, false, true><<<dim3(16, 32, 1), 256, 0, stream>>>(
        xnb, Ws1T, hbuf, nullptr, nullptr, T_, 1024, 1024, 2048, 0, 0, 0, 0);
    swiglu_kernel<<<(T_ * 128 + 255) / 256, 256, 0, stream>>>(hbuf, actb, T_);
    mfma_gemm_kernel<false, false, false><<<dim3(8, 32, 1), 256, 0, stream>>>(
        actb, Ws2T, shout, nullptr, nullptr, T_, 1024, 1024, 1024, 0, 0, 0, 0);

    // combine
    final_kernel<<<T_, 256, 0, stream>>>(x1, shout, eout, icnt, ipr, out);
}

// Round 8
// 644.005 us; speedup vs baseline: 1.3135x; 1.0700x over previous
//
#include <hip/hip_runtime.h>
#include <cstdint>
#include <cstddef>

// ---------------- static problem config ----------------
#define B_   2
#define S_   2048
#define D_   1024
#define T_   4096          // B*S
#define H_   16
#define HD_  64
#define LQ_  512
#define LKV_ 256
#define FF_  1024
#define NR_  7
#define CAP_ 585

typedef unsigned int   u32;
typedef unsigned long long u64;
typedef __bf16 bf16_t;
typedef __bf16 bf16x8 __attribute__((ext_vector_type(8)));
typedef __bf16 bf16x4 __attribute__((ext_vector_type(4)));
typedef float  f32x4  __attribute__((ext_vector_type(4)));

// async global->LDS, 16B per lane; LDS dest must be wave-uniform base + lane*16 (linear layouts only)
#define GLL16(g, l) __builtin_amdgcn_global_load_lds((__attribute__((address_space(1))) const void*)(g), \
                                                     (__attribute__((address_space(3))) void*)(l), 16, 0, 0)

// ---------------- workspace layout (bytes), regions phase-reused, ~111 MB ----------------
static constexpr size_t MB_ = 1024 * 1024;
static constexpr size_t KB_ = 1024;
// R0 0-16M: xn hi(8M)+lo(8M) -> att hi+lo -> xn2 f32 -> Wr2T bf16 (14.7M)
static constexpr size_t OFF_R0   = 0;
// R1 16-28M: zlat hi(6M)+lo(6M) -> Vthi bf16 8M (attn) -> xnb bf16 8M + Ws1T 4M
static constexpr size_t OFF_R1   = 16 * MB_;
// R2 28-44M: PLAT/PQC/PKV f32 temps (7M) -> q f32 16M -> hbuf bf16 16M
static constexpr size_t OFF_R2   = 28 * MB_;
// R3 44-76M: kv f32 32M -> actb bf16 8M + eout f32 16.8M
static constexpr size_t OFF_R3   = 44 * MB_;
// R4 76-92M: WoutT splits (4M) + packT temps -> Vtlo (8M @ 80M) -> Wr1H bf16 14.7M -> shout f32 16M
static constexpr size_t OFF_R4   = 76 * MB_;
static constexpr size_t OFF_X1   = 92 * MB_;             // Khi/Klo (attn) -> [T][D] f32 x1
static constexpr size_t OFF_PRI  = 108 * MB_;            // [NR][T] f32 (128K)
static constexpr size_t OFF_SELI = OFF_PRI + 128 * KB_;  // [NR][CAP] int
static constexpr size_t OFF_SELW = OFF_SELI + 32 * KB_;  // [NR][CAP] f32
static constexpr size_t OFF_ICNT = OFF_SELW + 32 * KB_;  // [T] int
static constexpr size_t OFF_IPR  = OFF_ICNT + 32 * KB_;  // [T][2] int
static constexpr size_t OFF_COS  = OFF_IPR + 64 * KB_;   // [S][16] f32
static constexpr size_t OFF_SIN  = OFF_COS + 128 * KB_;  // [S][16] f32
static constexpr size_t OFF_WS2T = 109 * MB_;            // Ws2T bf16 2M -> ends 111M
// sub-offsets
static constexpr size_t OFF_PLAT = OFF_R2;               // [1024][768] f32 (3M)
static constexpr size_t OFF_PQC  = OFF_R2 + 3 * MB_;     // [512][1024] f32 (2M)
static constexpr size_t OFF_PKV  = OFF_R2 + 5 * MB_;     // [256][2048] f32 (2M)
// R4 internals: WoutT survives through attn; PLT/PQT/PKT dead after q/kv GEMMs
static constexpr size_t OFF_WOTH = OFF_R4;                    // 76M, 2M (needed after attn)
static constexpr size_t OFF_WOTL = OFF_R4 + 2 * MB_;          // 78M, 2M
static constexpr size_t OFF_PLTH = OFF_R4 + 4 * MB_;          // 80M, 1.5M (dead after zlat GEMM)
static constexpr size_t OFF_PLTL = OFF_R4 + 5632 * KB_;       // 81.5M
static constexpr size_t OFF_PQTH = OFF_R4 + 7 * MB_;          // 83M, 1M (dead after q GEMM)
static constexpr size_t OFF_PQTL = OFF_R4 + 8 * MB_;          // 84M
static constexpr size_t OFF_PKTH = OFF_R4 + 9 * MB_;          // 85M, 1M (dead after kv GEMM)
static constexpr size_t OFF_PKTL = OFF_R4 + 10 * MB_;         // 86M -> ends 87M
// attention bf16 planes (alive only during attn)
static constexpr size_t OFF_VTHI = OFF_R1;                    // 16M, 8M (over dead zlat)
static constexpr size_t OFF_VTLO = OFF_R4 + 4 * MB_;          // 80M, 8M (over dead PLT/PQT/PKT + free)
static constexpr size_t OFF_KHI  = OFF_X1;                    // 92M, 8M (x1 written after attn)
static constexpr size_t OFF_KLO  = OFF_X1 + 8 * MB_;          // 100M, 8M

__device__ __forceinline__ void split2(float v, bf16_t& h, bf16_t& l) {
    h = (bf16_t)v;
    l = (bf16_t)(v - (float)h);
}

// ---------------- RMSNorm: MODE 0 -> emit hi/lo bf16 planes; MODE 1 -> emit f32 + single bf16 ----------------
template <int MODE>
__global__ __launch_bounds__(256) void rmsnorm_kernel(const float* __restrict__ x,
                                                      const float* __restrict__ w,
                                                      float* __restrict__ outf,
                                                      bf16_t* __restrict__ o1,
                                                      bf16_t* __restrict__ o2) {
    int t = blockIdx.x;
    int c = threadIdx.x * 4;
    float4 f = *(const float4*)(x + (size_t)t * D_ + c);
    float ss = f.x * f.x + f.y * f.y + f.z * f.z + f.w * f.w;
#pragma unroll
    for (int off = 32; off > 0; off >>= 1) ss += __shfl_down(ss, off);
    __shared__ float red[4];
    int lane = threadIdx.x & 63, wid = threadIdx.x >> 6;
    if (lane == 0) red[wid] = ss;
    __syncthreads();
    float tot = red[0] + red[1] + red[2] + red[3];
    float inv = 1.f / sqrtf(tot * (1.f / D_) + 1e-6f);
    float4 wv = *(const float4*)(w + c);
    float v[4];
    v[0] = f.x * inv * wv.x; v[1] = f.y * inv * wv.y;
    v[2] = f.z * inv * wv.z; v[3] = f.w * inv * wv.w;
    if (MODE == 0) {
        bf16x4 hv, lv;
#pragma unroll
        for (int j = 0; j < 4; j++) { bf16_t h, l; split2(v[j], h, l); hv[j] = h; lv[j] = l; }
        *(bf16x4*)(o1 + (size_t)t * D_ + c) = hv;
        *(bf16x4*)(o2 + (size_t)t * D_ + c) = lv;
    } else {
        float4 o; o.x = v[0]; o.y = v[1]; o.z = v[2]; o.w = v[3];
        *(float4*)(outf + (size_t)t * D_ + c) = o;
        bf16x4 bv;
#pragma unroll
        for (int j = 0; j < 4; j++) bv[j] = (bf16_t)v[j];
        *(bf16x4*)(o1 + (size_t)t * D_ + c) = bv;
    }
}

// ---------------- pack fp32 attention weights into [K][N] fused layouts ----------------
__global__ __launch_bounds__(256) void pack_w_kernel(const float* __restrict__ Wq_lat, const float* __restrict__ Wkv_lat,
                                                     const float* __restrict__ Wq_up, const float* __restrict__ Wrot_q,
                                                     const float* __restrict__ Wk_up, const float* __restrict__ Wrot_k,
                                                     const float* __restrict__ Wv_up,
                                                     float* __restrict__ PLAT, float* __restrict__ PQC,
                                                     float* __restrict__ PKV) {
    int i = blockIdx.x * 256 + threadIdx.x;
    const int NL = 1024 * 768;
    const int NQ = 512 * 1024;
    if (i < NL) {
        int k = i / 768, c = i - k * 768;
        PLAT[i] = (c < 512) ? Wq_lat[k * 512 + c] : Wkv_lat[k * 256 + (c - 512)];
    } else if (i < NL + NQ) {
        int i2 = i - NL;
        int k = i2 >> 10, c = i2 & 1023, h = c >> 6, j = c & 63;
        PQC[i2] = (j < 32) ? Wq_up[k * 1024 + c] : Wrot_q[k * 1024 + h * 64 + (j - 32)];
    } else {
        int i3 = i - NL - NQ;
        int k = i3 >> 11, c = i3 & 2047;
        if (c < 1024) {
            int h = c >> 6, j = c & 63;
            PKV[i3] = (j < 32) ? Wk_up[k * 1024 + c] : Wrot_k[k * 1024 + h * 64 + (j - 32)];
        } else {
            PKV[i3] = Wv_up[k * 1024 + (c - 1024)];
        }
    }
}

// ---------------- transpose + split: in [K][N] f32 -> outhi/outlo [N][K] bf16 ----------------
__global__ __launch_bounds__(256) void packTsplit_kernel(const float* __restrict__ in,
                                                         bf16_t* __restrict__ outhi, bf16_t* __restrict__ outlo,
                                                         int K, int N) {
    __shared__ float tile[32][33];
    const int k0 = blockIdx.x * 32, n0 = blockIdx.y * 32;
    const int rr = threadIdx.x >> 5, cc = threadIdx.x & 31;
#pragma unroll
    for (int it = 0; it < 4; it++) {
        int k = k0 + rr + it * 8;
        tile[rr + it * 8][cc] = in[(size_t)k * N + n0 + cc];
    }
    __syncthreads();
#pragma unroll
    for (int it = 0; it < 4; it++) {
        int nl = n0 + rr + it * 8;
        float v = tile[cc][rr + it * 8];
        bf16_t h, l; split2(v, h, l);
        outhi[(size_t)nl * K + k0 + cc] = h;
        outlo[(size_t)nl * K + k0 + cc] = l;
    }
}

// ---------------- rope tables ----------------
__global__ __launch_bounds__(256) void rope_table_kernel(float* __restrict__ ct, float* __restrict__ st) {
    int i = blockIdx.x * 256 + threadIdx.x;   // S_*16
    if (i >= S_ * 16) return;
    int s = i >> 4, j = i & 15;
    float inv = 1.f / powf(10000.f, (float)j * (1.f / 16.f));
    float fr = (float)s * inv;
    ct[i] = cosf(fr);
    st[i] = sinf(fr);
}

// apply rope in place: q [T][1024], k = cols 0..1023 of kv [T][2048]; rot dims = h*64+32..63
__global__ __launch_bounds__(256) void rope_apply_kernel(float* __restrict__ q, float* __restrict__ kv,
                                                         const float* __restrict__ ct, const float* __restrict__ st) {
    int gid = blockIdx.x * 256 + threadIdx.x;
    if (gid >= T_ * H_) return;
    int t = gid >> 4, h = gid & 15;
    int s = t & (S_ - 1);
    float c[16], sn[16];
#pragma unroll
    for (int j = 0; j < 16; j += 4) {
        *(float4*)&c[j]  = *(const float4*)(ct + s * 16 + j);
        *(float4*)&sn[j] = *(const float4*)(st + s * 16 + j);
    }
#pragma unroll
    for (int a2 = 0; a2 < 2; a2++) {
        float* p = a2 ? (kv + (size_t)t * 2048 + h * 64 + 32)
                      : (q  + (size_t)t * 1024 + h * 64 + 32);
        float r[32], o2[32];
#pragma unroll
        for (int j2 = 0; j2 < 32; j2 += 4) *(float4*)&r[j2] = *(const float4*)(p + j2);
#pragma unroll
        for (int i = 0; i < 16; i++) {
            o2[i]      = r[i] * c[i] - r[i + 16] * sn[i];
            o2[i + 16] = r[i + 16] * c[i] + r[i] * sn[i];
        }
#pragma unroll
        for (int j2 = 0; j2 < 32; j2 += 4) *(float4*)(p + j2) = *(const float4*)&o2[j2];
    }
}

// ---------------- K planes: kv f32 [T][2048] cols h*64+d -> Khi/Klo [(b*16+h)][s][64] bf16 ----------------
__global__ __launch_bounds__(256) void kpack_kernel(const float* __restrict__ kv,
                                                    bf16_t* __restrict__ Khi, bf16_t* __restrict__ Klo) {
    int i = blockIdx.x * 256 + threadIdx.x;      // T_*1024/4 threads
    int idx = i * 4;                             // output element index
    int d = idx & 63;
    int s = (idx >> 6) & (S_ - 1);
    int bh = idx >> 17;                          // b*16+h  (2^17 = S_*64)
    int b = bh >> 4, h = bh & 15;
    size_t src = ((size_t)(b * S_ + s)) * 2048 + h * 64 + d;
    float4 v = *(const float4*)(kv + src);
    bf16x4 hv, lv; bf16_t hh, ll;
    split2(v.x, hh, ll); hv[0] = hh; lv[0] = ll;
    split2(v.y, hh, ll); hv[1] = hh; lv[1] = ll;
    split2(v.z, hh, ll); hv[2] = hh; lv[2] = ll;
    split2(v.w, hh, ll); hv[3] = hh; lv[3] = ll;
    *(bf16x4*)(Khi + idx) = hv;
    *(bf16x4*)(Klo + idx) = lv;
}

// ---------------- V planes: kv f32 [b][s][1024 + hd] -> Vthi/Vtlo [b*1024+hd][S] bf16 (transposed) ----------------
__global__ __launch_bounds__(256) void vtrans_kernel(const float* __restrict__ kv,
                                                     bf16_t* __restrict__ Vthi, bf16_t* __restrict__ Vtlo) {
    __shared__ float tile[32][33];
    const int bz = blockIdx.z;
    const int s0 = blockIdx.x * 32, hd0 = blockIdx.y * 32;
    const int rr = threadIdx.x >> 5, cc = threadIdx.x & 31;
    const float* inb = kv + (size_t)bz * S_ * 2048 + 1024;
#pragma unroll
    for (int it = 0; it < 4; it++) {
        int s = s0 + rr + it * 8;
        tile[rr + it * 8][cc] = inb[(size_t)s * 2048 + hd0 + cc];
    }
    __syncthreads();
    bf16_t* oh = Vthi + (size_t)bz * 1024 * S_;
    bf16_t* ol = Vtlo + (size_t)bz * 1024 * S_;
#pragma unroll
    for (int it = 0; it < 4; it++) {
        int hd = hd0 + rr + it * 8;
        float v = tile[cc][rr + it * 8];
        bf16_t hh, ll; split2(v, hh, ll);
        oh[(size_t)hd * S_ + s0 + cc] = hh;
        ol[(size_t)hd * S_ + s0 + cc] = ll;
    }
}

// ---------------- bf16x3 MFMA GEMM (near-fp32): C = (Ah+Al)@(Bh+Bl)^T (+resid) ----------------
// 128x64 tile (waves 2M x 2N) for >=2 blocks/CU occupancy. M fixed = 4096 rows.
// EMIT: 0 = f32 out, 1 = hi/lo split out. Staging via global_load_lds (async DMA).
template <bool RESID, int EMIT>
__global__ __launch_bounds__(256, 2) void mfma3_gemm_kernel(const bf16_t* __restrict__ Ah, const bf16_t* __restrict__ Al,
                                                         const bf16_t* __restrict__ Bh, const bf16_t* __restrict__ Bl,
                                                         float* __restrict__ Cf,
                                                         bf16_t* __restrict__ Chi, bf16_t* __restrict__ Clo,
                                                         const float* __restrict__ resid,
                                                         int K, int lda, int ldc) {
    __shared__ __align__(16) bf16_t Ash[128 * 32];
    __shared__ __align__(16) bf16_t Asl[128 * 32];
    __shared__ __align__(16) bf16_t Bsh[64 * 32];
    __shared__ __align__(16) bf16_t Bsl[64 * 32];
    const int tid = threadIdx.x;
    const int lane = tid & 63, w = tid >> 6;
    const int wm = (w & 1) * 64, wn = (w >> 1) * 32;
    const int m0 = blockIdx.y * 128, n0 = blockIdx.x * 64;

    f32x4 acc[4][2];
#pragma unroll
    for (int mi = 0; mi < 4; mi++)
#pragma unroll
        for (int ni = 0; ni < 2; ni++) { f32x4 zz = {0.f, 0.f, 0.f, 0.f}; acc[mi][ni] = zz; }

    const int mrow = lane & 15, q = lane >> 4;
    for (int k0 = 0; k0 < K; k0 += 32) {
#pragma unroll
        for (int i = 0; i < 2; i++) {
            int chunk = tid + i * 256;
            int row = chunk >> 2, koff = (chunk & 3) * 8;
            size_t aoff = (size_t)(m0 + row) * lda + k0 + koff;
            GLL16(Ah + aoff, Ash + chunk * 8);
            GLL16(Al + aoff, Asl + chunk * 8);
        }
        {
            int row = tid >> 2, koff = (tid & 3) * 8;
            size_t boff = (size_t)(n0 + row) * K + k0 + koff;
            GLL16(Bh + boff, Bsh + tid * 8);
            GLL16(Bl + boff, Bsl + tid * 8);
        }
        __syncthreads();
        bf16x8 ah[4], al[4], bh[2], bl[2];
#pragma unroll
        for (int mi = 0; mi < 4; mi++) {
            ah[mi] = *(const bf16x8*)(Ash + (wm + mi * 16 + mrow) * 32 + q * 8);
            al[mi] = *(const bf16x8*)(Asl + (wm + mi * 16 + mrow) * 32 + q * 8);
        }
#pragma unroll
        for (int ni = 0; ni < 2; ni++) {
            bh[ni] = *(const bf16x8*)(Bsh + (wn + ni * 16 + mrow) * 32 + q * 8);
            bl[ni] = *(const bf16x8*)(Bsl + (wn + ni * 16 + mrow) * 32 + q * 8);
        }
#pragma unroll
        for (int mi = 0; mi < 4; mi++)
#pragma unroll
            for (int ni = 0; ni < 2; ni++) {
                acc[mi][ni] = __builtin_amdgcn_mfma_f32_16x16x32_bf16(al[mi], bh[ni], acc[mi][ni], 0, 0, 0);
                acc[mi][ni] = __builtin_amdgcn_mfma_f32_16x16x32_bf16(ah[mi], bl[ni], acc[mi][ni], 0, 0, 0);
                acc[mi][ni] = __builtin_amdgcn_mfma_f32_16x16x32_bf16(ah[mi], bh[ni], acc[mi][ni], 0, 0, 0);
            }
        __syncthreads();
    }
    // epilogue: C/D layout col = lane&15, row = (lane>>4)*4 + v
#pragma unroll
    for (int mi = 0; mi < 4; mi++) {
        int rbase = m0 + wm + mi * 16 + q * 4;
#pragma unroll
        for (int v = 0; v < 4; v++) {
            int r = rbase + v;
#pragma unroll
            for (int ni = 0; ni < 2; ni++) {
                int c = n0 + wn + ni * 16 + mrow;
                float val = acc[mi][ni][v];
                if (RESID) val += resid[(size_t)r * ldc + c];
                if (EMIT == 0) {
                    Cf[(size_t)r * ldc + c] = val;
                } else {
                    bf16_t h, l; split2(val, h, l);
                    Chi[(size_t)r * ldc + c] = h;
                    Clo[(size_t)r * ldc + c] = l;
                }
            }
        }
    }
}

// ---------------- MFMA flash attention (causal), bf16x3 QK / bf16x2 PV, K/V pre-split planes ----------------
// grid: 1024 = 32 q-tiles (64 rows) x 32 bh, balanced so each CU's 4 co-resident blocks sum to 66 work-units.
// 4 waves, wave w owns q rows [w*16, w*16+16). LDS: 5 x [64][64] bf16, all XOR-swizzled = 40 KB -> 4 blocks/CU.
__global__ __launch_bounds__(256, 4) void attn_mfma_kernel(const float* __restrict__ Q,
                                                        const bf16_t* __restrict__ Khig, const bf16_t* __restrict__ Klog,
                                                        const bf16_t* __restrict__ Vthig, const bf16_t* __restrict__ Vtlog,
                                                        bf16_t* __restrict__ Ohi, bf16_t* __restrict__ Olo) {
    __shared__ __align__(16) bf16_t Kh[64][64];
    __shared__ __align__(16) bf16_t Kl[64][64];
    __shared__ __align__(16) bf16_t Vth[64][64];   // Vth[d][k] (transposed), XOR-swizzled
    __shared__ __align__(16) bf16_t Vtl[64][64];
    __shared__ __align__(16) bf16_t Ph[64][64];    // P rounded to bf16, XOR-swizzled cols

    const int tid = threadIdx.x;
    const int lane = tid & 63, w = tid >> 6;
    const int mrow = lane & 15, qq = lane >> 4;
    const int j = blockIdx.x;
    // balanced (qt, bh) mapping: groups of 256; per-rank qt sums to const 66 work-units across the 4 groups
    const int g = j >> 8, c5 = j & 255, rk = c5 >> 5, bh = c5 & 31;
    const int qt = (g == 0) ? (31 - rk) : (g == 1) ? rk : (g == 2) ? (23 - rk) : (8 + rk);
    const int b = bh >> 4, h = bh & 15;
    const int q0 = qt * 64;
    const float*  Qb  = Q + (size_t)b * S_ * 1024 + h * 64;
    const bf16_t* Khb = Khig + (size_t)bh * S_ * 64;
    const bf16_t* Klb = Klog + (size_t)bh * S_ * 64;
    const bf16_t* Vhb = Vthig + (size_t)(b * 1024 + h * 64) * S_;
    const bf16_t* Vlb = Vtlog + (size_t)(b * 1024 + h * 64) * S_;

    // ---- Q fragments in registers, pre-scaled by 1/sqrt(HD)=0.125 (exact), hi/lo split ----
    bf16x8 qh[2], ql[2];                           // [ks]
    {
        int r = q0 + w * 16 + mrow;
#pragma unroll
        for (int ks = 0; ks < 2; ks++) {
            const float* p = Qb + (size_t)r * 1024 + ks * 32 + qq * 8;
            float4 a = *(const float4*)p;
            float4 b2 = *(const float4*)(p + 4);
            float vals[8] = {a.x, a.y, a.z, a.w, b2.x, b2.y, b2.z, b2.w};
#pragma unroll
            for (int jj = 0; jj < 8; jj++) {
                bf16_t hh, ll; split2(vals[jj] * 0.125f, hh, ll);
                qh[ks][jj] = hh; ql[ks][jj] = ll;
            }
        }
    }

    f32x4 acc_o[4];
    float m_r[4], l_r[4];
#pragma unroll
    for (int ni = 0; ni < 4; ni++) { f32x4 zz = {0.f, 0.f, 0.f, 0.f}; acc_o[ni] = zz; }
#pragma unroll
    for (int v = 0; v < 4; v++) { m_r[v] = -1e30f; l_r[v] = 0.f; }

    for (int kt = 0; kt <= qt; kt++) {
        const int k0 = kt * 64;
        // ---- stage K and V (both XOR-swizzled) from bf16 planes ----
#pragma unroll
        for (int i = 0; i < 2; i++) {
            int cc = tid + i * 256;                // 512 chunks of 8 bf16 per plane
            int rr = cc >> 3, c8 = (cc & 7) * 8;
            int csw = c8 ^ ((rr & 7) << 3);
            *(uint4*)&Kh[rr][csw] = *(const uint4*)(Khb + (size_t)(k0 + rr) * 64 + c8);
            *(uint4*)&Kl[rr][csw] = *(const uint4*)(Klb + (size_t)(k0 + rr) * 64 + c8);
            *(uint4*)&Vth[rr][csw] = *(const uint4*)(Vhb + (size_t)rr * S_ + k0 + c8);
            *(uint4*)&Vtl[rr][csw] = *(const uint4*)(Vlb + (size_t)rr * S_ + k0 + c8);
        }
        __syncthreads();

        // ---- S = Q @ K^T (bf16x3) ----
        f32x4 acc_s[4];
#pragma unroll
        for (int ni = 0; ni < 4; ni++) { f32x4 zz = {0.f, 0.f, 0.f, 0.f}; acc_s[ni] = zz; }
#pragma unroll
        for (int ks = 0; ks < 2; ks++) {
            const int c0 = ks * 32 + qq * 8;
            bf16x8 bhf[4], blf[4];
#pragma unroll
            for (int ni = 0; ni < 4; ni++) {
                int row = ni * 16 + mrow;
                int cs = c0 ^ ((row & 7) << 3);
                bhf[ni] = *(const bf16x8*)&Kh[row][cs];
                blf[ni] = *(const bf16x8*)&Kl[row][cs];
            }
#pragma unroll
            for (int ni = 0; ni < 4; ni++) {
                acc_s[ni] = __builtin_amdgcn_mfma_f32_16x16x32_bf16(ql[ks], bhf[ni], acc_s[ni], 0, 0, 0);
                acc_s[ni] = __builtin_amdgcn_mfma_f32_16x16x32_bf16(qh[ks], blf[ni], acc_s[ni], 0, 0, 0);
                acc_s[ni] = __builtin_amdgcn_mfma_f32_16x16x32_bf16(qh[ks], bhf[ni], acc_s[ni], 0, 0, 0);
            }
        }
        // ---- online softmax (rows: w*16 + qq*4+v; cols: ni*16+mrow) ----
        const bool diag = (kt == qt);
#pragma unroll
        for (int v = 0; v < 4; v++) {
            int rloc = w * 16 + qq * 4 + v;        // row within 64-row q tile
            float sv[4];
            float rmax = -1e30f;
#pragma unroll
            for (int ni = 0; ni < 4; ni++) {
                float s = acc_s[ni][v];
                if (diag && (ni * 16 + mrow) > rloc) s = -1e30f;
                sv[ni] = s;
                rmax = fmaxf(rmax, s);
            }
#pragma unroll
            for (int off = 1; off < 16; off <<= 1) rmax = fmaxf(rmax, __shfl_xor(rmax, off));
            float mo = m_r[v];
            float mn = fmaxf(mo, rmax);
            float al = __expf(mo - mn);
            m_r[v] = mn;
            int t7 = (rloc & 7) << 3;
            float rs = 0.f;
#pragma unroll
            for (int ni = 0; ni < 4; ni++) {
                float p = __expf(sv[ni] - mn);
                bf16_t ph = (bf16_t)p;
                Ph[rloc][(ni * 16 + mrow) ^ t7] = ph;
                rs += (float)ph;                   // denominator from same rounded P -> consistent weights
            }
#pragma unroll
            for (int off = 1; off < 16; off <<= 1) rs += __shfl_xor(rs, off);
            l_r[v] = l_r[v] * al + rs;
#pragma unroll
            for (int ni = 0; ni < 4; ni++) acc_o[ni][v] *= al;
        }
        // ---- O += P @ V (bf16x2: P@Vl + P@Vh). P rows read by owning wave only. ----
#pragma unroll
        for (int ks = 0; ks < 2; ks++) {
            const int rc = ks * 32 + qq * 8;
            bf16x8 pah, vhf[4], vlf[4];
            {
                int rowp = w * 16 + mrow;
                int cp = rc ^ ((rowp & 7) << 3);
                pah = *(const bf16x8*)&Ph[rowp][cp];
            }
#pragma unroll
            for (int ni = 0; ni < 4; ni++) {
                int cv = ni * 16 + mrow;
                int vs = rc ^ ((cv & 7) << 3);
                vhf[ni] = *(const bf16x8*)&Vth[cv][vs];
                vlf[ni] = *(const bf16x8*)&Vtl[cv][vs];
            }
#pragma unroll
            for (int ni = 0; ni < 4; ni++) {
                acc_o[ni] = __builtin_amdgcn_mfma_f32_16x16x32_bf16(pah, vlf[ni], acc_o[ni], 0, 0, 0);
                acc_o[ni] = __builtin_amdgcn_mfma_f32_16x16x32_bf16(pah, vhf[ni], acc_o[ni], 0, 0, 0);
            }
        }
        __syncthreads();
    }
    // ---- epilogue: normalize, split hi/lo, store ----
#pragma unroll
    for (int v = 0; v < 4; v++) {
        int rq = q0 + w * 16 + qq * 4 + v;
        float inv = 1.f / l_r[v];
        size_t base = (size_t)(b * S_ + rq) * 1024 + h * 64;
#pragma unroll
        for (int ni = 0; ni < 4; ni++) {
            float val = acc_o[ni][v] * inv;
            bf16_t hh, ll; split2(val, hh, ll);
            Ohi[base + ni * 16 + mrow] = hh;
            Olo[base + ni * 16 + mrow] = ll;
        }
    }
}

// ---------------- gate: affinities + top-2 membership -> priority [NR][T] ----------------
__global__ __launch_bounds__(256) void gate_kernel(const float* __restrict__ xn2, const float* __restrict__ Wg,
                                                   const float* __restrict__ bias, float* __restrict__ pri) {
    __shared__ float red[256][8];
    int t = blockIdx.x, tid = threadIdx.x;
    float acc[7] = {0.f, 0.f, 0.f, 0.f, 0.f, 0.f, 0.f};
    for (int d = tid; d < D_; d += 256) {
        float xv = xn2[(size_t)t * D_ + d];
        const float* wr = Wg + d * 7;
#pragma unroll
        for (int e = 0; e < 7; e++) acc[e] = fmaf(xv, wr[e], acc[e]);
    }
#pragma unroll
    for (int e = 0; e < 7; e++) red[tid][e] = acc[e];
    __syncthreads();
    for (int s2 = 128; s2 > 0; s2 >>= 1) {
        if (tid < s2) {
#pragma unroll
            for (int e = 0; e < 7; e++) red[tid][e] += red[tid + s2][e];
        }
        __syncthreads();
    }
    if (tid == 0) {
        float a[7];
#pragma unroll
        for (int e = 0; e < 7; e++) a[e] = 1.f / (1.f + expf(-(red[0][e] + bias[e])));
        int e1 = 0;
#pragma unroll
        for (int e = 1; e < 7; e++) if (a[e] > a[e1]) e1 = e;     // strict > : lowest-index tiebreak
        int e2 = -1;
#pragma unroll
        for (int e = 0; e < 7; e++) if (e != e1 && (e2 < 0 || a[e] > a[e2])) e2 = e;
#pragma unroll
        for (int e = 0; e < 7; e++) pri[(size_t)e * T_ + t] = (e == e1 || e == e2) ? a[e] : -1.f;
    }
}

// ---------------- exact top-585: 32-step binary threshold search, 1 barrier/bit, ballot tie-rank ----------------
// Tie-break order (slot i, wave wid, lane) == idx order (idx = i*1024 + wid*64 + lane) -> matches stable top_k.
__global__ __launch_bounds__(1024) void select_kernel(const float* __restrict__ pri, int* __restrict__ sel_idx,
                                                      float* __restrict__ sel_w, int* __restrict__ inv_cnt,
                                                      int* __restrict__ inv_pair) {
    __shared__ int wcnt[2][16];     // parity double-buffered per-wave counts
    __shared__ int wtot[4][16];     // eq-to-threshold counts per (slot, wave)
    __shared__ int wpre[4][16];     // exclusive prefix of wtot in (slot-major, wave) order
    __shared__ int ctr;
    const int e = blockIdx.x, tid = threadIdx.x;
    const int lane = tid & 63, wid = tid >> 6;

    u32 myk[4];
#pragma unroll
    for (int i = 0; i < 4; i++) {
        float pv = pri[(size_t)e * T_ + tid + i * 1024];
        myk[i] = (pv > 0.f) ? __float_as_uint(pv) : 0u;
    }
    if (tid == 0) ctr = 0;

    // binary search: p = max t with count(keys >= t) >= CAP.  One barrier per bit.
    u32 p = 0;
    for (int b = 31; b >= 0; b--) {
        u32 t = p | (1u << b);
        int cnt = 0;
#pragma unroll
        for (int i = 0; i < 4; i++) cnt += (myk[i] >= t) ? 1 : 0;
#pragma unroll
        for (int off = 32; off > 0; off >>= 1) cnt += __shfl_xor(cnt, off);
        if (lane == 0) wcnt[b & 1][wid] = cnt;
        __syncthreads();
        int tot = 0;
#pragma unroll
        for (int k2 = 0; k2 < 16; k2++) tot += wcnt[b & 1][k2];
        if (tot >= CAP_) p = t;
    }
    // count strictly greater
    int cntGT;
    {
        int cnt = 0;
#pragma unroll
        for (int i = 0; i < 4; i++) cnt += (myk[i] > p) ? 1 : 0;
#pragma unroll
        for (int off = 32; off > 0; off >>= 1) cnt += __shfl_xor(cnt, off);
        if (lane == 0) wcnt[1][wid] = cnt;
        __syncthreads();
        int g2 = 0;
#pragma unroll
        for (int k2 = 0; k2 < 16; k2++) g2 += wcnt[1][k2];
        cntGT = g2;
    }
    int quota = CAP_ - cntGT;   // slots left for keys == p (>=1 when p>0)

    // ballot-based rank among keys == p, in idx order (slot-major, wave, lane)
    int eqpre[4];
#pragma unroll
    for (int i = 0; i < 4; i++) {
        bool eq = (myk[i] == p) && (p != 0u);
        u64 mask = __ballot(eq);
        eqpre[i] = (int)__popcll(mask & ((1ull << lane) - 1ull));
        if (lane == 0) wtot[i][wid] = (int)__popcll(mask);
    }
    __syncthreads();
    if (tid < 64) {
        int v = wtot[tid >> 4][tid & 15];
        int inc = v;
#pragma unroll
        for (int off = 1; off < 64; off <<= 1) {
            int n = __shfl_up(inc, off);
            if (lane >= off) inc += n;
        }
        wpre[tid >> 4][tid & 15] = inc - v;    // exclusive prefix
    }
    __syncthreads();

    // assignment: kept = (k > p) or (k == p, p>0, rank < quota)
#pragma unroll
    for (int i = 0; i < 4; i++) {
        int idx = tid + i * 1024;
        u32 k = myk[i];
        bool kept = (k > p);
        if (!kept && k == p && p != 0u) kept = (wpre[i][wid] + eqpre[i] < quota);
        if (kept) {
            int s = atomicAdd(&ctr, 1);
            sel_idx[e * CAP_ + s] = idx;
            sel_w[e * CAP_ + s] = __uint_as_float(k);
            int pos = atomicAdd(&inv_cnt[idx], 1);
            inv_pair[idx * 2 + pos] = e * CAP_ + s;
        }
    }
    __syncthreads();
    for (int s = ctr + tid; s < CAP_; s += 1024) {  // unfilled slots -> token 0, weight 0
        sel_idx[e * CAP_ + s] = 0;
        sel_w[e * CAP_ + s] = 0.f;
    }
}

// ---------------- transpose + convert: out[z][n][k] = (bf16) in[z][k][nbase+n] ----------------
__global__ __launch_bounds__(256) void packT_kernel(const float* __restrict__ in, bf16_t* __restrict__ out,
                                                    int K, int N, int nbase,
                                                    long long inStride, long long outStride) {
    __shared__ float tile[32][33];
    const int z = blockIdx.z;
    const int k0 = blockIdx.x * 32, n0 = blockIdx.y * 32;
    const int rr = threadIdx.x >> 5, cc = threadIdx.x & 31;
    const float* inz = in + (size_t)z * inStride;
#pragma unroll
    for (int it = 0; it < 4; it++) {
        int k = k0 + rr + it * 8;
        tile[rr + it * 8][cc] = inz[(size_t)k * N + nbase + n0 + cc];
    }
    __syncthreads();
    bf16_t* outz = out + (size_t)z * outStride;
#pragma unroll
    for (int it = 0; it < 4; it++) {
        int nl = n0 + rr + it * 8;
        outz[(size_t)nl * K + k0 + cc] = (bf16_t)tile[cc][rr + it * 8];
    }
}

// ---------------- bf16 MFMA GEMM (single precision pass, experts): C = gather(A) @ Bt^T (*scale) ----------------
// 128x64 tile (waves 2M x 2N). Staging via global_load_lds; gathered A rows are per-lane global sources.
template <bool GATHER, bool SCALE, bool OUTBF16>
__global__ __launch_bounds__(256, 2) void mfma_gemm_kernel(const bf16_t* __restrict__ A, const bf16_t* __restrict__ Bt,
                                                        void* __restrict__ Cv,
                                                        const int* __restrict__ gidx, const float* __restrict__ scale,
                                                        int M, int K, int lda, int ldc,
                                                        long long strideA, long long strideBt, long long strideC,
                                                        int gstride) {
    __shared__ __align__(16) bf16_t As[128 * 32];
    __shared__ __align__(16) bf16_t Bs[64 * 32];
    const int tid = threadIdx.x;
    const int lane = tid & 63, w = tid >> 6;
    const int wm = (w & 1) * 64, wn = (w >> 1) * 32;
    const int z = blockIdx.z;
    const int m0 = blockIdx.y * 128, n0 = blockIdx.x * 64;
    const bf16_t* Az = A + (GATHER ? 0 : (size_t)z * strideA);
    const bf16_t* Bz = Bt + (size_t)z * strideBt;

    int arow[2];
#pragma unroll
    for (int i = 0; i < 2; i++) {
        int chunk = tid + i * 256;
        int r = m0 + (chunk >> 2);
        if (r > M - 1) r = M - 1;
        arow[i] = GATHER ? gidx[z * gstride + r] : r;
    }

    f32x4 acc[4][2];
#pragma unroll
    for (int mi = 0; mi < 4; mi++)
#pragma unroll
        for (int ni = 0; ni < 2; ni++) { f32x4 zz = {0.f, 0.f, 0.f, 0.f}; acc[mi][ni] = zz; }

    const int mrow = lane & 15, q = lane >> 4;
    for (int k0 = 0; k0 < K; k0 += 32) {
#pragma unroll
        for (int i = 0; i < 2; i++) {
            int chunk = tid + i * 256;
            int koff = (chunk & 3) * 8;
            GLL16(Az + (size_t)arow[i] * lda + k0 + koff, As + chunk * 8);
        }
        {
            int row = tid >> 2, koff = (tid & 3) * 8;
            GLL16(Bz + (size_t)(n0 + row) * K + k0 + koff, Bs + tid * 8);
        }
        __syncthreads();
        bf16x8 af[4], bfr[2];
#pragma unroll
        for (int mi = 0; mi < 4; mi++)
            af[mi] = *(const bf16x8*)(As + (wm + mi * 16 + mrow) * 32 + q * 8);
#pragma unroll
        for (int ni = 0; ni < 2; ni++)
            bfr[ni] = *(const bf16x8*)(Bs + (wn + ni * 16 + mrow) * 32 + q * 8);
#pragma unroll
        for (int mi = 0; mi < 4; mi++)
#pragma unroll
            for (int ni = 0; ni < 2; ni++)
                acc[mi][ni] = __builtin_amdgcn_mfma_f32_16x16x32_bf16(af[mi], bfr[ni], acc[mi][ni], 0, 0, 0);
        __syncthreads();
    }
#pragma unroll
    for (int mi = 0; mi < 4; mi++) {
        int rbase = m0 + wm + mi * 16 + q * 4;
#pragma unroll
        for (int v = 0; v < 4; v++) {
            int r = rbase + v;
            if (r < M) {
                float sc = SCALE ? scale[z * gstride + r] : 1.f;
#pragma unroll
                for (int ni = 0; ni < 2; ni++) {
                    int c = n0 + wn + ni * 16 + mrow;
                    float val = acc[mi][ni][v];
                    if (SCALE) val *= sc;
                    size_t off = (size_t)z * strideC + (size_t)r * ldc + c;
                    if (OUTBF16) ((bf16_t*)Cv)[off] = (bf16_t)val;
                    else         ((float*)Cv)[off] = val;
                }
            }
        }
    }
}

// ---------------- SwiGLU elementwise ----------------
__global__ __launch_bounds__(256) void swiglu_kernel(const bf16_t* __restrict__ h, bf16_t* __restrict__ act,
                                                     int rows) {
    int i8 = blockIdx.x * 256 + threadIdx.x;
    int total = rows * 128;
    if (i8 >= total) return;
    int r = i8 >> 7, f = (i8 & 127) * 8;
    bf16x8 h1 = *(const bf16x8*)(h + (size_t)r * 2048 + f);
    bf16x8 h2 = *(const bf16x8*)(h + (size_t)r * 2048 + 1024 + f);
    bf16x8 o;
#pragma unroll
    for (int j = 0; j < 8; j++) {
        float a = (float)h1[j], g = (float)h2[j];
        o[j] = (bf16_t)(a * g / (1.f + __expf(-g)));
    }
    *(bf16x8*)(act + (size_t)r * 1024 + f) = o;
}

// ---------------- final combine: out = x1 + shared + sum routed ----------------
__global__ __launch_bounds__(256) void final_kernel(const float* __restrict__ x1, const float* __restrict__ sh,
                                                    const float* __restrict__ eout, const int* __restrict__ icnt,
                                                    const int* __restrict__ ipair, float* __restrict__ out) {
    int t = blockIdx.x, c = threadIdx.x * 4;
    float4 v = *(const float4*)(x1 + (size_t)t * D_ + c);
    float4 s2 = *(const float4*)(sh + (size_t)t * D_ + c);
    v.x += s2.x; v.y += s2.y; v.z += s2.z; v.w += s2.w;
    int n = icnt[t];
    for (int p = 0; p < n; p++) {
        int row = ipair[t * 2 + p];
        float4 ev = *(const float4*)(eout + (size_t)row * D_ + c);
        v.x += ev.x; v.y += ev.y; v.z += ev.z; v.w += ev.w;
    }
    *(float4*)(out + (size_t)t * D_ + c) = v;
}

// ---------------- launch ----------------
extern "C" void kernel_launch(void* const* d_in, const int* in_sizes, int n_in,
                              void* d_out, int out_size, void* d_ws, size_t ws_size,
                              hipStream_t stream) {
    (void)in_sizes; (void)n_in; (void)out_size; (void)ws_size;
    const float* x       = (const float*)d_in[0];
    const float* Wq_lat  = (const float*)d_in[2];
    const float* Wkv_lat = (const float*)d_in[3];
    const float* Wrot_q  = (const float*)d_in[4];
    const float* Wrot_k  = (const float*)d_in[5];
    const float* Wq_up   = (const float*)d_in[6];
    const float* Wk_up   = (const float*)d_in[7];
    const float* Wv_up   = (const float*)d_in[8];
    const float* Wout    = (const float*)d_in[9];
    const float* n1w     = (const float*)d_in[10];
    const float* n2w     = (const float*)d_in[11];
    const float* Ws1     = (const float*)d_in[12];
    const float* Ws2     = (const float*)d_in[13];
    const float* Wr1     = (const float*)d_in[14];
    const float* Wr2     = (const float*)d_in[15];
    const float* Wgate   = (const float*)d_in[16];
    const float* ebias   = (const float*)d_in[17];
    float* out = (float*)d_out;

    char* wsb = (char*)d_ws;
    // phase-1 pointers
    bf16_t* xnhi = (bf16_t*)(wsb + OFF_R0);
    bf16_t* xnlo = (bf16_t*)(wsb + OFF_R0 + 8 * MB_);
    bf16_t* zlhi = (bf16_t*)(wsb + OFF_R1);
    bf16_t* zllo = (bf16_t*)(wsb + OFF_R1 + 6 * MB_);
    float*  plat = (float*)(wsb + OFF_PLAT);
    float*  pqc  = (float*)(wsb + OFF_PQC);
    float*  pkv  = (float*)(wsb + OFF_PKV);
    bf16_t* plth = (bf16_t*)(wsb + OFF_PLTH);
    bf16_t* pltl = (bf16_t*)(wsb + OFF_PLTL);
    bf16_t* pqth = (bf16_t*)(wsb + OFF_PQTH);
    bf16_t* pqtl = (bf16_t*)(wsb + OFF_PQTL);
    bf16_t* pkth = (bf16_t*)(wsb + OFF_PKTH);
    bf16_t* pktl = (bf16_t*)(wsb + OFF_PKTL);
    bf16_t* woth = (bf16_t*)(wsb + OFF_WOTH);
    bf16_t* wotl = (bf16_t*)(wsb + OFF_WOTL);
    float*  qb   = (float*)(wsb + OFF_R2);
    float*  kvb  = (float*)(wsb + OFF_R3);
    bf16_t* khig = (bf16_t*)(wsb + OFF_KHI);
    bf16_t* klog = (bf16_t*)(wsb + OFF_KLO);
    bf16_t* vthig = (bf16_t*)(wsb + OFF_VTHI);
    bf16_t* vtlog = (bf16_t*)(wsb + OFF_VTLO);
    bf16_t* atth = (bf16_t*)(wsb + OFF_R0);            // att splits reuse R0 (xn dead after zlat GEMM)
    bf16_t* attl = (bf16_t*)(wsb + OFF_R0 + 8 * MB_);
    float*  x1   = (float*)(wsb + OFF_X1);
    float*  cost = (float*)(wsb + OFF_COS);
    float*  sint = (float*)(wsb + OFF_SIN);
    // phase-2 pointers
    float*  xn2  = (float*)(wsb + OFF_R0);             // f32 for gate (att splits dead after Wout GEMM)
    bf16_t* Wr2T = (bf16_t*)(wsb + OFF_R0);            // after gate
    bf16_t* xnb  = (bf16_t*)(wsb + OFF_R1);
    bf16_t* Ws1T = (bf16_t*)(wsb + OFF_R1 + 8 * MB_);
    bf16_t* hbuf = (bf16_t*)(wsb + OFF_R2);
    bf16_t* actb = (bf16_t*)(wsb + OFF_R3);
    float*  eout = (float*)(wsb + OFF_R3 + 8 * MB_);
    bf16_t* Wr1H = (bf16_t*)(wsb + OFF_R4);
    float*  shout = (float*)(wsb + OFF_R4);
    bf16_t* Ws2T = (bf16_t*)(wsb + OFF_WS2T);
    float*  pri  = (float*)(wsb + OFF_PRI);
    int*    seli = (int*)(wsb + OFF_SELI);
    float*  selw = (float*)(wsb + OFF_SELW);
    int*    icnt = (int*)(wsb + OFF_ICNT);
    int*    ipr  = (int*)(wsb + OFF_IPR);

    // --- sublayer 1: attention path (bf16x3 MFMA GEMMs, MFMA flash attention) ---
    rmsnorm_kernel<0><<<T_, 256, 0, stream>>>(x, n1w, nullptr, xnhi, xnlo);
    pack_w_kernel<<<7168, 256, 0, stream>>>(Wq_lat, Wkv_lat, Wq_up, Wrot_q, Wk_up, Wrot_k, Wv_up,
                                            plat, pqc, pkv);
    rope_table_kernel<<<(S_ * 16) / 256, 256, 0, stream>>>(cost, sint);
    packTsplit_kernel<<<dim3(32, 24), 256, 0, stream>>>(plat, plth, pltl, 1024, 768);
    packTsplit_kernel<<<dim3(16, 32), 256, 0, stream>>>(pqc, pqth, pqtl, 512, 1024);
    packTsplit_kernel<<<dim3(8, 64), 256, 0, stream>>>(pkv, pkth, pktl, 256, 2048);
    packTsplit_kernel<<<dim3(32, 32), 256, 0, stream>>>(Wout, woth, wotl, 1024, 1024);
    // zlat = xn @ PLAT : 4096x768x1024, split output (128x64 tiles)
    mfma3_gemm_kernel<false, 1><<<dim3(12, 32), 256, 0, stream>>>(
        xnhi, xnlo, plth, pltl, nullptr, zlhi, zllo, nullptr, 1024, 1024, 768);
    // q = zlat[:, :512] @ PQC : 4096x1024x512, f32 out
    mfma3_gemm_kernel<false, 0><<<dim3(16, 32), 256, 0, stream>>>(
        zlhi, zllo, pqth, pqtl, qb, nullptr, nullptr, nullptr, 512, 768, 1024);
    // k|v = zlat[:, 512:768] @ PKV : 4096x2048x256, f32 out
    mfma3_gemm_kernel<false, 0><<<dim3(32, 32), 256, 0, stream>>>(
        zlhi + 512, zllo + 512, pkth, pktl, kvb, nullptr, nullptr, nullptr, 256, 768, 2048);
    rope_apply_kernel<<<(T_ * H_) / 256, 256, 0, stream>>>(qb, kvb, cost, sint);
    // pre-split K/V to bf16 hi/lo planes (hoists conversion out of the flash loop)
    kpack_kernel<<<(T_ * 1024 / 4) / 256, 256, 0, stream>>>(kvb, khig, klog);
    vtrans_kernel<<<dim3(64, 32, 2), 256, 0, stream>>>(kvb, vthig, vtlog);
    attn_mfma_kernel<<<dim3(1024), 256, 0, stream>>>(qb, khig, klog, vthig, vtlog, atth, attl);
    // x1 = att @ Wout + x : 4096x1024x1024
    mfma3_gemm_kernel<true, 0><<<dim3(16, 32), 256, 0, stream>>>(
        atth, attl, woth, wotl, x1, nullptr, nullptr, x, 1024, 1024, 1024);

    // --- sublayer 2: MoE ---
    rmsnorm_kernel<1><<<T_, 256, 0, stream>>>(x1, n2w, xn2, xnb, nullptr);
    hipMemsetAsync(icnt, 0, T_ * sizeof(int), stream);
    gate_kernel<<<T_, 256, 0, stream>>>(xn2, Wgate, ebias, pri);           // fp32 gate
    select_kernel<<<NR_, 1024, 0, stream>>>(pri, seli, selw, icnt, ipr);   // exact top-CAP

    // weight packs (R0 free after gate)
    packT_kernel<<<dim3(32, 32, 7), 256, 0, stream>>>(Wr2, Wr2T, 1024, 1024, 0,
                                                      (long long)1024 * 1024, (long long)1024 * 1024);
    packT_kernel<<<dim3(32, 64, 1), 256, 0, stream>>>(Ws1, Ws1T, 1024, 2048, 0, 0, 0);
    packT_kernel<<<dim3(32, 32, 1), 256, 0, stream>>>(Ws2, Ws2T, 1024, 1024, 0, 0, 0);

    // routed experts (Wr1 halves staged through R4)
    packT_kernel<<<dim3(32, 32, 7), 256, 0, stream>>>(Wr1, Wr1H, 1024, 2048, 0,
                                                      (long long)1024 * 2048, (long long)1024 * 1024);
    mfma_gemm_kernel<true, false, true><<<dim3(16, 5, 7), 256, 0, stream>>>(
        xnb, Wr1H, hbuf, seli, nullptr, CAP_, 1024, 1024, 2048,
        0, (long long)1024 * 1024, (long long)CAP_ * 2048, CAP_);
    packT_kernel<<<dim3(32, 32, 7), 256, 0, stream>>>(Wr1, Wr1H, 1024, 2048, 1024,
                                                      (long long)1024 * 2048, (long long)1024 * 1024);
    mfma_gemm_kernel<true, false, true><<<dim3(16, 5, 7), 256, 0, stream>>>(
        xnb, Wr1H, hbuf + 1024, seli, nullptr, CAP_, 1024, 1024, 2048,
        0, (long long)1024 * 1024, (long long)CAP_ * 2048, CAP_);
    swiglu_kernel<<<(NR_ * CAP_ * 128 + 255) / 256, 256, 0, stream>>>(hbuf, actb, NR_ * CAP_);
    mfma_gemm_kernel<false, true, false><<<dim3(16, 5, 7), 256, 0, stream>>>(
        actb, Wr2T, eout, nullptr, selw, CAP_, 1024, 1024, 1024,
        (long long)CAP_ * 1024, (long long)1024 * 1024, (long long)CAP_ * 1024, CAP_);

    // shared expert (R4 free -> shout)
    mfma_gemm_kernel<false, false, true><<<dim3(32, 32, 1), 256, 0, stream>>>(
        xnb, Ws1T, hbuf, nullptr, nullptr, T_, 1024, 1024, 2048, 0, 0, 0, 0);
    swiglu_kernel<<<(T_ * 128 + 255) / 256, 256, 0, stream>>>(hbuf, actb, T_);
    mfma_gemm_kernel<false, false, false><<<dim3(16, 32, 1), 256, 0, stream>>>(
        actb, Ws2T, shout, nullptr, nullptr, T_, 1024, 1024, 1024, 0, 0, 0, 0);

    // combine
    final_kernel<<<T_, 256, 0, stream>>>(x1, shout, eout, icnt, ipr, out);
}